// Round 14
// baseline (530.051 us; speedup 1.0000x reference)
//
#include <hip/hip_runtime.h>

#define BB 2
#define NN 1024
#define N1 1025
#define DM 128
#define NH 8
#define DK 16
#define DFF 512
#define NBUK 32
#define NLAYERS 3
#define KNN_K 10
#define ADJW 17          // 1025 bits -> 17 u64 words per row
#define BSTR 1088        // padded bucket row stride (bytes)
#define NSPLIT 8
#define BIGF 3.0e38f
#define SM_OFF 24.0f     // fixed softmax exponent offset (|s| bounded << 24+88)

// prepacked-weight element offsets (see init_kernel prepack branch)
#define PWQ_OFF 0
#define PWK_OFF 49152
#define PWV_OFF 98304
#define PWO_OFF 147456
#define PW1_OFF 196608
#define PW2_OFF 393216
#define PWOUT_OFF 589824
#define PWQE_OFF 606208
#define PW_TOT 704512

// init kernel block ranges
#define PBLK 344         // ceil(88064/256) prepack
#define NBNODE 1024      // embed node blocks
#define EBLK (NBNODE + BB)
#define BBLK 8713        // ceil(BB*N1*BSTR/256) bucket

typedef __attribute__((ext_vector_type(8))) short bf8;
typedef __attribute__((ext_vector_type(4))) float f4;
typedef unsigned short u16;
typedef unsigned int u32;

__device__ __forceinline__ u16 f2bf(float x) {
  unsigned u = __float_as_uint(x);
  return (u16)((u + 0x7fff + ((u >> 16) & 1)) >> 16);   // RNE
}
__device__ __forceinline__ float bf2f(u16 u) {
  return __uint_as_float(((unsigned)u) << 16);
}
__device__ __forceinline__ bf8 mk8(ushort4 a, ushort4 b) {
  bf8 r;
  r[0] = (short)a.x; r[1] = (short)a.y; r[2] = (short)a.z; r[3] = (short)a.w;
  r[4] = (short)b.x; r[5] = (short)b.y; r[6] = (short)b.z; r[7] = (short)b.w;
  return r;
}

// ---------------------------------------------------------------- init: prepack + embed(+splits) + bucket
__global__ __launch_bounds__(256) void init_kernel(
    const float* __restrict__ coords, const float* __restrict__ inW,
    const float* __restrict__ inb, const float* __restrict__ gnode,
    const float* __restrict__ Wq, const float* __restrict__ Wk,
    const float* __restrict__ Wv, const float* __restrict__ Wo,
    const float* __restrict__ W1, const float* __restrict__ W2,
    const float* __restrict__ oW, const float* __restrict__ emb,
    u16* __restrict__ PH, u16* __restrict__ PL,
    float* __restrict__ X, u16* __restrict__ XH, u16* __restrict__ XM,
    u16* __restrict__ XL, unsigned char* __restrict__ buckp) {
  int blk = blockIdx.x;
  if (blk < PBLK) {
    // ---------------- prepack (+inline wqe composite)
    int idx = blk * 256 + threadIdx.x;
    if (idx >= 88064) return;
    if (idx >= 75776) {
      int rel = idx - 75776;
      int lane = rel & 63, g = rel >> 6;
      int ks = g & 3, nt = g >> 2;
      int n = nt * 16 + (lane & 15);
      int k = ks * 32 + (lane >> 4) * 8;
      int l = n >> 8; int c = n & 255; int h = c >> 5, bk = c & 31;
      const float* e = emb + ((size_t)l * NBUK + bk) * DM + h * DK;
      const float* wq = Wq + ((size_t)l * DM + h * DK) * DM;
      u16* ph = PH + (size_t)idx * 8;
      u16* pl = PL + (size_t)idx * 8;
      #pragma unroll
      for (int q = 0; q < 8; ++q) {
        float s = 0.f;
        #pragma unroll
        for (int d = 0; d < DK; ++d) s += e[d] * wq[(size_t)d * DM + k + q];
        u16 hh = f2bf(s);
        ph[q] = hh;
        pl[q] = f2bf(s - bf2f(hh));
      }
      return;
    }
    const float* W; int rel, Kdim;
    if (idx < 24576) {
      int seg = idx / 6144; rel = idx % 6144; Kdim = 128;
      W = seg == 0 ? Wq : seg == 1 ? Wk : seg == 2 ? Wv : Wo;
    } else if (idx < 49152) { rel = idx - 24576; Kdim = 128; W = W1; }
    else if (idx < 73728)   { rel = idx - 49152; Kdim = 512; W = W2; }
    else                    { rel = idx - 73728; Kdim = 128; W = oW; }
    int lane = rel & 63;
    int g = rel >> 6;
    int ksteps = Kdim >> 5;
    int ks = g % ksteps, nt = g / ksteps;
    int n = nt * 16 + (lane & 15);
    int k = ks * 32 + (lane >> 4) * 8;
    const float* p = W + (size_t)n * Kdim + k;
    u16* ph = PH + (size_t)idx * 8;
    u16* pl = PL + (size_t)idx * 8;
    #pragma unroll
    for (int q = 0; q < 8; ++q) {
      float x = p[q];
      u16 hh = f2bf(x);
      ph[q] = hh;
      pl[q] = f2bf(x - bf2f(hh));
    }
    return;
  }
  if (blk < PBLK + EBLK) {
    // ---------------- embed (+g row), emitting 3-level splits
    int eb = blk - PBLK;
    if (eb >= NBNODE) {
      int b = eb - NBNODE;
      int t = threadIdx.x;
      if (t >= 128) return;
      int lane = t & 63;
      float sx = 0.f, sy = 0.f;
      for (int n = lane; n < NN; n += 64) {
        float2 c = *(const float2*)(coords + (size_t)(b * NN + n) * 2);
        sx += c.x; sy += c.y;
      }
      #pragma unroll
      for (int o = 1; o < 64; o <<= 1) { sx += __shfl_xor(sx, o); sy += __shfl_xor(sy, o); }
      float mx = sx * (1.0f / NN), my = sy * (1.0f / NN);
      int d = t;
      size_t id = ((size_t)b * N1 + NN) * DM + d;
      float v = gnode[d] + inb[d] + mx * inW[d * 2 + 0] + my * inW[d * 2 + 1];
      X[id] = v;
      u16 hh = f2bf(v); float r1 = v - bf2f(hh);
      u16 mm = f2bf(r1);
      XH[id] = hh; XM[id] = mm; XL[id] = f2bf(r1 - bf2f(mm));
      return;
    }
    int idx = eb * 256 + threadIdx.x;
    if (idx >= BB * NN * DM) return;
    int d = idx % DM; int r = idx / DM; int n = r % NN; int b = r / NN;
    float cx = coords[(b * NN + n) * 2 + 0], cy = coords[(b * NN + n) * 2 + 1];
    size_t id = ((size_t)b * N1 + n) * DM + d;
    float v = cx * inW[d * 2 + 0] + cy * inW[d * 2 + 1] + inb[d];
    X[id] = v;
    u16 hh = f2bf(v); float r1 = v - bf2f(hh);
    u16 mm = f2bf(r1);
    XH[id] = hh; XM[id] = mm; XL[id] = f2bf(r1 - bf2f(mm));
    return;
  }
  // ---------------- bucket (padded rows)
  int idx = (blk - PBLK - EBLK) * 256 + threadIdx.x;
  if (idx >= BB * N1 * BSTR) return;
  int j = idx % BSTR; int r = idx / BSTR; int i = r % N1; int b = r / N1;
  unsigned char v = 0;
  if (j < N1) {
    float xi = 0.f, yi = 0.f, xj = 0.f, yj = 0.f;
    if (i < NN) { xi = coords[(b * NN + i) * 2]; yi = coords[(b * NN + i) * 2 + 1]; }
    if (j < NN) { xj = coords[(b * NN + j) * 2]; yj = coords[(b * NN + j) * 2 + 1]; }
    float dx = xi - xj, dy = yi - yj;
    float dist = sqrtf(dx * dx + dy * dy);
    int bu = (int)(dist * 32.0f);
    bu = bu < 0 ? 0 : (bu > 31 ? 31 : bu);
    v = (unsigned char)bu;
  }
  buckp[idx] = v;
}

// ---------------------------------------------------------------- exact MFMA gram (+adj zero, +local sq)
// sq reconstructed from exact H+M+L decomposition, k-sequential order (deterministic).
__global__ __launch_bounds__(256) void gram_kernel(
    const u16* __restrict__ XH, const u16* __restrict__ XM, const u16* __restrict__ XL,
    unsigned long long* __restrict__ adj, float* __restrict__ d2) {
  __shared__ __align__(16) u16 AsH[32][72];
  __shared__ __align__(16) u16 AsM[32][72];
  __shared__ __align__(16) u16 AsL[32][72];
  __shared__ __align__(16) u16 BsH[64][72];
  __shared__ __align__(16) u16 BsM[64][72];
  __shared__ __align__(16) u16 BsL[64][72];
  __shared__ float sqS[96];               // [0..31]=A rows, [32..95]=B rows
  int b = blockIdx.z;
  int m0 = blockIdx.x * 32, n0 = blockIdx.y * 64;
  size_t boff = (size_t)b * N1;
  int t = threadIdx.x;

  // zero adjacency (1024 blocks x 256 thr covers 34850 u64 words)
  {
    int flat = blockIdx.x + 32 * (blockIdx.y + 16 * blockIdx.z);
    int tid = flat * 256 + t;
    if (tid < BB * N1 * ADJW) adj[tid] = 0ull;
  }

  int lane = t & 63, w = t >> 6;
  int wm = (w >> 1) * 16, wn = (w & 1) * 32;
  int quad = lane >> 4, r16 = lane & 15;

  f4 acc0 = {0.f, 0.f, 0.f, 0.f}, acc1 = {0.f, 0.f, 0.f, 0.f};
  int ar = t >> 3, as_ = (t & 7) * 8;     // A: 32 rows x 8 segs of 8
  int br = t >> 2, bs_ = (t & 3) * 16;    // B: 64 rows x 4 segs of 16
  float mySq = 0.f;                       // row-sq partial for threads t<96

  for (int k0 = 0; k0 < DM; k0 += 64) {
    {
      size_t src = (boff + m0 + ar) * DM + k0 + as_;
      *(bf8*)&AsH[ar][as_] = *(const bf8*)(XH + src);
      *(bf8*)&AsM[ar][as_] = *(const bf8*)(XM + src);
      *(bf8*)&AsL[ar][as_] = *(const bf8*)(XL + src);
    }
    {
      size_t src = (boff + n0 + br) * DM + k0 + bs_;
      *(bf8*)&BsH[br][bs_] = *(const bf8*)(XH + src);
      *(bf8*)&BsH[br][bs_ + 8] = *(const bf8*)(XH + src + 8);
      *(bf8*)&BsM[br][bs_] = *(const bf8*)(XM + src);
      *(bf8*)&BsM[br][bs_ + 8] = *(const bf8*)(XM + src + 8);
      *(bf8*)&BsL[br][bs_] = *(const bf8*)(XL + src);
      *(bf8*)&BsL[br][bs_ + 8] = *(const bf8*)(XL + src + 8);
    }
    __syncthreads();
    #pragma unroll
    for (int ks = 0; ks < 64; ks += 16) {
      int seg = (quad & 1) * 8;
      bf8 aHM = *(const bf8*)((quad < 2) ? &AsH[wm + r16][ks + seg] : &AsM[wm + r16][ks + seg]);
      bf8 aHL = *(const bf8*)((quad < 2) ? &AsH[wm + r16][ks + seg] : &AsL[wm + r16][ks + seg]);
      #pragma unroll
      for (int tt = 0; tt < 2; ++tt) {
        int nr = wn + tt * 16 + r16;
        bf8 bH = *(const bf8*)&BsH[nr][ks + seg];
        bf8 bM = *(const bf8*)&BsM[nr][ks + seg];
        bf8 b3 = *(const bf8*)((quad < 2) ? &BsL[nr][ks + seg] : &BsH[nr][ks + seg]);
        f4& a = tt ? acc1 : acc0;
        a = __builtin_amdgcn_mfma_f32_16x16x32_bf16(aHM, bH, a, 0, 0, 0);  // HH' + MH'
        a = __builtin_amdgcn_mfma_f32_16x16x32_bf16(aHM, bM, a, 0, 0, 0);  // HM' + MM'
        a = __builtin_amdgcn_mfma_f32_16x16x32_bf16(aHL, b3, a, 0, 0, 0);  // HL' + LH'
      }
    }
    // local row-sq accumulation (exact x = H+M+L reconstruction)
    if (t < 96) {
      if (t < 32) {
        for (int k = 0; k < 64; ++k) {
          float x = (bf2f(AsH[t][k]) + bf2f(AsM[t][k])) + bf2f(AsL[t][k]);
          mySq += x * x;
        }
      } else {
        int rb = t - 32;
        for (int k = 0; k < 64; ++k) {
          float x = (bf2f(BsH[rb][k]) + bf2f(BsM[rb][k])) + bf2f(BsL[rb][k]);
          mySq += x * x;
        }
      }
    }
    __syncthreads();
  }
  if (t < 96) sqS[t] = mySq;
  __syncthreads();

  #pragma unroll
  for (int tt = 0; tt < 2; ++tt) {
    f4 a = tt ? acc1 : acc0;
    int nl = wn + tt * 16 + r16;
    int n = n0 + nl;
    float sj = sqS[32 + nl];
    #pragma unroll
    for (int reg = 0; reg < 4; ++reg) {
      int ml = wm + quad * 4 + reg;
      int m = m0 + ml;
      float si = sqS[ml];
      float v = (m == n) ? BIGF : (si + sj - 2.f * a[reg]);
      d2[((size_t)b * NN + m) * NN + n] = v;
    }
  }
}

// ---------------------------------------------------------------- top-10 select -> adjacency bits
__global__ __launch_bounds__(256) void knnsel_kernel(const float* __restrict__ d2,
                                                     unsigned long long* __restrict__ adj) {
  __shared__ float dd[4][NN];
  int blk = blockIdx.x;
  int b = blk / (NN / 4);
  int i0 = (blk % (NN / 4)) * 4;
  int t = threadIdx.x, lane = t & 63, w = t >> 6;

  const float4* src = (const float4*)(d2 + ((size_t)b * NN + i0) * NN);
  float4* dst = (float4*)&dd[0][0];
  #pragma unroll
  for (int x = 0; x < 4; ++x) dst[t + x * 256] = src[t + x * 256];
  __syncthreads();

  int i = i0 + w;
  for (int it = 0; it < KNN_K; ++it) {
    float bv = BIGF; int bi = 0x3fffffff;
    for (int j = lane; j < NN; j += 64) {
      float v = dd[w][j];
      if (v < bv) { bv = v; bi = j; }
    }
    #pragma unroll
    for (int o = 1; o < 64; o <<= 1) {
      float ov = __shfl_xor(bv, o); int oi = __shfl_xor(bi, o);
      if (ov < bv || (ov == bv && oi < bi)) { bv = ov; bi = oi; }
    }
    if (lane == 0) {
      dd[w][bi] = BIGF;
      atomicOr(&adj[((size_t)b * N1 + i) * ADJW + (bi >> 6)], 1ull << (bi & 63));
      atomicOr(&adj[((size_t)b * N1 + bi) * ADJW + (i >> 6)], 1ull << (i & 63));
    }
  }
}

// ---------------------------------------------------------------- direct-fragment GEMM (16x16/wave)
__device__ __forceinline__ void gemm_dev16(
    const u16* __restrict__ AH, const u16* __restrict__ AL,
    const u16* __restrict__ PH, const u16* __restrict__ PL,
    const float* __restrict__ bias, const float* __restrict__ res,
    float* __restrict__ outF, u16* __restrict__ outH, u16* __restrict__ outL,
    int M, int Kdim, int Nout, int relu, int mt, int nt) {
  int lane = threadIdx.x & 63;
  int quad = lane >> 4, r16 = lane & 15;
  int ksteps = Kdim >> 5;
  f4 acc = {0.f, 0.f, 0.f, 0.f};

  int m0 = mt * 16;
  int mrow = m0 + r16; if (mrow >= M) mrow = M - 1;   // clamp; result discarded
  const u16* aph = AH + (size_t)mrow * Kdim + quad * 8;
  const u16* apl = AL + (size_t)mrow * Kdim + quad * 8;
  const u16* ph = PH + ((size_t)nt * ksteps * 64 + lane) * 8;
  const u16* pl = PL + ((size_t)nt * ksteps * 64 + lane) * 8;

  #pragma unroll 4
  for (int ks = 0; ks < ksteps; ++ks) {
    bf8 aH = *(const bf8*)(aph);
    bf8 aL = *(const bf8*)(apl);
    aph += 32; apl += 32;
    bf8 bH = *(const bf8*)(ph + (size_t)ks * 512);
    bf8 bL = *(const bf8*)(pl + (size_t)ks * 512);
    acc = __builtin_amdgcn_mfma_f32_16x16x32_bf16(aH, bH, acc, 0, 0, 0);
    acc = __builtin_amdgcn_mfma_f32_16x16x32_bf16(aH, bL, acc, 0, 0, 0);
    acc = __builtin_amdgcn_mfma_f32_16x16x32_bf16(aL, bH, acc, 0, 0, 0);
  }

  if (m0 >= M) return;
  int n = nt * 16 + r16;
  #pragma unroll
  for (int reg = 0; reg < 4; ++reg) {
    int m = m0 + quad * 4 + reg;    // C layout: col=lane&15, row=quad*4+reg
    if (m < M) {
      float v = acc[reg];
      if (bias) v += bias[n];
      if (relu) v = fmaxf(v, 0.f);
      if (res) v += res[(size_t)m * Nout + n];
      size_t oi = (size_t)m * Nout + n;
      if (outF) outF[oi] = v;
      if (outH) {
        u16 hh = f2bf(v);
        outH[oi] = hh;
        outL[oi] = f2bf(v - bf2f(hh));
      }
    }
  }
}

__global__ __launch_bounds__(256) void gemm_kernel(
    const u16* __restrict__ AH, const u16* __restrict__ AL,
    const u16* __restrict__ PH, const u16* __restrict__ PL,
    const float* __restrict__ bias, const float* __restrict__ res,
    float* __restrict__ outF, u16* __restrict__ outH, u16* __restrict__ outL,
    int M, int Kdim, int Nout, int relu) {
  gemm_dev16(AH, AL, PH, PL, bias, res, outF, outH, outL, M, Kdim, Nout, relu,
             blockIdx.x * 4 + (threadIdx.x >> 6), blockIdx.y);
}

// QKV+QE flattened grid: y<8 Q (0.25-scaled split), <16 K (split), <24 V (bf16), <40 qe (fp32)
__global__ __launch_bounds__(256) void gemm_qkv_kernel(
    const u16* __restrict__ AH, const u16* __restrict__ AL,
    const u16* __restrict__ Pbase_H, const u16* __restrict__ Pbase_L,
    size_t offQ, size_t offK, size_t offV, size_t offE,
    u16* __restrict__ QH, u16* __restrict__ QL,
    u16* __restrict__ KH, u16* __restrict__ KL, u16* __restrict__ Vbf,
    float* __restrict__ qe_all, int M) {
  int y = blockIdx.y;
  int z, nt;
  if (y < 8) { z = 0; nt = y; }
  else if (y < 16) { z = 1; nt = y - 8; }
  else if (y < 24) { z = 2; nt = y - 16; }
  else { z = 3; nt = y - 24; }
  size_t woff = z == 0 ? offQ : (z == 1 ? offK : (z == 2 ? offV : offE));
  const u16* PH = Pbase_H + woff;
  const u16* PL = Pbase_L + woff;
  int lane = threadIdx.x & 63;
  int quad = lane >> 4, r16 = lane & 15;
  int mt = blockIdx.x * 4 + (threadIdx.x >> 6);
  f4 acc = {0.f, 0.f, 0.f, 0.f};
  int m0 = mt * 16;
  int mrow = m0 + r16; if (mrow >= M) mrow = M - 1;
  const u16* aph = AH + (size_t)mrow * DM + quad * 8;
  const u16* apl = AL + (size_t)mrow * DM + quad * 8;
  const u16* ph = PH + ((size_t)nt * 4 * 64 + lane) * 8;
  const u16* pl = PL + ((size_t)nt * 4 * 64 + lane) * 8;
  #pragma unroll
  for (int ks = 0; ks < 4; ++ks) {
    bf8 aH = *(const bf8*)(aph);
    bf8 aL = *(const bf8*)(apl);
    aph += 32; apl += 32;
    bf8 bH = *(const bf8*)(ph + (size_t)ks * 512);
    bf8 bL = *(const bf8*)(pl + (size_t)ks * 512);
    acc = __builtin_amdgcn_mfma_f32_16x16x32_bf16(aH, bH, acc, 0, 0, 0);
    acc = __builtin_amdgcn_mfma_f32_16x16x32_bf16(aH, bL, acc, 0, 0, 0);
    acc = __builtin_amdgcn_mfma_f32_16x16x32_bf16(aL, bH, acc, 0, 0, 0);
  }
  if (m0 >= M) return;
  int n = nt * 16 + r16;
  #pragma unroll
  for (int reg = 0; reg < 4; ++reg) {
    int m = m0 + quad * 4 + reg;
    if (m >= M) continue;
    float v = acc[reg];
    if (z == 3) {
      int b = m / N1, nr = m % N1;
      int h = n >> 5, bk = n & 31;
      qe_all[(((size_t)b * NH + h) * N1 + nr) * 32 + bk] = v;
      continue;
    }
    size_t oi = (size_t)m * DM + n;
    if (z == 0) {
      float sv = v * 0.25f;
      u16 hh = f2bf(sv);
      QH[oi] = hh;
      QL[oi] = f2bf(sv - bf2f(hh));
    } else if (z == 1) {
      u16 hh = f2bf(v);
      KH[oi] = hh;
      KL[oi] = f2bf(v - bf2f(hh));
    } else {
      Vbf[oi] = f2bf(v);
    }
  }
}

// ---------------------------------------------------------------- MFMA flash attention, key-split
// Fixed-offset softmax; mask words computed inline from adj + static band/depot/diag.
#define CH 64
#define NCH 17
__global__ __launch_bounds__(128) void attn_kernel(
    const u16* __restrict__ QH, const u16* __restrict__ QL,
    const u16* __restrict__ KH, const u16* __restrict__ KL,
    const u16* __restrict__ Vbf, const float* __restrict__ qe_all,
    const unsigned char* __restrict__ buckp, const unsigned long long* __restrict__ adj,
    float* __restrict__ Opart, float* __restrict__ lpart) {
  __shared__ __align__(16) u16 KsHi[2][CH][20];
  __shared__ __align__(16) u16 KsLo[2][CH][20];
  __shared__ __align__(16) u16 Vt[2][DK][68];
  __shared__ __align__(16) u16 Ps[2][16][72];
  __shared__ __align__(16) float qe_s[2][16][36];
  __shared__ u32 maskS[32][6];
  __shared__ unsigned char buckS[2][32][68];

  int qt = blockIdx.x;
  int h = blockIdx.y & 7, b = blockIdx.y >> 3;
  int s = blockIdx.z;
  int c0 = (NCH * s) / NSPLIT, c1 = (NCH * (s + 1)) / NSPLIT;
  int nwm = 2 * (c1 - c0);
  int t = threadIdx.x, lane = t & 63, w = t >> 6;
  int quad = lane >> 4, r16 = lane & 15;
  int i0 = qt * 32;
  int iw = i0 + w * 16;
  int bh = b * NH + h;

  // mask words inline (== old connb output, bit-exact)
  for (int x = t; x < 32 * nwm; x += 128) {
    int rr = x / nwm, ww = x % nwm;
    int gi = i0 + rr; if (gi > NN) gi = NN;
    int W = 2 * c0 + ww;
    u32 v;
    if (gi == 0 || gi == NN) {
      v = 0xffffffffu;
    } else {
      const u32* a32 = (const u32*)(adj + ((size_t)b * N1 + gi) * ADJW);
      v = a32[W];
      int bs = gi & ~127;
      int lo = gi - 11 < bs ? bs : gi - 11;
      int be = bs + 127;
      int hi = gi + 11 > be ? be : gi + 11;
      int aa = lo - 32 * W, bnd = hi - 32 * W;
      if (aa < 0) aa = 0; if (bnd > 31) bnd = 31;
      if (aa <= bnd) v |= (0xffffffffu << aa) & (0xffffffffu >> (31 - bnd));
      if (W == 0) v |= 1u;
      if (W == 32) v |= 1u;
      int dg = gi - 32 * W;
      if (dg >= 0 && dg < 32) v |= 1u << dg;
    }
    if (W == 32) v &= 1u;
    else if (W == 33) v = 0u;
    maskS[rr][ww] = v;
  }
  // qe table: per-row clamped load
  #pragma unroll
  for (int e = 0; e < 2; ++e) {
    int x = lane + e * 64;
    int rr = x >> 3, bk = (x & 7) * 4;
    int gi = iw + rr; if (gi > NN) gi = NN;
    f4 v = *(const f4*)(qe_all + (((size_t)b * NH + h) * N1 + gi) * 32 + bk);
    *(f4*)&qe_s[w][rr][bk] = v;
  }
  bf8 qfrag;
  {
    int gi = iw + r16; if (gi > NN) gi = NN;
    const u16* qsrc = (quad < 2 ? QH : QL) + ((size_t)(b * N1 + gi) * DM + h * DK + (quad & 1) * 8);
    qfrag = *(const bf8*)qsrc;
  }

  ushort4 khr[2], klr[2], vvr[2]; u32 bkr[4];
  auto load_chunk = [&](int c) {
    int j0 = c * CH;
    #pragma unroll
    for (int ii = 0; ii < 2; ++ii) {
      int x = t + ii * 128;
      int key = x >> 2, ds = (x & 3) * 4;
      int jg = j0 + key; if (jg > NN) jg = NN;
      size_t src = (size_t)(b * N1 + jg) * DM + h * DK + ds;
      khr[ii] = *(const ushort4*)(KH + src);
      klr[ii] = *(const ushort4*)(KL + src);
      vvr[ii] = *(const ushort4*)(Vbf + src);
    }
    #pragma unroll
    for (int ii = 0; ii < 4; ++ii) {
      int x = t + ii * 128;
      int rr = x >> 4, c4 = (x & 15) * 4;
      int gi = i0 + rr; if (gi > NN) gi = NN;
      bkr[ii] = *(const u32*)(buckp + ((size_t)b * N1 + gi) * BSTR + j0 + c4);
    }
  };
  auto store_chunk = [&](int pb) {
    #pragma unroll
    for (int ii = 0; ii < 2; ++ii) {
      int x = t + ii * 128;
      int key = x >> 2, ds = (x & 3) * 4;
      *(ushort4*)&KsHi[pb][key][ds] = khr[ii];
      *(ushort4*)&KsLo[pb][key][ds] = klr[ii];
      Vt[pb][ds + 0][key] = vvr[ii].x;
      Vt[pb][ds + 1][key] = vvr[ii].y;
      Vt[pb][ds + 2][key] = vvr[ii].z;
      Vt[pb][ds + 3][key] = vvr[ii].w;
    }
    #pragma unroll
    for (int ii = 0; ii < 4; ++ii) {
      int x = t + ii * 128;
      int rr = x >> 4, c4 = (x & 15) * 4;
      *(u32*)&buckS[pb][rr][c4] = bkr[ii];
    }
  };

  f4 Oacc = {0.f, 0.f, 0.f, 0.f};
  float lrun[4] = {0.f, 0.f, 0.f, 0.f};

  load_chunk(c0);
  store_chunk(0);

  for (int c = c0; c < c1; ++c) {
    int pb = (c - c0) & 1;
    bool pf = (c + 1 < c1);
    if (pf) load_chunk(c + 1);
    __syncthreads();

    f4 S[4];
    #pragma unroll
    for (int tt = 0; tt < 4; ++tt) {
      int key = tt * 16 + r16;
      int off = (quad & 1) * 8;
      bf8 bhv = mk8(*(const ushort4*)&KsHi[pb][key][off], *(const ushort4*)&KsHi[pb][key][off + 4]);
      bf8 blv = mk8(*(const ushort4*)&KsLo[pb][key][off], *(const ushort4*)&KsLo[pb][key][off + 4]);
      f4 z = {0.f, 0.f, 0.f, 0.f};
      z = __builtin_amdgcn_mfma_f32_16x16x32_bf16(qfrag, bhv, z, 0, 0, 0);
      z = __builtin_amdgcn_mfma_f32_16x16x32_bf16(qfrag, blv, z, 0, 0, 0);
      S[tt] = z;
    }

    #pragma unroll
    for (int rg = 0; rg < 4; ++rg) {
      int rowb = w * 16 + quad * 4 + rg;
      u32 mw0 = maskS[rowb][2 * (c - c0)];
      u32 mw1 = maskS[rowb][2 * (c - c0) + 1];
      float ps = 0.f;
      #pragma unroll
      for (int tt = 0; tt < 4; ++tt) {
        u32 mword = (tt & 2) ? mw1 : mw0;
        int bit = (tt & 1) * 16 + r16;
        int bk = buckS[pb][rowb][tt * 16 + r16] & 31;
        float rel = qe_s[w][quad * 4 + rg][bk];
        float sc = S[tt][rg] + rel;
        sc += ((mword >> bit) & 1u) ? 0.f : -1.0e9f;
        float p = __expf(sc - SM_OFF);
        ps += p;
        Ps[w][quad * 4 + rg][tt * 16 + r16] = f2bf(p);
      }
      #pragma unroll
      for (int o = 1; o < 16; o <<= 1) ps += __shfl_xor(ps, o);
      lrun[rg] += ps;
    }
    #pragma unroll
    for (int half = 0; half < 2; ++half) {
      bf8 pa = *(const bf8*)&Ps[w][r16][half * 32 + quad * 8];
      bf8 vb = mk8(*(const ushort4*)&Vt[pb][r16][half * 32 + quad * 8],
                   *(const ushort4*)&Vt[pb][r16][half * 32 + quad * 8 + 4]);
      Oacc = __builtin_amdgcn_mfma_f32_16x16x32_bf16(pa, vb, Oacc, 0, 0, 0);
    }

    if (pf) store_chunk(pb ^ 1);
  }

  #pragma unroll
  for (int rg = 0; rg < 4; ++rg) {
    int gi = i0 + w * 16 + quad * 4 + rg;
    if (gi < N1) {
      size_t base = ((size_t)(bh * NSPLIT + s) * N1 + gi);
      Opart[base * 16 + r16] = Oacc[rg];
      if (r16 == 0) lpart[base] = lrun[rg];
    }
  }
}

// ---------------------------------------------------------------- combine split partials (plain sums)
__global__ void attn_combine_kernel(const float* __restrict__ Opart,
                                    const float* __restrict__ lpart,
                                    u16* __restrict__ CbH, u16* __restrict__ CbL) {
  int idx = blockIdx.x * 256 + threadIdx.x;
  if (idx >= BB * NH * N1) return;
  int q = idx % N1; int bh = idx / N1; int h = bh & 7; int b = bh >> 3;
  float l = 0.f;
  float o[16];
  #pragma unroll
  for (int d = 0; d < DK; ++d) o[d] = 0.f;
  #pragma unroll
  for (int s = 0; s < NSPLIT; ++s) {
    size_t base = (size_t)(bh * NSPLIT + s) * N1 + q;
    l += lpart[base];
    const float* op = Opart + base * 16;
    #pragma unroll
    for (int d = 0; d < DK; ++d) o[d] += op[d];
  }
  float inv = 1.0f / l;
  size_t obase = ((size_t)b * N1 + q) * DM + h * DK;
  #pragma unroll
  for (int d = 0; d < DK; ++d) {
    float v = o[d] * inv;
    u16 hh = f2bf(v);
    CbH[obase + d] = hh;
    CbL[obase + d] = f2bf(v - bf2f(hh));
  }
}

// ---------------------------------------------------------------- instance norm (+pool/g, +split emit)
// oM==nullptr: no emit; oL==nullptr: 2-level (oH,oM as hi/lo); else 3-level (oH,oM,oL)
__global__ void inorm_kernel(float* __restrict__ X, const float* __restrict__ w,
                             const float* __restrict__ b_, float* __restrict__ pool,
                             int do_g, u16* __restrict__ oH, u16* __restrict__ oM,
                             u16* __restrict__ oL) {
  int d = blockIdx.x; int bb = blockIdx.y; int lane = threadIdx.x;
  float g_old = X[((size_t)bb * N1 + NN) * DM + d];
  float s = 0.f;
  for (int n = lane; n < N1; n += 64) s += X[((size_t)bb * N1 + n) * DM + d];
  #pragma unroll
  for (int o = 1; o < 64; o <<= 1) s += __shfl_xor(s, o);
  float mu = s * (1.0f / N1);
  float v = 0.f;
  for (int n = lane; n < N1; n += 64) {
    float tt = X[((size_t)bb * N1 + n) * DM + d] - mu;
    v += tt * tt;
  }
  #pragma unroll
  for (int o = 1; o < 64; o <<= 1) v += __shfl_xor(v, o);
  float var = v * (1.0f / N1);
  float scv = rsqrtf(var + 1e-5f) * w[d];
  float sh = b_[d];
  for (int n = lane; n < N1; n += 64) {
    size_t id = ((size_t)bb * N1 + n) * DM + d;
    float nv = (X[id] - mu) * scv + sh;
    X[id] = nv;
    if (oH) {
      u16 hh = f2bf(nv); float r1 = nv - bf2f(hh);
      u16 mm = f2bf(r1);
      oH[id] = hh;
      oM[id] = mm;
      if (oL) oL[id] = f2bf(r1 - bf2f(mm));
    }
  }
  if (lane == 0) {
    float hmean = ((s - g_old) * (1.0f / NN) - mu) * scv + sh;
    if (pool) pool[bb * DM + d] = hmean;
    if (do_g) X[((size_t)bb * N1 + NN) * DM + d] += hmean;
  }
}

// ---------------------------------------------------------------- final GEMM (inline h+pm split, +out_pm)
__global__ __launch_bounds__(256) void gemm_final_kernel(
    const float* __restrict__ X, const float* __restrict__ pools,
    const u16* __restrict__ PH, const u16* __restrict__ PL,
    const float* __restrict__ bias, float* __restrict__ out, float* __restrict__ out_pm) {
  int t = threadIdx.x;
  if (blockIdx.x == 0 && blockIdx.y == 0) {
    float pmv = (pools[t] + pools[BB * DM + t] + pools[2 * BB * DM + t]) * (1.0f / 3.0f);
    out_pm[t] = pmv;
  }
  int lane = t & 63;
  int quad = lane >> 4, r16 = lane & 15;
  int mt = blockIdx.x * 4 + (t >> 6), nt = blockIdx.y;
  const int M = BB * NN;
  f4 acc = {0.f, 0.f, 0.f, 0.f};
  int m0 = mt * 16;
  int mrow = m0 + r16; if (mrow >= M) mrow = M - 1;
  int mb = mrow / NN, mn = mrow % NN;
  const float* xp = X + ((size_t)mb * N1 + mn) * DM + quad * 8;
  const float* pp = pools + mb * DM + quad * 8;
  const u16* ph = PH + ((size_t)nt * 4 * 64 + lane) * 8;
  const u16* pl = PL + ((size_t)nt * 4 * 64 + lane) * 8;
  #pragma unroll
  for (int ks = 0; ks < 4; ++ks) {
    bf8 aH, aL;
    #pragma unroll
    for (int half = 0; half < 2; ++half) {
      float4 xv = *(const float4*)(xp + ks * 32 + half * 4);
      float4 p0 = *(const float4*)(pp + ks * 32 + half * 4);
      float4 p1 = *(const float4*)(pp + BB * DM + ks * 32 + half * 4);
      float4 p2 = *(const float4*)(pp + 2 * BB * DM + ks * 32 + half * 4);
      float av[4] = {xv.x + (p0.x + p1.x + p2.x) * (1.0f / 3.0f),
                     xv.y + (p0.y + p1.y + p2.y) * (1.0f / 3.0f),
                     xv.z + (p0.z + p1.z + p2.z) * (1.0f / 3.0f),
                     xv.w + (p0.w + p1.w + p2.w) * (1.0f / 3.0f)};
      #pragma unroll
      for (int q = 0; q < 4; ++q) {
        u16 hh = f2bf(av[q]);
        aH[half * 4 + q] = (short)hh;
        aL[half * 4 + q] = (short)f2bf(av[q] - bf2f(hh));
      }
    }
    bf8 bH = *(const bf8*)(ph + (size_t)ks * 512);
    bf8 bL = *(const bf8*)(pl + (size_t)ks * 512);
    acc = __builtin_amdgcn_mfma_f32_16x16x32_bf16(aH, bH, acc, 0, 0, 0);
    acc = __builtin_amdgcn_mfma_f32_16x16x32_bf16(aH, bL, acc, 0, 0, 0);
    acc = __builtin_amdgcn_mfma_f32_16x16x32_bf16(aL, bH, acc, 0, 0, 0);
  }
  int n = nt * 16 + r16;
  #pragma unroll
  for (int reg = 0; reg < 4; ++reg) {
    int m = m0 + quad * 4 + reg;
    if (m < M) out[(size_t)m * DM + n] = acc[reg] + bias[n];
  }
}

// ================================================================ launch
extern "C" void kernel_launch(void* const* d_in, const int* in_sizes, int n_in,
                              void* d_out, int out_size, void* d_ws, size_t ws_size,
                              hipStream_t stream) {
  const float* coords = (const float*)d_in[0];
  const float* inW    = (const float*)d_in[1];
  const float* inb    = (const float*)d_in[2];
  const float* gnode  = (const float*)d_in[3];
  const float* Wq     = (const float*)d_in[4];
  const float* Wk     = (const float*)d_in[5];
  const float* Wv     = (const float*)d_in[6];
  const float* Wo     = (const float*)d_in[7];
  const float* emb    = (const float*)d_in[8];
  const float* W1     = (const float*)d_in[9];
  const float* b1     = (const float*)d_in[10];
  const float* W2     = (const float*)d_in[11];
  const float* b2     = (const float*)d_in[12];
  const float* n1w    = (const float*)d_in[13];
  const float* n1b    = (const float*)d_in[14];
  const float* n2w    = (const float*)d_in[15];
  const float* n2b    = (const float*)d_in[16];
  const float* outW   = (const float*)d_in[17];
  const float* outb   = (const float*)d_in[18];
  float* out = (float*)d_out;

  char* wsp = (char*)d_ws;
  size_t off = 0;
  auto alloc = [&](size_t bytes) -> void* {
    off = (off + 255) & ~(size_t)255;
    void* p = wsp + off;
    off += bytes;
    return p;
  };
  const size_t XB = (size_t)BB * N1 * DM * 4;       // fp32 activation buffer
  const size_t HB = (size_t)BB * N1 * DM * 2;       // u16 half buffer
  float* X0   = (float*)alloc(XB);
  float* X1   = (float*)alloc(XB);
  float* Yb   = (float*)alloc(XB);
  u16* XH = (u16*)alloc(HB); u16* XM = (u16*)alloc(HB); u16* XL = (u16*)alloc(HB);
  u16* QH = (u16*)alloc(HB); u16* QL = (u16*)alloc(HB);
  u16* KH = (u16*)alloc(HB); u16* KL = (u16*)alloc(HB);
  u16* Vbf = (u16*)alloc(HB);
  u16* CbH = (u16*)alloc(HB); u16* CbL = (u16*)alloc(HB);
  u16* YbH = (u16*)alloc(HB); u16* YbL = (u16*)alloc(HB);
  u16* FbH = (u16*)alloc((size_t)BB * N1 * DFF * 2);
  u16* FbL = (u16*)alloc((size_t)BB * N1 * DFF * 2);
  unsigned char* buckp = (unsigned char*)alloc((size_t)BB * N1 * BSTR);
  unsigned long long* adj = (unsigned long long*)alloc((size_t)BB * N1 * ADJW * 8);
  float* pools = (float*)alloc((size_t)NLAYERS * BB * DM * 4);
  float* qe_all = (float*)alloc((size_t)BB * NH * N1 * 32 * 4);
  float* lpart = (float*)alloc((size_t)BB * NH * NSPLIT * N1 * 4);
  u16* PH = (u16*)alloc((size_t)PW_TOT * 2);
  u16* PL = (u16*)alloc((size_t)PW_TOT * 2);
  float* scratch8 = (float*)alloc((size_t)BB * NH * NSPLIT * N1 * 16 * 4);  // >= d2 size

  float* d2 = scratch8;                    // gram keys (8.39 MB), dead before attn
  float* Opart = scratch8;                 // attn partials (8.40 MB)

  init_kernel<<<PBLK + EBLK + BBLK, 256, 0, stream>>>(
      coords, inW, inb, gnode, Wq, Wk, Wv, Wo, W1, W2, outW, emb,
      PH, PL, X0, XH, XM, XL, buckp);

  float* Xin = X0; float* Xout = X1;
  const int M = BB * N1;
  const int GX = 33;     // ceil(129 m-tiles / 4 waves)
  for (int l = 0; l < NLAYERS; ++l) {
    gram_kernel<<<dim3(32, 16, BB), 256, 0, stream>>>(XH, XM, XL, adj, d2);
    knnsel_kernel<<<BB * NN / 4, 256, 0, stream>>>(d2, adj);

    gemm_qkv_kernel<<<dim3(GX, 40), 256, 0, stream>>>(
        XH, XM, PH, PL,
        (size_t)PWQ_OFF + (size_t)l * DM * DM,
        (size_t)PWK_OFF + (size_t)l * DM * DM,
        (size_t)PWV_OFF + (size_t)l * DM * DM,
        (size_t)PWQE_OFF + (size_t)l * 256 * DM,
        QH, QL, KH, KL, Vbf, qe_all, M);

    attn_kernel<<<dim3(33, NH * BB, NSPLIT), 128, 0, stream>>>(
        QH, QL, KH, KL, Vbf, qe_all, buckp, adj, Opart, lpart);
    attn_combine_kernel<<<(BB * NH * N1 + 255) / 256, 256, 0, stream>>>(
        Opart, lpart, CbH, CbL);

    gemm_kernel<<<dim3(GX, 8), 256, 0, stream>>>(
        CbH, CbL, PH + PWO_OFF + (size_t)l * DM * DM, PL + PWO_OFF + (size_t)l * DM * DM,
        nullptr, Xin, Yb, nullptr, nullptr, M, DM, DM, 0);
    inorm_kernel<<<dim3(DM, BB), 64, 0, stream>>>(Yb, n1w + l * DM, n1b + l * DM,
                                                  nullptr, 0, YbH, YbL, nullptr);

    gemm_kernel<<<dim3(GX, 32), 256, 0, stream>>>(
        YbH, YbL, PH + PW1_OFF + (size_t)l * DFF * DM, PL + PW1_OFF + (size_t)l * DFF * DM,
        b1 + l * DFF, nullptr, nullptr, FbH, FbL, M, DM, DFF, 1);
    gemm_kernel<<<dim3(GX, 8), 256, 0, stream>>>(
        FbH, FbL, PH + PW2_OFF + (size_t)l * DM * DFF, PL + PW2_OFF + (size_t)l * DM * DFF,
        b2 + l * DM, Yb, Xout, nullptr, nullptr, M, DFF, DM, 0);
    // inorm2 emits next layer's 3-level X splits inline
    inorm_kernel<<<dim3(DM, BB), 64, 0, stream>>>(Xout, n2w + l * DM, n2b + l * DM,
                                                  pools + (size_t)l * BB * DM, 1,
                                                  XH, XM, XL);

    float* t2 = Xin; Xin = Xout; Xout = t2;
  }

  gemm_final_kernel<<<dim3(32, 8), 256, 0, stream>>>(
      Xin, pools, PH + PWOUT_OFF, PL + PWOUT_OFF, outb, out, out + (size_t)BB * NN * DM);
}

// Round 15
// 505.422 us; speedup vs baseline: 1.0487x; 1.0487x over previous
//
#include <hip/hip_runtime.h>

#define BB 2
#define NN 1024
#define N1 1025
#define DM 128
#define NH 8
#define DK 16
#define DFF 512
#define NBUK 32
#define NLAYERS 3
#define KNN_K 10
#define ADJW 17          // 1025 bits -> 17 u64 words per row
#define BSTR 1088        // padded bucket row stride (bytes)
#define NSPLIT 8
#define BIGF 3.0e38f
#define SM_OFF 24.0f     // fixed softmax exponent offset (|s| bounded << 24+88)

// prepacked-weight element offsets (see init_kernel prepack branch)
#define PWQ_OFF 0
#define PWK_OFF 49152
#define PWV_OFF 98304
#define PWO_OFF 147456
#define PW1_OFF 196608
#define PW2_OFF 393216
#define PWOUT_OFF 589824
#define PWQE_OFF 606208
#define PW_TOT 704512

// init kernel block ranges
#define PBLK 344         // ceil(88064/256) prepack
#define NBNODE 1024      // embed node blocks
#define EBLK (NBNODE + BB)
#define BBLK 8713        // ceil(BB*N1*BSTR/256) bucket

typedef __attribute__((ext_vector_type(8))) short bf8;
typedef __attribute__((ext_vector_type(4))) float f4;
typedef unsigned short u16;
typedef unsigned int u32;

__device__ __forceinline__ u16 f2bf(float x) {
  unsigned u = __float_as_uint(x);
  return (u16)((u + 0x7fff + ((u >> 16) & 1)) >> 16);   // RNE
}
__device__ __forceinline__ float bf2f(u16 u) {
  return __uint_as_float(((unsigned)u) << 16);
}
__device__ __forceinline__ bf8 mk8(ushort4 a, ushort4 b) {
  bf8 r;
  r[0] = (short)a.x; r[1] = (short)a.y; r[2] = (short)a.z; r[3] = (short)a.w;
  r[4] = (short)b.x; r[5] = (short)b.y; r[6] = (short)b.z; r[7] = (short)b.w;
  return r;
}

// ---------------------------------------------------------------- init: prepack + embed(+splits) + bucket
__global__ __launch_bounds__(256) void init_kernel(
    const float* __restrict__ coords, const float* __restrict__ inW,
    const float* __restrict__ inb, const float* __restrict__ gnode,
    const float* __restrict__ Wq, const float* __restrict__ Wk,
    const float* __restrict__ Wv, const float* __restrict__ Wo,
    const float* __restrict__ W1, const float* __restrict__ W2,
    const float* __restrict__ oW, const float* __restrict__ emb,
    u16* __restrict__ PH, u16* __restrict__ PL,
    float* __restrict__ X, u16* __restrict__ XH, u16* __restrict__ XM,
    u16* __restrict__ XL, unsigned char* __restrict__ buckp) {
  int blk = blockIdx.x;
  if (blk < PBLK) {
    // ---------------- prepack (+inline wqe composite)
    int idx = blk * 256 + threadIdx.x;
    if (idx >= 88064) return;
    if (idx >= 75776) {
      int rel = idx - 75776;
      int lane = rel & 63, g = rel >> 6;
      int ks = g & 3, nt = g >> 2;
      int n = nt * 16 + (lane & 15);
      int k = ks * 32 + (lane >> 4) * 8;
      int l = n >> 8; int c = n & 255; int h = c >> 5, bk = c & 31;
      const float* e = emb + ((size_t)l * NBUK + bk) * DM + h * DK;
      const float* wq = Wq + ((size_t)l * DM + h * DK) * DM;
      u16* ph = PH + (size_t)idx * 8;
      u16* pl = PL + (size_t)idx * 8;
      #pragma unroll
      for (int q = 0; q < 8; ++q) {
        float s = 0.f;
        #pragma unroll
        for (int d = 0; d < DK; ++d) s += e[d] * wq[(size_t)d * DM + k + q];
        u16 hh = f2bf(s);
        ph[q] = hh;
        pl[q] = f2bf(s - bf2f(hh));
      }
      return;
    }
    const float* W; int rel, Kdim;
    if (idx < 24576) {
      int seg = idx / 6144; rel = idx % 6144; Kdim = 128;
      W = seg == 0 ? Wq : seg == 1 ? Wk : seg == 2 ? Wv : Wo;
    } else if (idx < 49152) { rel = idx - 24576; Kdim = 128; W = W1; }
    else if (idx < 73728)   { rel = idx - 49152; Kdim = 512; W = W2; }
    else                    { rel = idx - 73728; Kdim = 128; W = oW; }
    int lane = rel & 63;
    int g = rel >> 6;
    int ksteps = Kdim >> 5;
    int ks = g % ksteps, nt = g / ksteps;
    int n = nt * 16 + (lane & 15);
    int k = ks * 32 + (lane >> 4) * 8;
    const float* p = W + (size_t)n * Kdim + k;
    u16* ph = PH + (size_t)idx * 8;
    u16* pl = PL + (size_t)idx * 8;
    #pragma unroll
    for (int q = 0; q < 8; ++q) {
      float x = p[q];
      u16 hh = f2bf(x);
      ph[q] = hh;
      pl[q] = f2bf(x - bf2f(hh));
    }
    return;
  }
  if (blk < PBLK + EBLK) {
    // ---------------- embed (+g row), emitting 3-level splits
    int eb = blk - PBLK;
    if (eb >= NBNODE) {
      int b = eb - NBNODE;
      int t = threadIdx.x;
      if (t >= 128) return;
      int lane = t & 63;
      float sx = 0.f, sy = 0.f;
      for (int n = lane; n < NN; n += 64) {
        float2 c = *(const float2*)(coords + (size_t)(b * NN + n) * 2);
        sx += c.x; sy += c.y;
      }
      #pragma unroll
      for (int o = 1; o < 64; o <<= 1) { sx += __shfl_xor(sx, o); sy += __shfl_xor(sy, o); }
      float mx = sx * (1.0f / NN), my = sy * (1.0f / NN);
      int d = t;
      size_t id = ((size_t)b * N1 + NN) * DM + d;
      float v = gnode[d] + inb[d] + mx * inW[d * 2 + 0] + my * inW[d * 2 + 1];
      X[id] = v;
      u16 hh = f2bf(v); float r1 = v - bf2f(hh);
      u16 mm = f2bf(r1);
      XH[id] = hh; XM[id] = mm; XL[id] = f2bf(r1 - bf2f(mm));
      return;
    }
    int idx = eb * 256 + threadIdx.x;
    if (idx >= BB * NN * DM) return;
    int d = idx % DM; int r = idx / DM; int n = r % NN; int b = r / NN;
    float cx = coords[(b * NN + n) * 2 + 0], cy = coords[(b * NN + n) * 2 + 1];
    size_t id = ((size_t)b * N1 + n) * DM + d;
    float v = cx * inW[d * 2 + 0] + cy * inW[d * 2 + 1] + inb[d];
    X[id] = v;
    u16 hh = f2bf(v); float r1 = v - bf2f(hh);
    u16 mm = f2bf(r1);
    XH[id] = hh; XM[id] = mm; XL[id] = f2bf(r1 - bf2f(mm));
    return;
  }
  // ---------------- bucket (padded rows)
  int idx = (blk - PBLK - EBLK) * 256 + threadIdx.x;
  if (idx >= BB * N1 * BSTR) return;
  int j = idx % BSTR; int r = idx / BSTR; int i = r % N1; int b = r / N1;
  unsigned char v = 0;
  if (j < N1) {
    float xi = 0.f, yi = 0.f, xj = 0.f, yj = 0.f;
    if (i < NN) { xi = coords[(b * NN + i) * 2]; yi = coords[(b * NN + i) * 2 + 1]; }
    if (j < NN) { xj = coords[(b * NN + j) * 2]; yj = coords[(b * NN + j) * 2 + 1]; }
    float dx = xi - xj, dy = yi - yj;
    float dist = sqrtf(dx * dx + dy * dy);
    int bu = (int)(dist * 32.0f);
    bu = bu < 0 ? 0 : (bu > 31 ? 31 : bu);
    v = (unsigned char)bu;
  }
  buckp[idx] = v;
}

// ---------------------------------------------------------------- exact MFMA gram (+adj zero)
// kNN key = sj - 2*dot (si dropped: row-constant, rank-equivalent). sj computed in
// parallel (64 rows x 4 threads, vector LDS reads, exact H+M+L reconstruction).
__global__ __launch_bounds__(256) void gram_kernel(
    const u16* __restrict__ XH, const u16* __restrict__ XM, const u16* __restrict__ XL,
    unsigned long long* __restrict__ adj, float* __restrict__ d2) {
  __shared__ __align__(16) u16 AsH[32][72];
  __shared__ __align__(16) u16 AsM[32][72];
  __shared__ __align__(16) u16 AsL[32][72];
  __shared__ __align__(16) u16 BsH[64][72];
  __shared__ __align__(16) u16 BsM[64][72];
  __shared__ __align__(16) u16 BsL[64][72];
  __shared__ float sqS[64];               // B-row squared norms
  int b = blockIdx.z;
  int m0 = blockIdx.x * 32, n0 = blockIdx.y * 64;
  size_t boff = (size_t)b * N1;
  int t = threadIdx.x;

  // zero adjacency (1024 blocks x 256 thr covers 34850 u64 words)
  {
    int flat = blockIdx.x + 32 * (blockIdx.y + 16 * blockIdx.z);
    int tid = flat * 256 + t;
    if (tid < BB * N1 * ADJW) adj[tid] = 0ull;
  }

  int lane = t & 63, w = t >> 6;
  int wm = (w >> 1) * 16, wn = (w & 1) * 32;
  int quad = lane >> 4, r16 = lane & 15;

  f4 acc0 = {0.f, 0.f, 0.f, 0.f}, acc1 = {0.f, 0.f, 0.f, 0.f};
  int ar = t >> 3, as_ = (t & 7) * 8;     // A: 32 rows x 8 segs of 8
  int br = t >> 2, bs_ = (t & 3) * 16;    // B: 64 rows x 4 segs of 16
  int sqrow = t >> 2, sqk = (t & 3) * 16; // sq: 64 rows x 4 threads x 16 elems
  float mySq = 0.f;

  for (int k0 = 0; k0 < DM; k0 += 64) {
    {
      size_t src = (boff + m0 + ar) * DM + k0 + as_;
      *(bf8*)&AsH[ar][as_] = *(const bf8*)(XH + src);
      *(bf8*)&AsM[ar][as_] = *(const bf8*)(XM + src);
      *(bf8*)&AsL[ar][as_] = *(const bf8*)(XL + src);
    }
    {
      size_t src = (boff + n0 + br) * DM + k0 + bs_;
      *(bf8*)&BsH[br][bs_] = *(const bf8*)(XH + src);
      *(bf8*)&BsH[br][bs_ + 8] = *(const bf8*)(XH + src + 8);
      *(bf8*)&BsM[br][bs_] = *(const bf8*)(XM + src);
      *(bf8*)&BsM[br][bs_ + 8] = *(const bf8*)(XM + src + 8);
      *(bf8*)&BsL[br][bs_] = *(const bf8*)(XL + src);
      *(bf8*)&BsL[br][bs_ + 8] = *(const bf8*)(XL + src + 8);
    }
    __syncthreads();
    #pragma unroll
    for (int ks = 0; ks < 64; ks += 16) {
      int seg = (quad & 1) * 8;
      bf8 aHM = *(const bf8*)((quad < 2) ? &AsH[wm + r16][ks + seg] : &AsM[wm + r16][ks + seg]);
      bf8 aHL = *(const bf8*)((quad < 2) ? &AsH[wm + r16][ks + seg] : &AsL[wm + r16][ks + seg]);
      #pragma unroll
      for (int tt = 0; tt < 2; ++tt) {
        int nr = wn + tt * 16 + r16;
        bf8 bH = *(const bf8*)&BsH[nr][ks + seg];
        bf8 bM = *(const bf8*)&BsM[nr][ks + seg];
        bf8 b3 = *(const bf8*)((quad < 2) ? &BsL[nr][ks + seg] : &BsH[nr][ks + seg]);
        f4& a = tt ? acc1 : acc0;
        a = __builtin_amdgcn_mfma_f32_16x16x32_bf16(aHM, bH, a, 0, 0, 0);  // HH' + MH'
        a = __builtin_amdgcn_mfma_f32_16x16x32_bf16(aHM, bM, a, 0, 0, 0);  // HM' + MM'
        a = __builtin_amdgcn_mfma_f32_16x16x32_bf16(aHL, b3, a, 0, 0, 0);  // HL' + LH'
      }
    }
    // parallel B-row sq: vector LDS reads, exact x = H+M+L
    #pragma unroll
    for (int half = 0; half < 2; ++half) {
      bf8 hv = *(const bf8*)&BsH[sqrow][sqk + half * 8];
      bf8 mv = *(const bf8*)&BsM[sqrow][sqk + half * 8];
      bf8 lv = *(const bf8*)&BsL[sqrow][sqk + half * 8];
      #pragma unroll
      for (int q = 0; q < 8; ++q) {
        float x = (bf2f((u16)hv[q]) + bf2f((u16)mv[q])) + bf2f((u16)lv[q]);
        mySq += x * x;
      }
    }
    __syncthreads();
  }
  // reduce 4 partials per row (threads row*4+jj adjacent in wave)
  mySq += __shfl_xor(mySq, 1);
  mySq += __shfl_xor(mySq, 2);
  if ((t & 3) == 0) sqS[sqrow] = mySq;
  __syncthreads();

  #pragma unroll
  for (int tt = 0; tt < 2; ++tt) {
    f4 a = tt ? acc1 : acc0;
    int nl = wn + tt * 16 + r16;
    int n = n0 + nl;
    float sj = sqS[nl];
    #pragma unroll
    for (int reg = 0; reg < 4; ++reg) {
      int m = m0 + wm + quad * 4 + reg;
      float v = (m == n) ? BIGF : (sj - 2.f * a[reg]);
      d2[((size_t)b * NN + m) * NN + n] = v;
    }
  }
}

// ---------------------------------------------------------------- top-10 select -> adjacency bits
__global__ __launch_bounds__(256) void knnsel_kernel(const float* __restrict__ d2,
                                                     unsigned long long* __restrict__ adj) {
  __shared__ float dd[4][NN];
  int blk = blockIdx.x;
  int b = blk / (NN / 4);
  int i0 = (blk % (NN / 4)) * 4;
  int t = threadIdx.x, lane = t & 63, w = t >> 6;

  const float4* src = (const float4*)(d2 + ((size_t)b * NN + i0) * NN);
  float4* dst = (float4*)&dd[0][0];
  #pragma unroll
  for (int x = 0; x < 4; ++x) dst[t + x * 256] = src[t + x * 256];
  __syncthreads();

  int i = i0 + w;
  for (int it = 0; it < KNN_K; ++it) {
    float bv = BIGF; int bi = 0x3fffffff;
    for (int j = lane; j < NN; j += 64) {
      float v = dd[w][j];
      if (v < bv) { bv = v; bi = j; }
    }
    #pragma unroll
    for (int o = 1; o < 64; o <<= 1) {
      float ov = __shfl_xor(bv, o); int oi = __shfl_xor(bi, o);
      if (ov < bv || (ov == bv && oi < bi)) { bv = ov; bi = oi; }
    }
    if (lane == 0) {
      dd[w][bi] = BIGF;
      atomicOr(&adj[((size_t)b * N1 + i) * ADJW + (bi >> 6)], 1ull << (bi & 63));
      atomicOr(&adj[((size_t)b * N1 + bi) * ADJW + (i >> 6)], 1ull << (i & 63));
    }
  }
}

// ---------------------------------------------------------------- direct-fragment GEMM (16x16/wave)
__device__ __forceinline__ void gemm_dev16(
    const u16* __restrict__ AH, const u16* __restrict__ AL,
    const u16* __restrict__ PH, const u16* __restrict__ PL,
    const float* __restrict__ bias, const float* __restrict__ res,
    float* __restrict__ outF, u16* __restrict__ outH, u16* __restrict__ outL,
    int M, int Kdim, int Nout, int relu, int mt, int nt) {
  int lane = threadIdx.x & 63;
  int quad = lane >> 4, r16 = lane & 15;
  int ksteps = Kdim >> 5;
  f4 acc = {0.f, 0.f, 0.f, 0.f};

  int m0 = mt * 16;
  int mrow = m0 + r16; if (mrow >= M) mrow = M - 1;   // clamp; result discarded
  const u16* aph = AH + (size_t)mrow * Kdim + quad * 8;
  const u16* apl = AL + (size_t)mrow * Kdim + quad * 8;
  const u16* ph = PH + ((size_t)nt * ksteps * 64 + lane) * 8;
  const u16* pl = PL + ((size_t)nt * ksteps * 64 + lane) * 8;

  #pragma unroll 4
  for (int ks = 0; ks < ksteps; ++ks) {
    bf8 aH = *(const bf8*)(aph);
    bf8 aL = *(const bf8*)(apl);
    aph += 32; apl += 32;
    bf8 bH = *(const bf8*)(ph + (size_t)ks * 512);
    bf8 bL = *(const bf8*)(pl + (size_t)ks * 512);
    acc = __builtin_amdgcn_mfma_f32_16x16x32_bf16(aH, bH, acc, 0, 0, 0);
    acc = __builtin_amdgcn_mfma_f32_16x16x32_bf16(aH, bL, acc, 0, 0, 0);
    acc = __builtin_amdgcn_mfma_f32_16x16x32_bf16(aL, bH, acc, 0, 0, 0);
  }

  if (m0 >= M) return;
  int n = nt * 16 + r16;
  #pragma unroll
  for (int reg = 0; reg < 4; ++reg) {
    int m = m0 + quad * 4 + reg;    // C layout: col=lane&15, row=quad*4+reg
    if (m < M) {
      float v = acc[reg];
      if (bias) v += bias[n];
      if (relu) v = fmaxf(v, 0.f);
      if (res) v += res[(size_t)m * Nout + n];
      size_t oi = (size_t)m * Nout + n;
      if (outF) outF[oi] = v;
      if (outH) {
        u16 hh = f2bf(v);
        outH[oi] = hh;
        outL[oi] = f2bf(v - bf2f(hh));
      }
    }
  }
}

__global__ __launch_bounds__(256) void gemm_kernel(
    const u16* __restrict__ AH, const u16* __restrict__ AL,
    const u16* __restrict__ PH, const u16* __restrict__ PL,
    const float* __restrict__ bias, const float* __restrict__ res,
    float* __restrict__ outF, u16* __restrict__ outH, u16* __restrict__ outL,
    int M, int Kdim, int Nout, int relu) {
  gemm_dev16(AH, AL, PH, PL, bias, res, outF, outH, outL, M, Kdim, Nout, relu,
             blockIdx.x * 4 + (threadIdx.x >> 6), blockIdx.y);
}

// QKV+QE flattened grid: y<8 Q (0.25-scaled split), <16 K (split), <24 V (bf16), <40 qe (fp32)
__global__ __launch_bounds__(256) void gemm_qkv_kernel(
    const u16* __restrict__ AH, const u16* __restrict__ AL,
    const u16* __restrict__ Pbase_H, const u16* __restrict__ Pbase_L,
    size_t offQ, size_t offK, size_t offV, size_t offE,
    u16* __restrict__ QH, u16* __restrict__ QL,
    u16* __restrict__ KH, u16* __restrict__ KL, u16* __restrict__ Vbf,
    float* __restrict__ qe_all, int M) {
  int y = blockIdx.y;
  int z, nt;
  if (y < 8) { z = 0; nt = y; }
  else if (y < 16) { z = 1; nt = y - 8; }
  else if (y < 24) { z = 2; nt = y - 16; }
  else { z = 3; nt = y - 24; }
  size_t woff = z == 0 ? offQ : (z == 1 ? offK : (z == 2 ? offV : offE));
  const u16* PH = Pbase_H + woff;
  const u16* PL = Pbase_L + woff;
  int lane = threadIdx.x & 63;
  int quad = lane >> 4, r16 = lane & 15;
  int mt = blockIdx.x * 4 + (threadIdx.x >> 6);
  f4 acc = {0.f, 0.f, 0.f, 0.f};
  int m0 = mt * 16;
  int mrow = m0 + r16; if (mrow >= M) mrow = M - 1;
  const u16* aph = AH + (size_t)mrow * DM + quad * 8;
  const u16* apl = AL + (size_t)mrow * DM + quad * 8;
  const u16* ph = PH + ((size_t)nt * 4 * 64 + lane) * 8;
  const u16* pl = PL + ((size_t)nt * 4 * 64 + lane) * 8;
  #pragma unroll
  for (int ks = 0; ks < 4; ++ks) {
    bf8 aH = *(const bf8*)(aph);
    bf8 aL = *(const bf8*)(apl);
    aph += 32; apl += 32;
    bf8 bH = *(const bf8*)(ph + (size_t)ks * 512);
    bf8 bL = *(const bf8*)(pl + (size_t)ks * 512);
    acc = __builtin_amdgcn_mfma_f32_16x16x32_bf16(aH, bH, acc, 0, 0, 0);
    acc = __builtin_amdgcn_mfma_f32_16x16x32_bf16(aH, bL, acc, 0, 0, 0);
    acc = __builtin_amdgcn_mfma_f32_16x16x32_bf16(aL, bH, acc, 0, 0, 0);
  }
  if (m0 >= M) return;
  int n = nt * 16 + r16;
  #pragma unroll
  for (int reg = 0; reg < 4; ++reg) {
    int m = m0 + quad * 4 + reg;
    if (m >= M) continue;
    float v = acc[reg];
    if (z == 3) {
      int b = m / N1, nr = m % N1;
      int h = n >> 5, bk = n & 31;
      qe_all[(((size_t)b * NH + h) * N1 + nr) * 32 + bk] = v;
      continue;
    }
    size_t oi = (size_t)m * DM + n;
    if (z == 0) {
      float sv = v * 0.25f;
      u16 hh = f2bf(sv);
      QH[oi] = hh;
      QL[oi] = f2bf(sv - bf2f(hh));
    } else if (z == 1) {
      u16 hh = f2bf(v);
      KH[oi] = hh;
      KL[oi] = f2bf(v - bf2f(hh));
    } else {
      Vbf[oi] = f2bf(v);
    }
  }
}

// ---------------------------------------------------------------- MFMA flash attention, key-split
// Fixed-offset softmax; mask words computed inline from adj + static band/depot/diag.
#define CH 64
#define NCH 17
__global__ __launch_bounds__(128) void attn_kernel(
    const u16* __restrict__ QH, const u16* __restrict__ QL,
    const u16* __restrict__ KH, const u16* __restrict__ KL,
    const u16* __restrict__ Vbf, const float* __restrict__ qe_all,
    const unsigned char* __restrict__ buckp, const unsigned long long* __restrict__ adj,
    float* __restrict__ Opart, float* __restrict__ lpart) {
  __shared__ __align__(16) u16 KsHi[2][CH][20];
  __shared__ __align__(16) u16 KsLo[2][CH][20];
  __shared__ __align__(16) u16 Vt[2][DK][68];
  __shared__ __align__(16) u16 Ps[2][16][72];
  __shared__ __align__(16) float qe_s[2][16][36];
  __shared__ u32 maskS[32][6];
  __shared__ unsigned char buckS[2][32][68];

  int qt = blockIdx.x;
  int h = blockIdx.y & 7, b = blockIdx.y >> 3;
  int s = blockIdx.z;
  int c0 = (NCH * s) / NSPLIT, c1 = (NCH * (s + 1)) / NSPLIT;
  int nwm = 2 * (c1 - c0);
  int t = threadIdx.x, lane = t & 63, w = t >> 6;
  int quad = lane >> 4, r16 = lane & 15;
  int i0 = qt * 32;
  int iw = i0 + w * 16;
  int bh = b * NH + h;

  // mask words inline (== old connb output, bit-exact)
  for (int x = t; x < 32 * nwm; x += 128) {
    int rr = x / nwm, ww = x % nwm;
    int gi = i0 + rr; if (gi > NN) gi = NN;
    int W = 2 * c0 + ww;
    u32 v;
    if (gi == 0 || gi == NN) {
      v = 0xffffffffu;
    } else {
      const u32* a32 = (const u32*)(adj + ((size_t)b * N1 + gi) * ADJW);
      v = a32[W];
      int bs = gi & ~127;
      int lo = gi - 11 < bs ? bs : gi - 11;
      int be = bs + 127;
      int hi = gi + 11 > be ? be : gi + 11;
      int aa = lo - 32 * W, bnd = hi - 32 * W;
      if (aa < 0) aa = 0; if (bnd > 31) bnd = 31;
      if (aa <= bnd) v |= (0xffffffffu << aa) & (0xffffffffu >> (31 - bnd));
      if (W == 0) v |= 1u;
      if (W == 32) v |= 1u;
      int dg = gi - 32 * W;
      if (dg >= 0 && dg < 32) v |= 1u << dg;
    }
    if (W == 32) v &= 1u;
    else if (W == 33) v = 0u;
    maskS[rr][ww] = v;
  }
  // qe table: per-row clamped load
  #pragma unroll
  for (int e = 0; e < 2; ++e) {
    int x = lane + e * 64;
    int rr = x >> 3, bk = (x & 7) * 4;
    int gi = iw + rr; if (gi > NN) gi = NN;
    f4 v = *(const f4*)(qe_all + (((size_t)b * NH + h) * N1 + gi) * 32 + bk);
    *(f4*)&qe_s[w][rr][bk] = v;
  }
  bf8 qfrag;
  {
    int gi = iw + r16; if (gi > NN) gi = NN;
    const u16* qsrc = (quad < 2 ? QH : QL) + ((size_t)(b * N1 + gi) * DM + h * DK + (quad & 1) * 8);
    qfrag = *(const bf8*)qsrc;
  }

  ushort4 khr[2], klr[2], vvr[2]; u32 bkr[4];
  auto load_chunk = [&](int c) {
    int j0 = c * CH;
    #pragma unroll
    for (int ii = 0; ii < 2; ++ii) {
      int x = t + ii * 128;
      int key = x >> 2, ds = (x & 3) * 4;
      int jg = j0 + key; if (jg > NN) jg = NN;
      size_t src = (size_t)(b * N1 + jg) * DM + h * DK + ds;
      khr[ii] = *(const ushort4*)(KH + src);
      klr[ii] = *(const ushort4*)(KL + src);
      vvr[ii] = *(const ushort4*)(Vbf + src);
    }
    #pragma unroll
    for (int ii = 0; ii < 4; ++ii) {
      int x = t + ii * 128;
      int rr = x >> 4, c4 = (x & 15) * 4;
      int gi = i0 + rr; if (gi > NN) gi = NN;
      bkr[ii] = *(const u32*)(buckp + ((size_t)b * N1 + gi) * BSTR + j0 + c4);
    }
  };
  auto store_chunk = [&](int pb) {
    #pragma unroll
    for (int ii = 0; ii < 2; ++ii) {
      int x = t + ii * 128;
      int key = x >> 2, ds = (x & 3) * 4;
      *(ushort4*)&KsHi[pb][key][ds] = khr[ii];
      *(ushort4*)&KsLo[pb][key][ds] = klr[ii];
      Vt[pb][ds + 0][key] = vvr[ii].x;
      Vt[pb][ds + 1][key] = vvr[ii].y;
      Vt[pb][ds + 2][key] = vvr[ii].z;
      Vt[pb][ds + 3][key] = vvr[ii].w;
    }
    #pragma unroll
    for (int ii = 0; ii < 4; ++ii) {
      int x = t + ii * 128;
      int rr = x >> 4, c4 = (x & 15) * 4;
      *(u32*)&buckS[pb][rr][c4] = bkr[ii];
    }
  };

  f4 Oacc = {0.f, 0.f, 0.f, 0.f};
  float lrun[4] = {0.f, 0.f, 0.f, 0.f};

  load_chunk(c0);
  store_chunk(0);

  for (int c = c0; c < c1; ++c) {
    int pb = (c - c0) & 1;
    bool pf = (c + 1 < c1);
    if (pf) load_chunk(c + 1);
    __syncthreads();

    f4 S[4];
    #pragma unroll
    for (int tt = 0; tt < 4; ++tt) {
      int key = tt * 16 + r16;
      int off = (quad & 1) * 8;
      bf8 bhv = mk8(*(const ushort4*)&KsHi[pb][key][off], *(const ushort4*)&KsHi[pb][key][off + 4]);
      bf8 blv = mk8(*(const ushort4*)&KsLo[pb][key][off], *(const ushort4*)&KsLo[pb][key][off + 4]);
      f4 z = {0.f, 0.f, 0.f, 0.f};
      z = __builtin_amdgcn_mfma_f32_16x16x32_bf16(qfrag, bhv, z, 0, 0, 0);
      z = __builtin_amdgcn_mfma_f32_16x16x32_bf16(qfrag, blv, z, 0, 0, 0);
      S[tt] = z;
    }

    #pragma unroll
    for (int rg = 0; rg < 4; ++rg) {
      int rowb = w * 16 + quad * 4 + rg;
      u32 mw0 = maskS[rowb][2 * (c - c0)];
      u32 mw1 = maskS[rowb][2 * (c - c0) + 1];
      float ps = 0.f;
      #pragma unroll
      for (int tt = 0; tt < 4; ++tt) {
        u32 mword = (tt & 2) ? mw1 : mw0;
        int bit = (tt & 1) * 16 + r16;
        int bk = buckS[pb][rowb][tt * 16 + r16] & 31;
        float rel = qe_s[w][quad * 4 + rg][bk];
        float sc = S[tt][rg] + rel;
        sc += ((mword >> bit) & 1u) ? 0.f : -1.0e9f;
        float p = __expf(sc - SM_OFF);
        ps += p;
        Ps[w][quad * 4 + rg][tt * 16 + r16] = f2bf(p);
      }
      #pragma unroll
      for (int o = 1; o < 16; o <<= 1) ps += __shfl_xor(ps, o);
      lrun[rg] += ps;
    }
    #pragma unroll
    for (int half = 0; half < 2; ++half) {
      bf8 pa = *(const bf8*)&Ps[w][r16][half * 32 + quad * 8];
      bf8 vb = mk8(*(const ushort4*)&Vt[pb][r16][half * 32 + quad * 8],
                   *(const ushort4*)&Vt[pb][r16][half * 32 + quad * 8 + 4]);
      Oacc = __builtin_amdgcn_mfma_f32_16x16x32_bf16(pa, vb, Oacc, 0, 0, 0);
    }

    if (pf) store_chunk(pb ^ 1);
  }

  #pragma unroll
  for (int rg = 0; rg < 4; ++rg) {
    int gi = i0 + w * 16 + quad * 4 + rg;
    if (gi < N1) {
      size_t base = ((size_t)(bh * NSPLIT + s) * N1 + gi);
      Opart[base * 16 + r16] = Oacc[rg];
      if (r16 == 0) lpart[base] = lrun[rg];
    }
  }
}

// ---------------------------------------------------------------- combine split partials (plain sums)
__global__ void attn_combine_kernel(const float* __restrict__ Opart,
                                    const float* __restrict__ lpart,
                                    u16* __restrict__ CbH, u16* __restrict__ CbL) {
  int idx = blockIdx.x * 256 + threadIdx.x;
  if (idx >= BB * NH * N1) return;
  int q = idx % N1; int bh = idx / N1; int h = bh & 7; int b = bh >> 3;
  float l = 0.f;
  float o[16];
  #pragma unroll
  for (int d = 0; d < DK; ++d) o[d] = 0.f;
  #pragma unroll
  for (int s = 0; s < NSPLIT; ++s) {
    size_t base = (size_t)(bh * NSPLIT + s) * N1 + q;
    l += lpart[base];
    const float* op = Opart + base * 16;
    #pragma unroll
    for (int d = 0; d < DK; ++d) o[d] += op[d];
  }
  float inv = 1.0f / l;
  size_t obase = ((size_t)b * N1 + q) * DM + h * DK;
  #pragma unroll
  for (int d = 0; d < DK; ++d) {
    float v = o[d] * inv;
    u16 hh = f2bf(v);
    CbH[obase + d] = hh;
    CbL[obase + d] = f2bf(v - bf2f(hh));
  }
}

// ---------------------------------------------------------------- instance norm (+pool/g, +split emit)
// oM==nullptr: no emit; oL==nullptr: 2-level (oH,oM as hi/lo); else 3-level (oH,oM,oL)
__global__ void inorm_kernel(float* __restrict__ X, const float* __restrict__ w,
                             const float* __restrict__ b_, float* __restrict__ pool,
                             int do_g, u16* __restrict__ oH, u16* __restrict__ oM,
                             u16* __restrict__ oL) {
  int d = blockIdx.x; int bb = blockIdx.y; int lane = threadIdx.x;
  float g_old = X[((size_t)bb * N1 + NN) * DM + d];
  float s = 0.f;
  for (int n = lane; n < N1; n += 64) s += X[((size_t)bb * N1 + n) * DM + d];
  #pragma unroll
  for (int o = 1; o < 64; o <<= 1) s += __shfl_xor(s, o);
  float mu = s * (1.0f / N1);
  float v = 0.f;
  for (int n = lane; n < N1; n += 64) {
    float tt = X[((size_t)bb * N1 + n) * DM + d] - mu;
    v += tt * tt;
  }
  #pragma unroll
  for (int o = 1; o < 64; o <<= 1) v += __shfl_xor(v, o);
  float var = v * (1.0f / N1);
  float scv = rsqrtf(var + 1e-5f) * w[d];
  float sh = b_[d];
  for (int n = lane; n < N1; n += 64) {
    size_t id = ((size_t)bb * N1 + n) * DM + d;
    float nv = (X[id] - mu) * scv + sh;
    X[id] = nv;
    if (oH) {
      u16 hh = f2bf(nv); float r1 = nv - bf2f(hh);
      u16 mm = f2bf(r1);
      oH[id] = hh;
      oM[id] = mm;
      if (oL) oL[id] = f2bf(r1 - bf2f(mm));
    }
  }
  if (lane == 0) {
    float hmean = ((s - g_old) * (1.0f / NN) - mu) * scv + sh;
    if (pool) pool[bb * DM + d] = hmean;
    if (do_g) X[((size_t)bb * N1 + NN) * DM + d] += hmean;
  }
}

// ---------------------------------------------------------------- final GEMM (inline h+pm split, +out_pm)
__global__ __launch_bounds__(256) void gemm_final_kernel(
    const float* __restrict__ X, const float* __restrict__ pools,
    const u16* __restrict__ PH, const u16* __restrict__ PL,
    const float* __restrict__ bias, float* __restrict__ out, float* __restrict__ out_pm) {
  int t = threadIdx.x;
  if (blockIdx.x == 0 && blockIdx.y == 0) {
    float pmv = (pools[t] + pools[BB * DM + t] + pools[2 * BB * DM + t]) * (1.0f / 3.0f);
    out_pm[t] = pmv;
  }
  int lane = t & 63;
  int quad = lane >> 4, r16 = lane & 15;
  int mt = blockIdx.x * 4 + (t >> 6), nt = blockIdx.y;
  const int M = BB * NN;
  f4 acc = {0.f, 0.f, 0.f, 0.f};
  int m0 = mt * 16;
  int mrow = m0 + r16; if (mrow >= M) mrow = M - 1;
  int mb = mrow / NN, mn = mrow % NN;
  const float* xp = X + ((size_t)mb * N1 + mn) * DM + quad * 8;
  const float* pp = pools + mb * DM + quad * 8;
  const u16* ph = PH + ((size_t)nt * 4 * 64 + lane) * 8;
  const u16* pl = PL + ((size_t)nt * 4 * 64 + lane) * 8;
  #pragma unroll
  for (int ks = 0; ks < 4; ++ks) {
    bf8 aH, aL;
    #pragma unroll
    for (int half = 0; half < 2; ++half) {
      float4 xv = *(const float4*)(xp + ks * 32 + half * 4);
      float4 p0 = *(const float4*)(pp + ks * 32 + half * 4);
      float4 p1 = *(const float4*)(pp + BB * DM + ks * 32 + half * 4);
      float4 p2 = *(const float4*)(pp + 2 * BB * DM + ks * 32 + half * 4);
      float av[4] = {xv.x + (p0.x + p1.x + p2.x) * (1.0f / 3.0f),
                     xv.y + (p0.y + p1.y + p2.y) * (1.0f / 3.0f),
                     xv.z + (p0.z + p1.z + p2.z) * (1.0f / 3.0f),
                     xv.w + (p0.w + p1.w + p2.w) * (1.0f / 3.0f)};
      #pragma unroll
      for (int q = 0; q < 4; ++q) {
        u16 hh = f2bf(av[q]);
        aH[half * 4 + q] = (short)hh;
        aL[half * 4 + q] = (short)f2bf(av[q] - bf2f(hh));
      }
    }
    bf8 bH = *(const bf8*)(ph + (size_t)ks * 512);
    bf8 bL = *(const bf8*)(pl + (size_t)ks * 512);
    acc = __builtin_amdgcn_mfma_f32_16x16x32_bf16(aH, bH, acc, 0, 0, 0);
    acc = __builtin_amdgcn_mfma_f32_16x16x32_bf16(aH, bL, acc, 0, 0, 0);
    acc = __builtin_amdgcn_mfma_f32_16x16x32_bf16(aL, bH, acc, 0, 0, 0);
  }
  int n = nt * 16 + r16;
  #pragma unroll
  for (int reg = 0; reg < 4; ++reg) {
    int m = m0 + quad * 4 + reg;
    if (m < M) out[(size_t)m * DM + n] = acc[reg] + bias[n];
  }
}

// ================================================================ launch
extern "C" void kernel_launch(void* const* d_in, const int* in_sizes, int n_in,
                              void* d_out, int out_size, void* d_ws, size_t ws_size,
                              hipStream_t stream) {
  const float* coords = (const float*)d_in[0];
  const float* inW    = (const float*)d_in[1];
  const float* inb    = (const float*)d_in[2];
  const float* gnode  = (const float*)d_in[3];
  const float* Wq     = (const float*)d_in[4];
  const float* Wk     = (const float*)d_in[5];
  const float* Wv     = (const float*)d_in[6];
  const float* Wo     = (const float*)d_in[7];
  const float* emb    = (const float*)d_in[8];
  const float* W1     = (const float*)d_in[9];
  const float* b1     = (const float*)d_in[10];
  const float* W2     = (const float*)d_in[11];
  const float* b2     = (const float*)d_in[12];
  const float* n1w    = (const float*)d_in[13];
  const float* n1b    = (const float*)d_in[14];
  const float* n2w    = (const float*)d_in[15];
  const float* n2b    = (const float*)d_in[16];
  const float* outW   = (const float*)d_in[17];
  const float* outb   = (const float*)d_in[18];
  float* out = (float*)d_out;

  char* wsp = (char*)d_ws;
  size_t off = 0;
  auto alloc = [&](size_t bytes) -> void* {
    off = (off + 255) & ~(size_t)255;
    void* p = wsp + off;
    off += bytes;
    return p;
  };
  const size_t XB = (size_t)BB * N1 * DM * 4;       // fp32 activation buffer
  const size_t HB = (size_t)BB * N1 * DM * 2;       // u16 half buffer
  float* X0   = (float*)alloc(XB);
  float* X1   = (float*)alloc(XB);
  float* Yb   = (float*)alloc(XB);
  u16* XH = (u16*)alloc(HB); u16* XM = (u16*)alloc(HB); u16* XL = (u16*)alloc(HB);
  u16* QH = (u16*)alloc(HB); u16* QL = (u16*)alloc(HB);
  u16* KH = (u16*)alloc(HB); u16* KL = (u16*)alloc(HB);
  u16* Vbf = (u16*)alloc(HB);
  u16* CbH = (u16*)alloc(HB); u16* CbL = (u16*)alloc(HB);
  u16* YbH = (u16*)alloc(HB); u16* YbL = (u16*)alloc(HB);
  u16* FbH = (u16*)alloc((size_t)BB * N1 * DFF * 2);
  u16* FbL = (u16*)alloc((size_t)BB * N1 * DFF * 2);
  unsigned char* buckp = (unsigned char*)alloc((size_t)BB * N1 * BSTR);
  unsigned long long* adj = (unsigned long long*)alloc((size_t)BB * N1 * ADJW * 8);
  float* pools = (float*)alloc((size_t)NLAYERS * BB * DM * 4);
  float* qe_all = (float*)alloc((size_t)BB * NH * N1 * 32 * 4);
  float* lpart = (float*)alloc((size_t)BB * NH * NSPLIT * N1 * 4);
  u16* PH = (u16*)alloc((size_t)PW_TOT * 2);
  u16* PL = (u16*)alloc((size_t)PW_TOT * 2);
  float* scratch8 = (float*)alloc((size_t)BB * NH * NSPLIT * N1 * 16 * 4);  // >= d2 size

  float* d2 = scratch8;                    // gram keys (8.39 MB), dead before attn
  float* Opart = scratch8;                 // attn partials (8.40 MB)

  init_kernel<<<PBLK + EBLK + BBLK, 256, 0, stream>>>(
      coords, inW, inb, gnode, Wq, Wk, Wv, Wo, W1, W2, outW, emb,
      PH, PL, X0, XH, XM, XL, buckp);

  float* Xin = X0; float* Xout = X1;
  const int M = BB * N1;
  const int GX = 33;     // ceil(129 m-tiles / 4 waves)
  for (int l = 0; l < NLAYERS; ++l) {
    gram_kernel<<<dim3(32, 16, BB), 256, 0, stream>>>(XH, XM, XL, adj, d2);
    knnsel_kernel<<<BB * NN / 4, 256, 0, stream>>>(d2, adj);

    gemm_qkv_kernel<<<dim3(GX, 40), 256, 0, stream>>>(
        XH, XM, PH, PL,
        (size_t)PWQ_OFF + (size_t)l * DM * DM,
        (size_t)PWK_OFF + (size_t)l * DM * DM,
        (size_t)PWV_OFF + (size_t)l * DM * DM,
        (size_t)PWQE_OFF + (size_t)l * 256 * DM,
        QH, QL, KH, KL, Vbf, qe_all, M);

    attn_kernel<<<dim3(33, NH * BB, NSPLIT), 128, 0, stream>>>(
        QH, QL, KH, KL, Vbf, qe_all, buckp, adj, Opart, lpart);
    attn_combine_kernel<<<(BB * NH * N1 + 255) / 256, 256, 0, stream>>>(
        Opart, lpart, CbH, CbL);

    gemm_kernel<<<dim3(GX, 8), 256, 0, stream>>>(
        CbH, CbL, PH + PWO_OFF + (size_t)l * DM * DM, PL + PWO_OFF + (size_t)l * DM * DM,
        nullptr, Xin, Yb, nullptr, nullptr, M, DM, DM, 0);
    inorm_kernel<<<dim3(DM, BB), 64, 0, stream>>>(Yb, n1w + l * DM, n1b + l * DM,
                                                  nullptr, 0, YbH, YbL, nullptr);

    gemm_kernel<<<dim3(GX, 32), 256, 0, stream>>>(
        YbH, YbL, PH + PW1_OFF + (size_t)l * DFF * DM, PL + PW1_OFF + (size_t)l * DFF * DM,
        b1 + l * DFF, nullptr, nullptr, FbH, FbL, M, DM, DFF, 1);
    gemm_kernel<<<dim3(GX, 8), 256, 0, stream>>>(
        FbH, FbL, PH + PW2_OFF + (size_t)l * DM * DFF, PL + PW2_OFF + (size_t)l * DM * DFF,
        b2 + l * DM, Yb, Xout, nullptr, nullptr, M, DFF, DM, 0);
    // inorm2 emits next layer's 3-level X splits inline
    inorm_kernel<<<dim3(DM, BB), 64, 0, stream>>>(Xout, n2w + l * DM, n2b + l * DM,
                                                  pools + (size_t)l * BB * DM, 1,
                                                  XH, XM, XL);

    float* t2 = Xin; Xin = Xout; Xout = t2;
  }

  gemm_final_kernel<<<dim3(32, 8), 256, 0, stream>>>(
      Xin, pools, PH + PWOUT_OFF, PL + PWOUT_OFF, outb, out, out + (size_t)BB * NN * DM);
}

// Round 16
// 482.117 us; speedup vs baseline: 1.0994x; 1.0483x over previous
//
#include <hip/hip_runtime.h>

#define BB 2
#define NN 1024
#define N1 1025
#define DM 128
#define NH 8
#define DK 16
#define DFF 512
#define NBUK 32
#define NLAYERS 3
#define KNN_K 10
#define ADJW 17          // 1025 bits -> 17 u64 words per row
#define BSTR 1088        // padded bucket row stride (bytes)
#define NSPLIT 8
#define BIGF 3.0e38f
#define SM_OFF 24.0f     // fixed softmax exponent offset (|s| bounded << 24+88)

// prepacked-weight element offsets (see init_kernel prepack branch)
#define PWQ_OFF 0
#define PWK_OFF 49152
#define PWV_OFF 98304
#define PWO_OFF 147456
#define PW1_OFF 196608
#define PW2_OFF 393216
#define PWOUT_OFF 589824
#define PWQE_OFF 606208
#define PW_TOT 704512

// init kernel block ranges
#define PBLK 344         // ceil(88064/256) prepack
#define NBNODE 1024      // embed node blocks
#define EBLK (NBNODE + BB)
#define BBLK 8713        // ceil(BB*N1*BSTR/256) bucket

// knnsel+qkv merged kernel block ranges
#define KSEL_BLK 512     // BB*NN/4
#define QKV_GX 33
#define QKV_BLK (QKV_GX * 40)

typedef __attribute__((ext_vector_type(8))) short bf8;
typedef __attribute__((ext_vector_type(4))) float f4;
typedef unsigned short u16;
typedef unsigned int u32;

__device__ __forceinline__ u16 f2bf(float x) {
  unsigned u = __float_as_uint(x);
  return (u16)((u + 0x7fff + ((u >> 16) & 1)) >> 16);   // RNE
}
__device__ __forceinline__ float bf2f(u16 u) {
  return __uint_as_float(((unsigned)u) << 16);
}
__device__ __forceinline__ bf8 mk8(ushort4 a, ushort4 b) {
  bf8 r;
  r[0] = (short)a.x; r[1] = (short)a.y; r[2] = (short)a.z; r[3] = (short)a.w;
  r[4] = (short)b.x; r[5] = (short)b.y; r[6] = (short)b.z; r[7] = (short)b.w;
  return r;
}

// ---------------------------------------------------------------- init: prepack + embed(+splits) + bucket
__global__ __launch_bounds__(256) void init_kernel(
    const float* __restrict__ coords, const float* __restrict__ inW,
    const float* __restrict__ inb, const float* __restrict__ gnode,
    const float* __restrict__ Wq, const float* __restrict__ Wk,
    const float* __restrict__ Wv, const float* __restrict__ Wo,
    const float* __restrict__ W1, const float* __restrict__ W2,
    const float* __restrict__ oW, const float* __restrict__ emb,
    u16* __restrict__ PH, u16* __restrict__ PL,
    float* __restrict__ X, u16* __restrict__ XH, u16* __restrict__ XM,
    u16* __restrict__ XL, unsigned char* __restrict__ buckp) {
  int blk = blockIdx.x;
  if (blk < PBLK) {
    // ---------------- prepack (+inline wqe composite)
    int idx = blk * 256 + threadIdx.x;
    if (idx >= 88064) return;
    if (idx >= 75776) {
      int rel = idx - 75776;
      int lane = rel & 63, g = rel >> 6;
      int ks = g & 3, nt = g >> 2;
      int n = nt * 16 + (lane & 15);
      int k = ks * 32 + (lane >> 4) * 8;
      int l = n >> 8; int c = n & 255; int h = c >> 5, bk = c & 31;
      const float* e = emb + ((size_t)l * NBUK + bk) * DM + h * DK;
      const float* wq = Wq + ((size_t)l * DM + h * DK) * DM;
      u16* ph = PH + (size_t)idx * 8;
      u16* pl = PL + (size_t)idx * 8;
      #pragma unroll
      for (int q = 0; q < 8; ++q) {
        float s = 0.f;
        #pragma unroll
        for (int d = 0; d < DK; ++d) s += e[d] * wq[(size_t)d * DM + k + q];
        u16 hh = f2bf(s);
        ph[q] = hh;
        pl[q] = f2bf(s - bf2f(hh));
      }
      return;
    }
    const float* W; int rel, Kdim;
    if (idx < 24576) {
      int seg = idx / 6144; rel = idx % 6144; Kdim = 128;
      W = seg == 0 ? Wq : seg == 1 ? Wk : seg == 2 ? Wv : Wo;
    } else if (idx < 49152) { rel = idx - 24576; Kdim = 128; W = W1; }
    else if (idx < 73728)   { rel = idx - 49152; Kdim = 512; W = W2; }
    else                    { rel = idx - 73728; Kdim = 128; W = oW; }
    int lane = rel & 63;
    int g = rel >> 6;
    int ksteps = Kdim >> 5;
    int ks = g % ksteps, nt = g / ksteps;
    int n = nt * 16 + (lane & 15);
    int k = ks * 32 + (lane >> 4) * 8;
    const float* p = W + (size_t)n * Kdim + k;
    u16* ph = PH + (size_t)idx * 8;
    u16* pl = PL + (size_t)idx * 8;
    #pragma unroll
    for (int q = 0; q < 8; ++q) {
      float x = p[q];
      u16 hh = f2bf(x);
      ph[q] = hh;
      pl[q] = f2bf(x - bf2f(hh));
    }
    return;
  }
  if (blk < PBLK + EBLK) {
    // ---------------- embed (+g row), emitting 3-level splits
    int eb = blk - PBLK;
    if (eb >= NBNODE) {
      int b = eb - NBNODE;
      int t = threadIdx.x;
      if (t >= 128) return;
      int lane = t & 63;
      float sx = 0.f, sy = 0.f;
      for (int n = lane; n < NN; n += 64) {
        float2 c = *(const float2*)(coords + (size_t)(b * NN + n) * 2);
        sx += c.x; sy += c.y;
      }
      #pragma unroll
      for (int o = 1; o < 64; o <<= 1) { sx += __shfl_xor(sx, o); sy += __shfl_xor(sy, o); }
      float mx = sx * (1.0f / NN), my = sy * (1.0f / NN);
      int d = t;
      size_t id = ((size_t)b * N1 + NN) * DM + d;
      float v = gnode[d] + inb[d] + mx * inW[d * 2 + 0] + my * inW[d * 2 + 1];
      X[id] = v;
      u16 hh = f2bf(v); float r1 = v - bf2f(hh);
      u16 mm = f2bf(r1);
      XH[id] = hh; XM[id] = mm; XL[id] = f2bf(r1 - bf2f(mm));
      return;
    }
    int idx = eb * 256 + threadIdx.x;
    if (idx >= BB * NN * DM) return;
    int d = idx % DM; int r = idx / DM; int n = r % NN; int b = r / NN;
    float cx = coords[(b * NN + n) * 2 + 0], cy = coords[(b * NN + n) * 2 + 1];
    size_t id = ((size_t)b * N1 + n) * DM + d;
    float v = cx * inW[d * 2 + 0] + cy * inW[d * 2 + 1] + inb[d];
    X[id] = v;
    u16 hh = f2bf(v); float r1 = v - bf2f(hh);
    u16 mm = f2bf(r1);
    XH[id] = hh; XM[id] = mm; XL[id] = f2bf(r1 - bf2f(mm));
    return;
  }
  // ---------------- bucket (padded rows)
  int idx = (blk - PBLK - EBLK) * 256 + threadIdx.x;
  if (idx >= BB * N1 * BSTR) return;
  int j = idx % BSTR; int r = idx / BSTR; int i = r % N1; int b = r / N1;
  unsigned char v = 0;
  if (j < N1) {
    float xi = 0.f, yi = 0.f, xj = 0.f, yj = 0.f;
    if (i < NN) { xi = coords[(b * NN + i) * 2]; yi = coords[(b * NN + i) * 2 + 1]; }
    if (j < NN) { xj = coords[(b * NN + j) * 2]; yj = coords[(b * NN + j) * 2 + 1]; }
    float dx = xi - xj, dy = yi - yj;
    float dist = sqrtf(dx * dx + dy * dy);
    int bu = (int)(dist * 32.0f);
    bu = bu < 0 ? 0 : (bu > 31 ? 31 : bu);
    v = (unsigned char)bu;
  }
  buckp[idx] = v;
}

// ---------------------------------------------------------------- exact MFMA gram (+adj zero)
// kNN key = sj - 2*dot (si dropped: row-constant, rank-equivalent). sj computed in
// parallel (64 rows x 4 threads, vector LDS reads, exact H+M+L reconstruction).
__global__ __launch_bounds__(256) void gram_kernel(
    const u16* __restrict__ XH, const u16* __restrict__ XM, const u16* __restrict__ XL,
    unsigned long long* __restrict__ adj, float* __restrict__ d2) {
  __shared__ __align__(16) u16 AsH[32][72];
  __shared__ __align__(16) u16 AsM[32][72];
  __shared__ __align__(16) u16 AsL[32][72];
  __shared__ __align__(16) u16 BsH[64][72];
  __shared__ __align__(16) u16 BsM[64][72];
  __shared__ __align__(16) u16 BsL[64][72];
  __shared__ float sqS[64];               // B-row squared norms
  int b = blockIdx.z;
  int m0 = blockIdx.x * 32, n0 = blockIdx.y * 64;
  size_t boff = (size_t)b * N1;
  int t = threadIdx.x;

  // zero adjacency (1024 blocks x 256 thr covers 34850 u64 words)
  {
    int flat = blockIdx.x + 32 * (blockIdx.y + 16 * blockIdx.z);
    int tid = flat * 256 + t;
    if (tid < BB * N1 * ADJW) adj[tid] = 0ull;
  }

  int lane = t & 63, w = t >> 6;
  int wm = (w >> 1) * 16, wn = (w & 1) * 32;
  int quad = lane >> 4, r16 = lane & 15;

  f4 acc0 = {0.f, 0.f, 0.f, 0.f}, acc1 = {0.f, 0.f, 0.f, 0.f};
  int ar = t >> 3, as_ = (t & 7) * 8;     // A: 32 rows x 8 segs of 8
  int br = t >> 2, bs_ = (t & 3) * 16;    // B: 64 rows x 4 segs of 16
  int sqrow = t >> 2, sqk = (t & 3) * 16; // sq: 64 rows x 4 threads x 16 elems
  float mySq = 0.f;

  for (int k0 = 0; k0 < DM; k0 += 64) {
    {
      size_t src = (boff + m0 + ar) * DM + k0 + as_;
      *(bf8*)&AsH[ar][as_] = *(const bf8*)(XH + src);
      *(bf8*)&AsM[ar][as_] = *(const bf8*)(XM + src);
      *(bf8*)&AsL[ar][as_] = *(const bf8*)(XL + src);
    }
    {
      size_t src = (boff + n0 + br) * DM + k0 + bs_;
      *(bf8*)&BsH[br][bs_] = *(const bf8*)(XH + src);
      *(bf8*)&BsH[br][bs_ + 8] = *(const bf8*)(XH + src + 8);
      *(bf8*)&BsM[br][bs_] = *(const bf8*)(XM + src);
      *(bf8*)&BsM[br][bs_ + 8] = *(const bf8*)(XM + src + 8);
      *(bf8*)&BsL[br][bs_] = *(const bf8*)(XL + src);
      *(bf8*)&BsL[br][bs_ + 8] = *(const bf8*)(XL + src + 8);
    }
    __syncthreads();
    #pragma unroll
    for (int ks = 0; ks < 64; ks += 16) {
      int seg = (quad & 1) * 8;
      bf8 aHM = *(const bf8*)((quad < 2) ? &AsH[wm + r16][ks + seg] : &AsM[wm + r16][ks + seg]);
      bf8 aHL = *(const bf8*)((quad < 2) ? &AsH[wm + r16][ks + seg] : &AsL[wm + r16][ks + seg]);
      #pragma unroll
      for (int tt = 0; tt < 2; ++tt) {
        int nr = wn + tt * 16 + r16;
        bf8 bH = *(const bf8*)&BsH[nr][ks + seg];
        bf8 bM = *(const bf8*)&BsM[nr][ks + seg];
        bf8 b3 = *(const bf8*)((quad < 2) ? &BsL[nr][ks + seg] : &BsH[nr][ks + seg]);
        f4& a = tt ? acc1 : acc0;
        a = __builtin_amdgcn_mfma_f32_16x16x32_bf16(aHM, bH, a, 0, 0, 0);  // HH' + MH'
        a = __builtin_amdgcn_mfma_f32_16x16x32_bf16(aHM, bM, a, 0, 0, 0);  // HM' + MM'
        a = __builtin_amdgcn_mfma_f32_16x16x32_bf16(aHL, b3, a, 0, 0, 0);  // HL' + LH'
      }
    }
    // parallel B-row sq: vector LDS reads, exact x = H+M+L
    #pragma unroll
    for (int half = 0; half < 2; ++half) {
      bf8 hv = *(const bf8*)&BsH[sqrow][sqk + half * 8];
      bf8 mv = *(const bf8*)&BsM[sqrow][sqk + half * 8];
      bf8 lv = *(const bf8*)&BsL[sqrow][sqk + half * 8];
      #pragma unroll
      for (int q = 0; q < 8; ++q) {
        float x = (bf2f((u16)hv[q]) + bf2f((u16)mv[q])) + bf2f((u16)lv[q]);
        mySq += x * x;
      }
    }
    __syncthreads();
  }
  // reduce 4 partials per row (threads row*4+jj adjacent in wave)
  mySq += __shfl_xor(mySq, 1);
  mySq += __shfl_xor(mySq, 2);
  if ((t & 3) == 0) sqS[sqrow] = mySq;
  __syncthreads();

  #pragma unroll
  for (int tt = 0; tt < 2; ++tt) {
    f4 a = tt ? acc1 : acc0;
    int nl = wn + tt * 16 + r16;
    int n = n0 + nl;
    float sj = sqS[nl];
    #pragma unroll
    for (int reg = 0; reg < 4; ++reg) {
      int m = m0 + wm + quad * 4 + reg;
      float v = (m == n) ? BIGF : (sj - 2.f * a[reg]);
      d2[((size_t)b * NN + m) * NN + n] = v;
    }
  }
}

// ---------------------------------------------------------------- merged: knnsel || qkv+qe
// blocks 0..KSEL_BLK-1: top-10 select (reads d2, writes adj).
// blocks KSEL_BLK..   : QKV+QE direct-fragment GEMM (independent of knnsel).
__global__ __launch_bounds__(256) void knnqkv_kernel(
    const float* __restrict__ d2, unsigned long long* __restrict__ adj,
    const u16* __restrict__ AH, const u16* __restrict__ AL,
    const u16* __restrict__ Pbase_H, const u16* __restrict__ Pbase_L,
    size_t offQ, size_t offK, size_t offV, size_t offE,
    u16* __restrict__ QH, u16* __restrict__ QL,
    u16* __restrict__ KH, u16* __restrict__ KL, u16* __restrict__ Vbf,
    float* __restrict__ qe_all, int M) {
  __shared__ float dd[4][NN];
  int blk = blockIdx.x;
  if (blk < KSEL_BLK) {
    // ---------------- knnsel (verbatim)
    int b = blk / (NN / 4);
    int i0 = (blk % (NN / 4)) * 4;
    int t = threadIdx.x, lane = t & 63, w = t >> 6;

    const float4* src = (const float4*)(d2 + ((size_t)b * NN + i0) * NN);
    float4* dst = (float4*)&dd[0][0];
    #pragma unroll
    for (int x = 0; x < 4; ++x) dst[t + x * 256] = src[t + x * 256];
    __syncthreads();

    int i = i0 + w;
    for (int it = 0; it < KNN_K; ++it) {
      float bv = BIGF; int bi = 0x3fffffff;
      for (int j = lane; j < NN; j += 64) {
        float v = dd[w][j];
        if (v < bv) { bv = v; bi = j; }
      }
      #pragma unroll
      for (int o = 1; o < 64; o <<= 1) {
        float ov = __shfl_xor(bv, o); int oi = __shfl_xor(bi, o);
        if (ov < bv || (ov == bv && oi < bi)) { bv = ov; bi = oi; }
      }
      if (lane == 0) {
        dd[w][bi] = BIGF;
        atomicOr(&adj[((size_t)b * N1 + i) * ADJW + (bi >> 6)], 1ull << (bi & 63));
        atomicOr(&adj[((size_t)b * N1 + bi) * ADJW + (i >> 6)], 1ull << (i & 63));
      }
    }
    return;
  }
  // ---------------- qkv+qe (verbatim, flattened grid)
  int rel = blk - KSEL_BLK;
  int gx = rel % QKV_GX;
  int y = rel / QKV_GX;
  int z, nt;
  if (y < 8) { z = 0; nt = y; }
  else if (y < 16) { z = 1; nt = y - 8; }
  else if (y < 24) { z = 2; nt = y - 16; }
  else { z = 3; nt = y - 24; }
  size_t woff = z == 0 ? offQ : (z == 1 ? offK : (z == 2 ? offV : offE));
  const u16* PH = Pbase_H + woff;
  const u16* PL = Pbase_L + woff;
  int lane = threadIdx.x & 63;
  int quad = lane >> 4, r16 = lane & 15;
  int mt = gx * 4 + (threadIdx.x >> 6);
  f4 acc = {0.f, 0.f, 0.f, 0.f};
  int m0 = mt * 16;
  int mrow = m0 + r16; if (mrow >= M) mrow = M - 1;
  const u16* aph = AH + (size_t)mrow * DM + quad * 8;
  const u16* apl = AL + (size_t)mrow * DM + quad * 8;
  const u16* ph = PH + ((size_t)nt * 4 * 64 + lane) * 8;
  const u16* pl = PL + ((size_t)nt * 4 * 64 + lane) * 8;
  #pragma unroll
  for (int ks = 0; ks < 4; ++ks) {
    bf8 aH = *(const bf8*)(aph);
    bf8 aL = *(const bf8*)(apl);
    aph += 32; apl += 32;
    bf8 bH = *(const bf8*)(ph + (size_t)ks * 512);
    bf8 bL = *(const bf8*)(pl + (size_t)ks * 512);
    acc = __builtin_amdgcn_mfma_f32_16x16x32_bf16(aH, bH, acc, 0, 0, 0);
    acc = __builtin_amdgcn_mfma_f32_16x16x32_bf16(aH, bL, acc, 0, 0, 0);
    acc = __builtin_amdgcn_mfma_f32_16x16x32_bf16(aL, bH, acc, 0, 0, 0);
  }
  if (m0 >= M) return;
  int n = nt * 16 + r16;
  #pragma unroll
  for (int reg = 0; reg < 4; ++reg) {
    int m = m0 + quad * 4 + reg;
    if (m >= M) continue;
    float v = acc[reg];
    if (z == 3) {
      int b = m / N1, nr = m % N1;
      int h = n >> 5, bk = n & 31;
      qe_all[(((size_t)b * NH + h) * N1 + nr) * 32 + bk] = v;
      continue;
    }
    size_t oi = (size_t)m * DM + n;
    if (z == 0) {
      float sv = v * 0.25f;
      u16 hh = f2bf(sv);
      QH[oi] = hh;
      QL[oi] = f2bf(sv - bf2f(hh));
    } else if (z == 1) {
      u16 hh = f2bf(v);
      KH[oi] = hh;
      KL[oi] = f2bf(v - bf2f(hh));
    } else {
      Vbf[oi] = f2bf(v);
    }
  }
}

// ---------------------------------------------------------------- direct-fragment GEMM (16x16/wave)
__device__ __forceinline__ void gemm_dev16(
    const u16* __restrict__ AH, const u16* __restrict__ AL,
    const u16* __restrict__ PH, const u16* __restrict__ PL,
    const float* __restrict__ bias, const float* __restrict__ res,
    float* __restrict__ outF, u16* __restrict__ outH, u16* __restrict__ outL,
    int M, int Kdim, int Nout, int relu, int mt, int nt) {
  int lane = threadIdx.x & 63;
  int quad = lane >> 4, r16 = lane & 15;
  int ksteps = Kdim >> 5;
  f4 acc = {0.f, 0.f, 0.f, 0.f};

  int m0 = mt * 16;
  int mrow = m0 + r16; if (mrow >= M) mrow = M - 1;   // clamp; result discarded
  const u16* aph = AH + (size_t)mrow * Kdim + quad * 8;
  const u16* apl = AL + (size_t)mrow * Kdim + quad * 8;
  const u16* ph = PH + ((size_t)nt * ksteps * 64 + lane) * 8;
  const u16* pl = PL + ((size_t)nt * ksteps * 64 + lane) * 8;

  #pragma unroll 4
  for (int ks = 0; ks < ksteps; ++ks) {
    bf8 aH = *(const bf8*)(aph);
    bf8 aL = *(const bf8*)(apl);
    aph += 32; apl += 32;
    bf8 bH = *(const bf8*)(ph + (size_t)ks * 512);
    bf8 bL = *(const bf8*)(pl + (size_t)ks * 512);
    acc = __builtin_amdgcn_mfma_f32_16x16x32_bf16(aH, bH, acc, 0, 0, 0);
    acc = __builtin_amdgcn_mfma_f32_16x16x32_bf16(aH, bL, acc, 0, 0, 0);
    acc = __builtin_amdgcn_mfma_f32_16x16x32_bf16(aL, bH, acc, 0, 0, 0);
  }

  if (m0 >= M) return;
  int n = nt * 16 + r16;
  #pragma unroll
  for (int reg = 0; reg < 4; ++reg) {
    int m = m0 + quad * 4 + reg;    // C layout: col=lane&15, row=quad*4+reg
    if (m < M) {
      float v = acc[reg];
      if (bias) v += bias[n];
      if (relu) v = fmaxf(v, 0.f);
      if (res) v += res[(size_t)m * Nout + n];
      size_t oi = (size_t)m * Nout + n;
      if (outF) outF[oi] = v;
      if (outH) {
        u16 hh = f2bf(v);
        outH[oi] = hh;
        outL[oi] = f2bf(v - bf2f(hh));
      }
    }
  }
}

__global__ __launch_bounds__(256) void gemm_kernel(
    const u16* __restrict__ AH, const u16* __restrict__ AL,
    const u16* __restrict__ PH, const u16* __restrict__ PL,
    const float* __restrict__ bias, const float* __restrict__ res,
    float* __restrict__ outF, u16* __restrict__ outH, u16* __restrict__ outL,
    int M, int Kdim, int Nout, int relu) {
  gemm_dev16(AH, AL, PH, PL, bias, res, outF, outH, outL, M, Kdim, Nout, relu,
             blockIdx.x * 4 + (threadIdx.x >> 6), blockIdx.y);
}

// ---------------------------------------------------------------- MFMA flash attention, key-split
// Fixed-offset softmax; mask words computed inline from adj + static band/depot/diag.
#define CH 64
#define NCH 17
__global__ __launch_bounds__(128) void attn_kernel(
    const u16* __restrict__ QH, const u16* __restrict__ QL,
    const u16* __restrict__ KH, const u16* __restrict__ KL,
    const u16* __restrict__ Vbf, const float* __restrict__ qe_all,
    const unsigned char* __restrict__ buckp, const unsigned long long* __restrict__ adj,
    float* __restrict__ Opart, float* __restrict__ lpart) {
  __shared__ __align__(16) u16 KsHi[2][CH][20];
  __shared__ __align__(16) u16 KsLo[2][CH][20];
  __shared__ __align__(16) u16 Vt[2][DK][68];
  __shared__ __align__(16) u16 Ps[2][16][72];
  __shared__ __align__(16) float qe_s[2][16][36];
  __shared__ u32 maskS[32][6];
  __shared__ unsigned char buckS[2][32][68];

  int qt = blockIdx.x;
  int h = blockIdx.y & 7, b = blockIdx.y >> 3;
  int s = blockIdx.z;
  int c0 = (NCH * s) / NSPLIT, c1 = (NCH * (s + 1)) / NSPLIT;
  int nwm = 2 * (c1 - c0);
  int t = threadIdx.x, lane = t & 63, w = t >> 6;
  int quad = lane >> 4, r16 = lane & 15;
  int i0 = qt * 32;
  int iw = i0 + w * 16;
  int bh = b * NH + h;

  // mask words inline (== old connb output, bit-exact)
  for (int x = t; x < 32 * nwm; x += 128) {
    int rr = x / nwm, ww = x % nwm;
    int gi = i0 + rr; if (gi > NN) gi = NN;
    int W = 2 * c0 + ww;
    u32 v;
    if (gi == 0 || gi == NN) {
      v = 0xffffffffu;
    } else {
      const u32* a32 = (const u32*)(adj + ((size_t)b * N1 + gi) * ADJW);
      v = a32[W];
      int bs = gi & ~127;
      int lo = gi - 11 < bs ? bs : gi - 11;
      int be = bs + 127;
      int hi = gi + 11 > be ? be : gi + 11;
      int aa = lo - 32 * W, bnd = hi - 32 * W;
      if (aa < 0) aa = 0; if (bnd > 31) bnd = 31;
      if (aa <= bnd) v |= (0xffffffffu << aa) & (0xffffffffu >> (31 - bnd));
      if (W == 0) v |= 1u;
      if (W == 32) v |= 1u;
      int dg = gi - 32 * W;
      if (dg >= 0 && dg < 32) v |= 1u << dg;
    }
    if (W == 32) v &= 1u;
    else if (W == 33) v = 0u;
    maskS[rr][ww] = v;
  }
  // qe table: per-row clamped load
  #pragma unroll
  for (int e = 0; e < 2; ++e) {
    int x = lane + e * 64;
    int rr = x >> 3, bk = (x & 7) * 4;
    int gi = iw + rr; if (gi > NN) gi = NN;
    f4 v = *(const f4*)(qe_all + (((size_t)b * NH + h) * N1 + gi) * 32 + bk);
    *(f4*)&qe_s[w][rr][bk] = v;
  }
  bf8 qfrag;
  {
    int gi = iw + r16; if (gi > NN) gi = NN;
    const u16* qsrc = (quad < 2 ? QH : QL) + ((size_t)(b * N1 + gi) * DM + h * DK + (quad & 1) * 8);
    qfrag = *(const bf8*)qsrc;
  }

  ushort4 khr[2], klr[2], vvr[2]; u32 bkr[4];
  auto load_chunk = [&](int c) {
    int j0 = c * CH;
    #pragma unroll
    for (int ii = 0; ii < 2; ++ii) {
      int x = t + ii * 128;
      int key = x >> 2, ds = (x & 3) * 4;
      int jg = j0 + key; if (jg > NN) jg = NN;
      size_t src = (size_t)(b * N1 + jg) * DM + h * DK + ds;
      khr[ii] = *(const ushort4*)(KH + src);
      klr[ii] = *(const ushort4*)(KL + src);
      vvr[ii] = *(const ushort4*)(Vbf + src);
    }
    #pragma unroll
    for (int ii = 0; ii < 4; ++ii) {
      int x = t + ii * 128;
      int rr = x >> 4, c4 = (x & 15) * 4;
      int gi = i0 + rr; if (gi > NN) gi = NN;
      bkr[ii] = *(const u32*)(buckp + ((size_t)b * N1 + gi) * BSTR + j0 + c4);
    }
  };
  auto store_chunk = [&](int pb) {
    #pragma unroll
    for (int ii = 0; ii < 2; ++ii) {
      int x = t + ii * 128;
      int key = x >> 2, ds = (x & 3) * 4;
      *(ushort4*)&KsHi[pb][key][ds] = khr[ii];
      *(ushort4*)&KsLo[pb][key][ds] = klr[ii];
      Vt[pb][ds + 0][key] = vvr[ii].x;
      Vt[pb][ds + 1][key] = vvr[ii].y;
      Vt[pb][ds + 2][key] = vvr[ii].z;
      Vt[pb][ds + 3][key] = vvr[ii].w;
    }
    #pragma unroll
    for (int ii = 0; ii < 4; ++ii) {
      int x = t + ii * 128;
      int rr = x >> 4, c4 = (x & 15) * 4;
      *(u32*)&buckS[pb][rr][c4] = bkr[ii];
    }
  };

  f4 Oacc = {0.f, 0.f, 0.f, 0.f};
  float lrun[4] = {0.f, 0.f, 0.f, 0.f};

  load_chunk(c0);
  store_chunk(0);

  for (int c = c0; c < c1; ++c) {
    int pb = (c - c0) & 1;
    bool pf = (c + 1 < c1);
    if (pf) load_chunk(c + 1);
    __syncthreads();

    f4 S[4];
    #pragma unroll
    for (int tt = 0; tt < 4; ++tt) {
      int key = tt * 16 + r16;
      int off = (quad & 1) * 8;
      bf8 bhv = mk8(*(const ushort4*)&KsHi[pb][key][off], *(const ushort4*)&KsHi[pb][key][off + 4]);
      bf8 blv = mk8(*(const ushort4*)&KsLo[pb][key][off], *(const ushort4*)&KsLo[pb][key][off + 4]);
      f4 z = {0.f, 0.f, 0.f, 0.f};
      z = __builtin_amdgcn_mfma_f32_16x16x32_bf16(qfrag, bhv, z, 0, 0, 0);
      z = __builtin_amdgcn_mfma_f32_16x16x32_bf16(qfrag, blv, z, 0, 0, 0);
      S[tt] = z;
    }

    #pragma unroll
    for (int rg = 0; rg < 4; ++rg) {
      int rowb = w * 16 + quad * 4 + rg;
      u32 mw0 = maskS[rowb][2 * (c - c0)];
      u32 mw1 = maskS[rowb][2 * (c - c0) + 1];
      float ps = 0.f;
      #pragma unroll
      for (int tt = 0; tt < 4; ++tt) {
        u32 mword = (tt & 2) ? mw1 : mw0;
        int bit = (tt & 1) * 16 + r16;
        int bk = buckS[pb][rowb][tt * 16 + r16] & 31;
        float rel = qe_s[w][quad * 4 + rg][bk];
        float sc = S[tt][rg] + rel;
        sc += ((mword >> bit) & 1u) ? 0.f : -1.0e9f;
        float p = __expf(sc - SM_OFF);
        ps += p;
        Ps[w][quad * 4 + rg][tt * 16 + r16] = f2bf(p);
      }
      #pragma unroll
      for (int o = 1; o < 16; o <<= 1) ps += __shfl_xor(ps, o);
      lrun[rg] += ps;
    }
    #pragma unroll
    for (int half = 0; half < 2; ++half) {
      bf8 pa = *(const bf8*)&Ps[w][r16][half * 32 + quad * 8];
      bf8 vb = mk8(*(const ushort4*)&Vt[pb][r16][half * 32 + quad * 8],
                   *(const ushort4*)&Vt[pb][r16][half * 32 + quad * 8 + 4]);
      Oacc = __builtin_amdgcn_mfma_f32_16x16x32_bf16(pa, vb, Oacc, 0, 0, 0);
    }

    if (pf) store_chunk(pb ^ 1);
  }

  #pragma unroll
  for (int rg = 0; rg < 4; ++rg) {
    int gi = i0 + w * 16 + quad * 4 + rg;
    if (gi < N1) {
      size_t base = ((size_t)(bh * NSPLIT + s) * N1 + gi);
      Opart[base * 16 + r16] = Oacc[rg];
      if (r16 == 0) lpart[base] = lrun[rg];
    }
  }
}

// ---------------------------------------------------------------- combine split partials (plain sums)
__global__ void attn_combine_kernel(const float* __restrict__ Opart,
                                    const float* __restrict__ lpart,
                                    u16* __restrict__ CbH, u16* __restrict__ CbL) {
  int idx = blockIdx.x * 256 + threadIdx.x;
  if (idx >= BB * NH * N1) return;
  int q = idx % N1; int bh = idx / N1; int h = bh & 7; int b = bh >> 3;
  float l = 0.f;
  float o[16];
  #pragma unroll
  for (int d = 0; d < DK; ++d) o[d] = 0.f;
  #pragma unroll
  for (int s = 0; s < NSPLIT; ++s) {
    size_t base = (size_t)(bh * NSPLIT + s) * N1 + q;
    l += lpart[base];
    const float* op = Opart + base * 16;
    #pragma unroll
    for (int d = 0; d < DK; ++d) o[d] += op[d];
  }
  float inv = 1.0f / l;
  size_t obase = ((size_t)b * N1 + q) * DM + h * DK;
  #pragma unroll
  for (int d = 0; d < DK; ++d) {
    float v = o[d] * inv;
    u16 hh = f2bf(v);
    CbH[obase + d] = hh;
    CbL[obase + d] = f2bf(v - bf2f(hh));
  }
}

// ---------------------------------------------------------------- instance norm (+pool/g, +split emit)
// oM==nullptr: no emit; oL==nullptr: 2-level (oH,oM as hi/lo); else 3-level (oH,oM,oL)
__global__ void inorm_kernel(float* __restrict__ X, const float* __restrict__ w,
                             const float* __restrict__ b_, float* __restrict__ pool,
                             int do_g, u16* __restrict__ oH, u16* __restrict__ oM,
                             u16* __restrict__ oL) {
  int d = blockIdx.x; int bb = blockIdx.y; int lane = threadIdx.x;
  float g_old = X[((size_t)bb * N1 + NN) * DM + d];
  float s = 0.f;
  for (int n = lane; n < N1; n += 64) s += X[((size_t)bb * N1 + n) * DM + d];
  #pragma unroll
  for (int o = 1; o < 64; o <<= 1) s += __shfl_xor(s, o);
  float mu = s * (1.0f / N1);
  float v = 0.f;
  for (int n = lane; n < N1; n += 64) {
    float tt = X[((size_t)bb * N1 + n) * DM + d] - mu;
    v += tt * tt;
  }
  #pragma unroll
  for (int o = 1; o < 64; o <<= 1) v += __shfl_xor(v, o);
  float var = v * (1.0f / N1);
  float scv = rsqrtf(var + 1e-5f) * w[d];
  float sh = b_[d];
  for (int n = lane; n < N1; n += 64) {
    size_t id = ((size_t)bb * N1 + n) * DM + d;
    float nv = (X[id] - mu) * scv + sh;
    X[id] = nv;
    if (oH) {
      u16 hh = f2bf(nv); float r1 = nv - bf2f(hh);
      u16 mm = f2bf(r1);
      oH[id] = hh;
      oM[id] = mm;
      if (oL) oL[id] = f2bf(r1 - bf2f(mm));
    }
  }
  if (lane == 0) {
    float hmean = ((s - g_old) * (1.0f / NN) - mu) * scv + sh;
    if (pool) pool[bb * DM + d] = hmean;
    if (do_g) X[((size_t)bb * N1 + NN) * DM + d] += hmean;
  }
}

// ---------------------------------------------------------------- final GEMM (inline h+pm split, +out_pm)
__global__ __launch_bounds__(256) void gemm_final_kernel(
    const float* __restrict__ X, const float* __restrict__ pools,
    const u16* __restrict__ PH, const u16* __restrict__ PL,
    const float* __restrict__ bias, float* __restrict__ out, float* __restrict__ out_pm) {
  int t = threadIdx.x;
  if (blockIdx.x == 0 && blockIdx.y == 0) {
    float pmv = (pools[t] + pools[BB * DM + t] + pools[2 * BB * DM + t]) * (1.0f / 3.0f);
    out_pm[t] = pmv;
  }
  int lane = t & 63;
  int quad = lane >> 4, r16 = lane & 15;
  int mt = blockIdx.x * 4 + (t >> 6), nt = blockIdx.y;
  const int M = BB * NN;
  f4 acc = {0.f, 0.f, 0.f, 0.f};
  int m0 = mt * 16;
  int mrow = m0 + r16; if (mrow >= M) mrow = M - 1;
  int mb = mrow / NN, mn = mrow % NN;
  const float* xp = X + ((size_t)mb * N1 + mn) * DM + quad * 8;
  const float* pp = pools + mb * DM + quad * 8;
  const u16* ph = PH + ((size_t)nt * 4 * 64 + lane) * 8;
  const u16* pl = PL + ((size_t)nt * 4 * 64 + lane) * 8;
  #pragma unroll
  for (int ks = 0; ks < 4; ++ks) {
    bf8 aH, aL;
    #pragma unroll
    for (int half = 0; half < 2; ++half) {
      float4 xv = *(const float4*)(xp + ks * 32 + half * 4);
      float4 p0 = *(const float4*)(pp + ks * 32 + half * 4);
      float4 p1 = *(const float4*)(pp + BB * DM + ks * 32 + half * 4);
      float4 p2 = *(const float4*)(pp + 2 * BB * DM + ks * 32 + half * 4);
      float av[4] = {xv.x + (p0.x + p1.x + p2.x) * (1.0f / 3.0f),
                     xv.y + (p0.y + p1.y + p2.y) * (1.0f / 3.0f),
                     xv.z + (p0.z + p1.z + p2.z) * (1.0f / 3.0f),
                     xv.w + (p0.w + p1.w + p2.w) * (1.0f / 3.0f)};
      #pragma unroll
      for (int q = 0; q < 4; ++q) {
        u16 hh = f2bf(av[q]);
        aH[half * 4 + q] = (short)hh;
        aL[half * 4 + q] = (short)f2bf(av[q] - bf2f(hh));
      }
    }
    bf8 bH = *(const bf8*)(ph + (size_t)ks * 512);
    bf8 bL = *(const bf8*)(pl + (size_t)ks * 512);
    acc = __builtin_amdgcn_mfma_f32_16x16x32_bf16(aH, bH, acc, 0, 0, 0);
    acc = __builtin_amdgcn_mfma_f32_16x16x32_bf16(aH, bL, acc, 0, 0, 0);
    acc = __builtin_amdgcn_mfma_f32_16x16x32_bf16(aL, bH, acc, 0, 0, 0);
  }
  int n = nt * 16 + r16;
  #pragma unroll
  for (int reg = 0; reg < 4; ++reg) {
    int m = m0 + quad * 4 + reg;
    if (m < M) out[(size_t)m * DM + n] = acc[reg] + bias[n];
  }
}

// ================================================================ launch
extern "C" void kernel_launch(void* const* d_in, const int* in_sizes, int n_in,
                              void* d_out, int out_size, void* d_ws, size_t ws_size,
                              hipStream_t stream) {
  const float* coords = (const float*)d_in[0];
  const float* inW    = (const float*)d_in[1];
  const float* inb    = (const float*)d_in[2];
  const float* gnode  = (const float*)d_in[3];
  const float* Wq     = (const float*)d_in[4];
  const float* Wk     = (const float*)d_in[5];
  const float* Wv     = (const float*)d_in[6];
  const float* Wo     = (const float*)d_in[7];
  const float* emb    = (const float*)d_in[8];
  const float* W1     = (const float*)d_in[9];
  const float* b1     = (const float*)d_in[10];
  const float* W2     = (const float*)d_in[11];
  const float* b2     = (const float*)d_in[12];
  const float* n1w    = (const float*)d_in[13];
  const float* n1b    = (const float*)d_in[14];
  const float* n2w    = (const float*)d_in[15];
  const float* n2b    = (const float*)d_in[16];
  const float* outW   = (const float*)d_in[17];
  const float* outb   = (const float*)d_in[18];
  float* out = (float*)d_out;

  char* wsp = (char*)d_ws;
  size_t off = 0;
  auto alloc = [&](size_t bytes) -> void* {
    off = (off + 255) & ~(size_t)255;
    void* p = wsp + off;
    off += bytes;
    return p;
  };
  const size_t XB = (size_t)BB * N1 * DM * 4;       // fp32 activation buffer
  const size_t HB = (size_t)BB * N1 * DM * 2;       // u16 half buffer
  float* X0   = (float*)alloc(XB);
  float* X1   = (float*)alloc(XB);
  float* Yb   = (float*)alloc(XB);
  u16* XH = (u16*)alloc(HB); u16* XM = (u16*)alloc(HB); u16* XL = (u16*)alloc(HB);
  u16* QH = (u16*)alloc(HB); u16* QL = (u16*)alloc(HB);
  u16* KH = (u16*)alloc(HB); u16* KL = (u16*)alloc(HB);
  u16* Vbf = (u16*)alloc(HB);
  u16* CbH = (u16*)alloc(HB); u16* CbL = (u16*)alloc(HB);
  u16* YbH = (u16*)alloc(HB); u16* YbL = (u16*)alloc(HB);
  u16* FbH = (u16*)alloc((size_t)BB * N1 * DFF * 2);
  u16* FbL = (u16*)alloc((size_t)BB * N1 * DFF * 2);
  unsigned char* buckp = (unsigned char*)alloc((size_t)BB * N1 * BSTR);
  unsigned long long* adj = (unsigned long long*)alloc((size_t)BB * N1 * ADJW * 8);
  float* pools = (float*)alloc((size_t)NLAYERS * BB * DM * 4);
  float* qe_all = (float*)alloc((size_t)BB * NH * N1 * 32 * 4);
  float* lpart = (float*)alloc((size_t)BB * NH * NSPLIT * N1 * 4);
  u16* PH = (u16*)alloc((size_t)PW_TOT * 2);
  u16* PL = (u16*)alloc((size_t)PW_TOT * 2);
  float* scratch8 = (float*)alloc((size_t)BB * NH * NSPLIT * N1 * 16 * 4);  // >= d2 size

  float* d2 = scratch8;                    // gram keys (8.39 MB), dead before attn
  float* Opart = scratch8;                 // attn partials (8.40 MB)

  init_kernel<<<PBLK + EBLK + BBLK, 256, 0, stream>>>(
      coords, inW, inb, gnode, Wq, Wk, Wv, Wo, W1, W2, outW, emb,
      PH, PL, X0, XH, XM, XL, buckp);

  float* Xin = X0; float* Xout = X1;
  const int M = BB * N1;
  const int GX = 33;     // ceil(129 m-tiles / 4 waves)
  for (int l = 0; l < NLAYERS; ++l) {
    gram_kernel<<<dim3(32, 16, BB), 256, 0, stream>>>(XH, XM, XL, adj, d2);

    // knnsel || qkv (independent) merged into one launch
    knnqkv_kernel<<<KSEL_BLK + QKV_BLK, 256, 0, stream>>>(
        d2, adj, XH, XM, PH, PL,
        (size_t)PWQ_OFF + (size_t)l * DM * DM,
        (size_t)PWK_OFF + (size_t)l * DM * DM,
        (size_t)PWV_OFF + (size_t)l * DM * DM,
        (size_t)PWQE_OFF + (size_t)l * 256 * DM,
        QH, QL, KH, KL, Vbf, qe_all, M);

    attn_kernel<<<dim3(33, NH * BB, NSPLIT), 128, 0, stream>>>(
        QH, QL, KH, KL, Vbf, qe_all, buckp, adj, Opart, lpart);
    attn_combine_kernel<<<(BB * NH * N1 + 255) / 256, 256, 0, stream>>>(
        Opart, lpart, CbH, CbL);

    gemm_kernel<<<dim3(GX, 8), 256, 0, stream>>>(
        CbH, CbL, PH + PWO_OFF + (size_t)l * DM * DM, PL + PWO_OFF + (size_t)l * DM * DM,
        nullptr, Xin, Yb, nullptr, nullptr, M, DM, DM, 0);
    inorm_kernel<<<dim3(DM, BB), 64, 0, stream>>>(Yb, n1w + l * DM, n1b + l * DM,
                                                  nullptr, 0, YbH, YbL, nullptr);

    gemm_kernel<<<dim3(GX, 32), 256, 0, stream>>>(
        YbH, YbL, PH + PW1_OFF + (size_t)l * DFF * DM, PL + PW1_OFF + (size_t)l * DFF * DM,
        b1 + l * DFF, nullptr, nullptr, FbH, FbL, M, DM, DFF, 1);
    gemm_kernel<<<dim3(GX, 8), 256, 0, stream>>>(
        FbH, FbL, PH + PW2_OFF + (size_t)l * DM * DFF, PL + PW2_OFF + (size_t)l * DM * DFF,
        b2 + l * DM, Yb, Xout, nullptr, nullptr, M, DFF, DM, 0);
    // inorm2 emits next layer's 3-level X splits inline
    inorm_kernel<<<dim3(DM, BB), 64, 0, stream>>>(Xout, n2w + l * DM, n2b + l * DM,
                                                  pools + (size_t)l * BB * DM, 1,
                                                  XH, XM, XL);

    float* t2 = Xin; Xin = Xout; Xout = t2;
  }

  gemm_final_kernel<<<dim3(32, 8), 256, 0, stream>>>(
      Xin, pools, PH + PWOUT_OFF, PL + PWOUT_OFF, outb, out, out + (size_t)BB * NN * DM);
}

// Round 17
// 467.621 us; speedup vs baseline: 1.1335x; 1.0310x over previous
//
#include <hip/hip_runtime.h>

#define BB 2
#define NN 1024
#define N1 1025
#define DM 128
#define NH 8
#define DK 16
#define DFF 512
#define NBUK 32
#define NLAYERS 3
#define KNN_K 10
#define ADJW 17          // 1025 bits -> 17 u64 words per row
#define BSTR 1088        // padded bucket row stride (bytes)
#define NSPLIT 8
#define BIGF 3.0e38f
#define SM_OFF 24.0f     // fixed softmax exponent offset (|s| bounded << 24+88)

// prepacked-weight element offsets (see init_kernel prepack branch)
#define PWQ_OFF 0
#define PWK_OFF 49152
#define PWV_OFF 98304
#define PWO_OFF 147456
#define PW1_OFF 196608
#define PW2_OFF 393216
#define PWOUT_OFF 589824
#define PWQE_OFF 606208
#define PW_TOT 704512

// init kernel block ranges
#define PBLK 344         // ceil(88064/256) prepack
#define NBNODE 1024      // embed node blocks
#define EBLK (NBNODE + BB)
#define BBLK 8713        // ceil(BB*N1*BSTR/256) bucket

// knnsel+qkv merged kernel block ranges
#define KSEL_BLK 512     // BB*NN/4
#define QKV_GX 33
#define QKV_BLK (QKV_GX * 40)
#define OSUM_N (BB * NH * N1 * 16)       // 262400
#define ZTOT (OSUM_N + BB * NH * N1)     // + lsum = 278800

typedef __attribute__((ext_vector_type(8))) short bf8;
typedef __attribute__((ext_vector_type(4))) float f4;
typedef unsigned short u16;
typedef unsigned int u32;

__device__ __forceinline__ u16 f2bf(float x) {
  unsigned u = __float_as_uint(x);
  return (u16)((u + 0x7fff + ((u >> 16) & 1)) >> 16);   // RNE
}
__device__ __forceinline__ float bf2f(u16 u) {
  return __uint_as_float(((unsigned)u) << 16);
}
__device__ __forceinline__ bf8 mk8(ushort4 a, ushort4 b) {
  bf8 r;
  r[0] = (short)a.x; r[1] = (short)a.y; r[2] = (short)a.z; r[3] = (short)a.w;
  r[4] = (short)b.x; r[5] = (short)b.y; r[6] = (short)b.z; r[7] = (short)b.w;
  return r;
}

// ---------------------------------------------------------------- init: prepack + embed(+splits) + bucket
__global__ __launch_bounds__(256) void init_kernel(
    const float* __restrict__ coords, const float* __restrict__ inW,
    const float* __restrict__ inb, const float* __restrict__ gnode,
    const float* __restrict__ Wq, const float* __restrict__ Wk,
    const float* __restrict__ Wv, const float* __restrict__ Wo,
    const float* __restrict__ W1, const float* __restrict__ W2,
    const float* __restrict__ oW, const float* __restrict__ emb,
    u16* __restrict__ PH, u16* __restrict__ PL,
    float* __restrict__ X, u16* __restrict__ XH, u16* __restrict__ XM,
    u16* __restrict__ XL, unsigned char* __restrict__ buckp) {
  int blk = blockIdx.x;
  if (blk < PBLK) {
    // ---------------- prepack (+inline wqe composite)
    int idx = blk * 256 + threadIdx.x;
    if (idx >= 88064) return;
    if (idx >= 75776) {
      int rel = idx - 75776;
      int lane = rel & 63, g = rel >> 6;
      int ks = g & 3, nt = g >> 2;
      int n = nt * 16 + (lane & 15);
      int k = ks * 32 + (lane >> 4) * 8;
      int l = n >> 8; int c = n & 255; int h = c >> 5, bk = c & 31;
      const float* e = emb + ((size_t)l * NBUK + bk) * DM + h * DK;
      const float* wq = Wq + ((size_t)l * DM + h * DK) * DM;
      u16* ph = PH + (size_t)idx * 8;
      u16* pl = PL + (size_t)idx * 8;
      #pragma unroll
      for (int q = 0; q < 8; ++q) {
        float s = 0.f;
        #pragma unroll
        for (int d = 0; d < DK; ++d) s += e[d] * wq[(size_t)d * DM + k + q];
        u16 hh = f2bf(s);
        ph[q] = hh;
        pl[q] = f2bf(s - bf2f(hh));
      }
      return;
    }
    const float* W; int rel, Kdim;
    if (idx < 24576) {
      int seg = idx / 6144; rel = idx % 6144; Kdim = 128;
      W = seg == 0 ? Wq : seg == 1 ? Wk : seg == 2 ? Wv : Wo;
    } else if (idx < 49152) { rel = idx - 24576; Kdim = 128; W = W1; }
    else if (idx < 73728)   { rel = idx - 49152; Kdim = 512; W = W2; }
    else                    { rel = idx - 73728; Kdim = 128; W = oW; }
    int lane = rel & 63;
    int g = rel >> 6;
    int ksteps = Kdim >> 5;
    int ks = g % ksteps, nt = g / ksteps;
    int n = nt * 16 + (lane & 15);
    int k = ks * 32 + (lane >> 4) * 8;
    const float* p = W + (size_t)n * Kdim + k;
    u16* ph = PH + (size_t)idx * 8;
    u16* pl = PL + (size_t)idx * 8;
    #pragma unroll
    for (int q = 0; q < 8; ++q) {
      float x = p[q];
      u16 hh = f2bf(x);
      ph[q] = hh;
      pl[q] = f2bf(x - bf2f(hh));
    }
    return;
  }
  if (blk < PBLK + EBLK) {
    // ---------------- embed (+g row), emitting 3-level splits
    int eb = blk - PBLK;
    if (eb >= NBNODE) {
      int b = eb - NBNODE;
      int t = threadIdx.x;
      if (t >= 128) return;
      int lane = t & 63;
      float sx = 0.f, sy = 0.f;
      for (int n = lane; n < NN; n += 64) {
        float2 c = *(const float2*)(coords + (size_t)(b * NN + n) * 2);
        sx += c.x; sy += c.y;
      }
      #pragma unroll
      for (int o = 1; o < 64; o <<= 1) { sx += __shfl_xor(sx, o); sy += __shfl_xor(sy, o); }
      float mx = sx * (1.0f / NN), my = sy * (1.0f / NN);
      int d = t;
      size_t id = ((size_t)b * N1 + NN) * DM + d;
      float v = gnode[d] + inb[d] + mx * inW[d * 2 + 0] + my * inW[d * 2 + 1];
      X[id] = v;
      u16 hh = f2bf(v); float r1 = v - bf2f(hh);
      u16 mm = f2bf(r1);
      XH[id] = hh; XM[id] = mm; XL[id] = f2bf(r1 - bf2f(mm));
      return;
    }
    int idx = eb * 256 + threadIdx.x;
    if (idx >= BB * NN * DM) return;
    int d = idx % DM; int r = idx / DM; int n = r % NN; int b = r / NN;
    float cx = coords[(b * NN + n) * 2 + 0], cy = coords[(b * NN + n) * 2 + 1];
    size_t id = ((size_t)b * N1 + n) * DM + d;
    float v = cx * inW[d * 2 + 0] + cy * inW[d * 2 + 1] + inb[d];
    X[id] = v;
    u16 hh = f2bf(v); float r1 = v - bf2f(hh);
    u16 mm = f2bf(r1);
    XH[id] = hh; XM[id] = mm; XL[id] = f2bf(r1 - bf2f(mm));
    return;
  }
  // ---------------- bucket (padded rows)
  int idx = (blk - PBLK - EBLK) * 256 + threadIdx.x;
  if (idx >= BB * N1 * BSTR) return;
  int j = idx % BSTR; int r = idx / BSTR; int i = r % N1; int b = r / N1;
  unsigned char v = 0;
  if (j < N1) {
    float xi = 0.f, yi = 0.f, xj = 0.f, yj = 0.f;
    if (i < NN) { xi = coords[(b * NN + i) * 2]; yi = coords[(b * NN + i) * 2 + 1]; }
    if (j < NN) { xj = coords[(b * NN + j) * 2]; yj = coords[(b * NN + j) * 2 + 1]; }
    float dx = xi - xj, dy = yi - yj;
    float dist = sqrtf(dx * dx + dy * dy);
    int bu = (int)(dist * 32.0f);
    bu = bu < 0 ? 0 : (bu > 31 ? 31 : bu);
    v = (unsigned char)bu;
  }
  buckp[idx] = v;
}

// ---------------------------------------------------------------- exact MFMA gram (+adj zero)
__global__ __launch_bounds__(256) void gram_kernel(
    const u16* __restrict__ XH, const u16* __restrict__ XM, const u16* __restrict__ XL,
    unsigned long long* __restrict__ adj, float* __restrict__ d2) {
  __shared__ __align__(16) u16 AsH[32][72];
  __shared__ __align__(16) u16 AsM[32][72];
  __shared__ __align__(16) u16 AsL[32][72];
  __shared__ __align__(16) u16 BsH[64][72];
  __shared__ __align__(16) u16 BsM[64][72];
  __shared__ __align__(16) u16 BsL[64][72];
  __shared__ float sqS[64];               // B-row squared norms
  int b = blockIdx.z;
  int m0 = blockIdx.x * 32, n0 = blockIdx.y * 64;
  size_t boff = (size_t)b * N1;
  int t = threadIdx.x;

  // zero adjacency (1024 blocks x 256 thr covers 34850 u64 words)
  {
    int flat = blockIdx.x + 32 * (blockIdx.y + 16 * blockIdx.z);
    int tid = flat * 256 + t;
    if (tid < BB * N1 * ADJW) adj[tid] = 0ull;
  }

  int lane = t & 63, w = t >> 6;
  int wm = (w >> 1) * 16, wn = (w & 1) * 32;
  int quad = lane >> 4, r16 = lane & 15;

  f4 acc0 = {0.f, 0.f, 0.f, 0.f}, acc1 = {0.f, 0.f, 0.f, 0.f};
  int ar = t >> 3, as_ = (t & 7) * 8;     // A: 32 rows x 8 segs of 8
  int br = t >> 2, bs_ = (t & 3) * 16;    // B: 64 rows x 4 segs of 16
  int sqrow = t >> 2, sqk = (t & 3) * 16; // sq: 64 rows x 4 threads x 16 elems
  float mySq = 0.f;

  for (int k0 = 0; k0 < DM; k0 += 64) {
    {
      size_t src = (boff + m0 + ar) * DM + k0 + as_;
      *(bf8*)&AsH[ar][as_] = *(const bf8*)(XH + src);
      *(bf8*)&AsM[ar][as_] = *(const bf8*)(XM + src);
      *(bf8*)&AsL[ar][as_] = *(const bf8*)(XL + src);
    }
    {
      size_t src = (boff + n0 + br) * DM + k0 + bs_;
      *(bf8*)&BsH[br][bs_] = *(const bf8*)(XH + src);
      *(bf8*)&BsH[br][bs_ + 8] = *(const bf8*)(XH + src + 8);
      *(bf8*)&BsM[br][bs_] = *(const bf8*)(XM + src);
      *(bf8*)&BsM[br][bs_ + 8] = *(const bf8*)(XM + src + 8);
      *(bf8*)&BsL[br][bs_] = *(const bf8*)(XL + src);
      *(bf8*)&BsL[br][bs_ + 8] = *(const bf8*)(XL + src + 8);
    }
    __syncthreads();
    #pragma unroll
    for (int ks = 0; ks < 64; ks += 16) {
      int seg = (quad & 1) * 8;
      bf8 aHM = *(const bf8*)((quad < 2) ? &AsH[wm + r16][ks + seg] : &AsM[wm + r16][ks + seg]);
      bf8 aHL = *(const bf8*)((quad < 2) ? &AsH[wm + r16][ks + seg] : &AsL[wm + r16][ks + seg]);
      #pragma unroll
      for (int tt = 0; tt < 2; ++tt) {
        int nr = wn + tt * 16 + r16;
        bf8 bH = *(const bf8*)&BsH[nr][ks + seg];
        bf8 bM = *(const bf8*)&BsM[nr][ks + seg];
        bf8 b3 = *(const bf8*)((quad < 2) ? &BsL[nr][ks + seg] : &BsH[nr][ks + seg]);
        f4& a = tt ? acc1 : acc0;
        a = __builtin_amdgcn_mfma_f32_16x16x32_bf16(aHM, bH, a, 0, 0, 0);  // HH' + MH'
        a = __builtin_amdgcn_mfma_f32_16x16x32_bf16(aHM, bM, a, 0, 0, 0);  // HM' + MM'
        a = __builtin_amdgcn_mfma_f32_16x16x32_bf16(aHL, b3, a, 0, 0, 0);  // HL' + LH'
      }
    }
    // parallel B-row sq: vector LDS reads, exact x = H+M+L
    #pragma unroll
    for (int half = 0; half < 2; ++half) {
      bf8 hv = *(const bf8*)&BsH[sqrow][sqk + half * 8];
      bf8 mv = *(const bf8*)&BsM[sqrow][sqk + half * 8];
      bf8 lv = *(const bf8*)&BsL[sqrow][sqk + half * 8];
      #pragma unroll
      for (int q = 0; q < 8; ++q) {
        float x = (bf2f((u16)hv[q]) + bf2f((u16)mv[q])) + bf2f((u16)lv[q]);
        mySq += x * x;
      }
    }
    __syncthreads();
  }
  // reduce 4 partials per row (threads row*4+jj adjacent in wave)
  mySq += __shfl_xor(mySq, 1);
  mySq += __shfl_xor(mySq, 2);
  if ((t & 3) == 0) sqS[sqrow] = mySq;
  __syncthreads();

  #pragma unroll
  for (int tt = 0; tt < 2; ++tt) {
    f4 a = tt ? acc1 : acc0;
    int nl = wn + tt * 16 + r16;
    int n = n0 + nl;
    float sj = sqS[nl];
    #pragma unroll
    for (int reg = 0; reg < 4; ++reg) {
      int m = m0 + wm + quad * 4 + reg;
      float v = (m == n) ? BIGF : (sj - 2.f * a[reg]);
      d2[((size_t)b * NN + m) * NN + n] = v;
    }
  }
}

// ---------------------------------------------------------------- merged: knnsel || qkv+qe (+Osum zero)
__global__ __launch_bounds__(256) void knnqkv_kernel(
    const float* __restrict__ d2, unsigned long long* __restrict__ adj,
    const u16* __restrict__ AH, const u16* __restrict__ AL,
    const u16* __restrict__ Pbase_H, const u16* __restrict__ Pbase_L,
    size_t offQ, size_t offK, size_t offV, size_t offE,
    u16* __restrict__ QH, u16* __restrict__ QL,
    u16* __restrict__ KH, u16* __restrict__ KL, u16* __restrict__ Vbf,
    float* __restrict__ qe_all, float* __restrict__ zbuf, int M) {
  __shared__ float dd[4][NN];
  // zero Osum+lsum accumulators (read by attn after this kernel completes)
  {
    int ztid = blockIdx.x * 256 + threadIdx.x;
    if (ztid < ZTOT) zbuf[ztid] = 0.f;
  }
  int blk = blockIdx.x;
  if (blk < KSEL_BLK) {
    // ---------------- knnsel (verbatim)
    int b = blk / (NN / 4);
    int i0 = (blk % (NN / 4)) * 4;
    int t = threadIdx.x, lane = t & 63, w = t >> 6;

    const float4* src = (const float4*)(d2 + ((size_t)b * NN + i0) * NN);
    float4* dst = (float4*)&dd[0][0];
    #pragma unroll
    for (int x = 0; x < 4; ++x) dst[t + x * 256] = src[t + x * 256];
    __syncthreads();

    int i = i0 + w;
    for (int it = 0; it < KNN_K; ++it) {
      float bv = BIGF; int bi = 0x3fffffff;
      for (int j = lane; j < NN; j += 64) {
        float v = dd[w][j];
        if (v < bv) { bv = v; bi = j; }
      }
      #pragma unroll
      for (int o = 1; o < 64; o <<= 1) {
        float ov = __shfl_xor(bv, o); int oi = __shfl_xor(bi, o);
        if (ov < bv || (ov == bv && oi < bi)) { bv = ov; bi = oi; }
      }
      if (lane == 0) {
        dd[w][bi] = BIGF;
        atomicOr(&adj[((size_t)b * N1 + i) * ADJW + (bi >> 6)], 1ull << (bi & 63));
        atomicOr(&adj[((size_t)b * N1 + bi) * ADJW + (i >> 6)], 1ull << (i & 63));
      }
    }
    return;
  }
  // ---------------- qkv+qe (verbatim, flattened grid)
  int rel = blk - KSEL_BLK;
  int gx = rel % QKV_GX;
  int y = rel / QKV_GX;
  int z, nt;
  if (y < 8) { z = 0; nt = y; }
  else if (y < 16) { z = 1; nt = y - 8; }
  else if (y < 24) { z = 2; nt = y - 16; }
  else { z = 3; nt = y - 24; }
  size_t woff = z == 0 ? offQ : (z == 1 ? offK : (z == 2 ? offV : offE));
  const u16* PH = Pbase_H + woff;
  const u16* PL = Pbase_L + woff;
  int lane = threadIdx.x & 63;
  int quad = lane >> 4, r16 = lane & 15;
  int mt = gx * 4 + (threadIdx.x >> 6);
  f4 acc = {0.f, 0.f, 0.f, 0.f};
  int m0 = mt * 16;
  int mrow = m0 + r16; if (mrow >= M) mrow = M - 1;
  const u16* aph = AH + (size_t)mrow * DM + quad * 8;
  const u16* apl = AL + (size_t)mrow * DM + quad * 8;
  const u16* ph = PH + ((size_t)nt * 4 * 64 + lane) * 8;
  const u16* pl = PL + ((size_t)nt * 4 * 64 + lane) * 8;
  #pragma unroll
  for (int ks = 0; ks < 4; ++ks) {
    bf8 aH = *(const bf8*)(aph);
    bf8 aL = *(const bf8*)(apl);
    aph += 32; apl += 32;
    bf8 bH = *(const bf8*)(ph + (size_t)ks * 512);
    bf8 bL = *(const bf8*)(pl + (size_t)ks * 512);
    acc = __builtin_amdgcn_mfma_f32_16x16x32_bf16(aH, bH, acc, 0, 0, 0);
    acc = __builtin_amdgcn_mfma_f32_16x16x32_bf16(aH, bL, acc, 0, 0, 0);
    acc = __builtin_amdgcn_mfma_f32_16x16x32_bf16(aL, bH, acc, 0, 0, 0);
  }
  if (m0 >= M) return;
  int n = nt * 16 + r16;
  #pragma unroll
  for (int reg = 0; reg < 4; ++reg) {
    int m = m0 + quad * 4 + reg;
    if (m >= M) continue;
    float v = acc[reg];
    if (z == 3) {
      int b = m / N1, nr = m % N1;
      int h = n >> 5, bk = n & 31;
      qe_all[(((size_t)b * NH + h) * N1 + nr) * 32 + bk] = v;
      continue;
    }
    size_t oi = (size_t)m * DM + n;
    if (z == 0) {
      float sv = v * 0.25f;
      u16 hh = f2bf(sv);
      QH[oi] = hh;
      QL[oi] = f2bf(sv - bf2f(hh));
    } else if (z == 1) {
      u16 hh = f2bf(v);
      KH[oi] = hh;
      KL[oi] = f2bf(v - bf2f(hh));
    } else {
      Vbf[oi] = f2bf(v);
    }
  }
}

// ---------------------------------------------------------------- direct-fragment GEMM (16x16/wave)
__device__ __forceinline__ void gemm_dev16(
    const u16* __restrict__ AH, const u16* __restrict__ AL,
    const u16* __restrict__ PH, const u16* __restrict__ PL,
    const float* __restrict__ bias, const float* __restrict__ res,
    float* __restrict__ outF, u16* __restrict__ outH, u16* __restrict__ outL,
    int M, int Kdim, int Nout, int relu, int mt, int nt) {
  int lane = threadIdx.x & 63;
  int quad = lane >> 4, r16 = lane & 15;
  int ksteps = Kdim >> 5;
  f4 acc = {0.f, 0.f, 0.f, 0.f};

  int m0 = mt * 16;
  int mrow = m0 + r16; if (mrow >= M) mrow = M - 1;   // clamp; result discarded
  const u16* aph = AH + (size_t)mrow * Kdim + quad * 8;
  const u16* apl = AL + (size_t)mrow * Kdim + quad * 8;
  const u16* ph = PH + ((size_t)nt * ksteps * 64 + lane) * 8;
  const u16* pl = PL + ((size_t)nt * ksteps * 64 + lane) * 8;

  #pragma unroll 4
  for (int ks = 0; ks < ksteps; ++ks) {
    bf8 aH = *(const bf8*)(aph);
    bf8 aL = *(const bf8*)(apl);
    aph += 32; apl += 32;
    bf8 bH = *(const bf8*)(ph + (size_t)ks * 512);
    bf8 bL = *(const bf8*)(pl + (size_t)ks * 512);
    acc = __builtin_amdgcn_mfma_f32_16x16x32_bf16(aH, bH, acc, 0, 0, 0);
    acc = __builtin_amdgcn_mfma_f32_16x16x32_bf16(aH, bL, acc, 0, 0, 0);
    acc = __builtin_amdgcn_mfma_f32_16x16x32_bf16(aL, bH, acc, 0, 0, 0);
  }

  if (m0 >= M) return;
  int n = nt * 16 + r16;
  #pragma unroll
  for (int reg = 0; reg < 4; ++reg) {
    int m = m0 + quad * 4 + reg;    // C layout: col=lane&15, row=quad*4+reg
    if (m < M) {
      float v = acc[reg];
      if (bias) v += bias[n];
      if (relu) v = fmaxf(v, 0.f);
      if (res) v += res[(size_t)m * Nout + n];
      size_t oi = (size_t)m * Nout + n;
      if (outF) outF[oi] = v;
      if (outH) {
        u16 hh = f2bf(v);
        outH[oi] = hh;
        outL[oi] = f2bf(v - bf2f(hh));
      }
    }
  }
}

__global__ __launch_bounds__(256) void gemm_kernel(
    const u16* __restrict__ AH, const u16* __restrict__ AL,
    const u16* __restrict__ PH, const u16* __restrict__ PL,
    const float* __restrict__ bias, const float* __restrict__ res,
    float* __restrict__ outF, u16* __restrict__ outH, u16* __restrict__ outL,
    int M, int Kdim, int Nout, int relu) {
  gemm_dev16(AH, AL, PH, PL, bias, res, outF, outH, outL, M, Kdim, Nout, relu,
             blockIdx.x * 4 + (threadIdx.x >> 6), blockIdx.y);
}

// ---------------------------------------------------------------- Wo GEMM: A = Osum/lsum inline
__global__ __launch_bounds__(256) void gemm_wo_kernel(
    const float* __restrict__ Osum, const float* __restrict__ lsum,
    const u16* __restrict__ PH, const u16* __restrict__ PL,
    const float* __restrict__ res, float* __restrict__ outF, int M) {
  int lane = threadIdx.x & 63;
  int quad = lane >> 4, r16 = lane & 15;
  int mt = blockIdx.x * 4 + (threadIdx.x >> 6), nt = blockIdx.y;
  f4 acc = {0.f, 0.f, 0.f, 0.f};
  int m0 = mt * 16;
  int mrow = m0 + r16; if (mrow >= M) mrow = M - 1;
  int b = mrow / N1, nr = mrow % N1;
  const u16* ph = PH + ((size_t)nt * 4 * 64 + lane) * 8;
  const u16* pl = PL + ((size_t)nt * 4 * 64 + lane) * 8;
  #pragma unroll
  for (int ks = 0; ks < 4; ++ks) {
    int k = ks * 32 + quad * 8;
    int h = k >> 4, d0 = k & 15;
    size_t base = (size_t)(b * NH + h) * N1 + nr;
    float inv = 1.0f / lsum[base];
    const float* op = Osum + base * 16 + d0;
    bf8 aH, aL;
    #pragma unroll
    for (int j = 0; j < 8; ++j) {
      float v = op[j] * inv;
      u16 hh = f2bf(v);
      aH[j] = (short)hh;
      aL[j] = (short)f2bf(v - bf2f(hh));
    }
    bf8 bH = *(const bf8*)(ph + (size_t)ks * 512);
    bf8 bL = *(const bf8*)(pl + (size_t)ks * 512);
    acc = __builtin_amdgcn_mfma_f32_16x16x32_bf16(aH, bH, acc, 0, 0, 0);
    acc = __builtin_amdgcn_mfma_f32_16x16x32_bf16(aH, bL, acc, 0, 0, 0);
    acc = __builtin_amdgcn_mfma_f32_16x16x32_bf16(aL, bH, acc, 0, 0, 0);
  }
  if (m0 >= M) return;
  int n = nt * 16 + r16;
  #pragma unroll
  for (int reg = 0; reg < 4; ++reg) {
    int m = m0 + quad * 4 + reg;
    if (m < M) outF[(size_t)m * DM + n] = acc[reg] + res[(size_t)m * DM + n];
  }
}

// ---------------------------------------------------------------- MFMA flash attention, key-split
// Fixed-offset softmax; partials accumulated atomically into Osum/lsum (no combine pass).
#define CH 64
#define NCH 17
__global__ __launch_bounds__(128) void attn_kernel(
    const u16* __restrict__ QH, const u16* __restrict__ QL,
    const u16* __restrict__ KH, const u16* __restrict__ KL,
    const u16* __restrict__ Vbf, const float* __restrict__ qe_all,
    const unsigned char* __restrict__ buckp, const unsigned long long* __restrict__ adj,
    float* __restrict__ Osum, float* __restrict__ lsum) {
  __shared__ __align__(16) u16 KsHi[2][CH][20];
  __shared__ __align__(16) u16 KsLo[2][CH][20];
  __shared__ __align__(16) u16 Vt[2][DK][68];
  __shared__ __align__(16) u16 Ps[2][16][72];
  __shared__ __align__(16) float qe_s[2][16][36];
  __shared__ u32 maskS[32][6];
  __shared__ unsigned char buckS[2][32][68];

  int qt = blockIdx.x;
  int h = blockIdx.y & 7, b = blockIdx.y >> 3;
  int s = blockIdx.z;
  int c0 = (NCH * s) / NSPLIT, c1 = (NCH * (s + 1)) / NSPLIT;
  int nwm = 2 * (c1 - c0);
  int t = threadIdx.x, lane = t & 63, w = t >> 6;
  int quad = lane >> 4, r16 = lane & 15;
  int i0 = qt * 32;
  int iw = i0 + w * 16;
  int bh = b * NH + h;

  // mask words inline (== old connb output, bit-exact)
  for (int x = t; x < 32 * nwm; x += 128) {
    int rr = x / nwm, ww = x % nwm;
    int gi = i0 + rr; if (gi > NN) gi = NN;
    int W = 2 * c0 + ww;
    u32 v;
    if (gi == 0 || gi == NN) {
      v = 0xffffffffu;
    } else {
      const u32* a32 = (const u32*)(adj + ((size_t)b * N1 + gi) * ADJW);
      v = a32[W];
      int bs = gi & ~127;
      int lo = gi - 11 < bs ? bs : gi - 11;
      int be = bs + 127;
      int hi = gi + 11 > be ? be : gi + 11;
      int aa = lo - 32 * W, bnd = hi - 32 * W;
      if (aa < 0) aa = 0; if (bnd > 31) bnd = 31;
      if (aa <= bnd) v |= (0xffffffffu << aa) & (0xffffffffu >> (31 - bnd));
      if (W == 0) v |= 1u;
      if (W == 32) v |= 1u;
      int dg = gi - 32 * W;
      if (dg >= 0 && dg < 32) v |= 1u << dg;
    }
    if (W == 32) v &= 1u;
    else if (W == 33) v = 0u;
    maskS[rr][ww] = v;
  }
  // qe table: per-row clamped load
  #pragma unroll
  for (int e = 0; e < 2; ++e) {
    int x = lane + e * 64;
    int rr = x >> 3, bk = (x & 7) * 4;
    int gi = iw + rr; if (gi > NN) gi = NN;
    f4 v = *(const f4*)(qe_all + (((size_t)b * NH + h) * N1 + gi) * 32 + bk);
    *(f4*)&qe_s[w][rr][bk] = v;
  }
  bf8 qfrag;
  {
    int gi = iw + r16; if (gi > NN) gi = NN;
    const u16* qsrc = (quad < 2 ? QH : QL) + ((size_t)(b * N1 + gi) * DM + h * DK + (quad & 1) * 8);
    qfrag = *(const bf8*)qsrc;
  }

  ushort4 khr[2], klr[2], vvr[2]; u32 bkr[4];
  auto load_chunk = [&](int c) {
    int j0 = c * CH;
    #pragma unroll
    for (int ii = 0; ii < 2; ++ii) {
      int x = t + ii * 128;
      int key = x >> 2, ds = (x & 3) * 4;
      int jg = j0 + key; if (jg > NN) jg = NN;
      size_t src = (size_t)(b * N1 + jg) * DM + h * DK + ds;
      khr[ii] = *(const ushort4*)(KH + src);
      klr[ii] = *(const ushort4*)(KL + src);
      vvr[ii] = *(const ushort4*)(Vbf + src);
    }
    #pragma unroll
    for (int ii = 0; ii < 4; ++ii) {
      int x = t + ii * 128;
      int rr = x >> 4, c4 = (x & 15) * 4;
      int gi = i0 + rr; if (gi > NN) gi = NN;
      bkr[ii] = *(const u32*)(buckp + ((size_t)b * N1 + gi) * BSTR + j0 + c4);
    }
  };
  auto store_chunk = [&](int pb) {
    #pragma unroll
    for (int ii = 0; ii < 2; ++ii) {
      int x = t + ii * 128;
      int key = x >> 2, ds = (x & 3) * 4;
      *(ushort4*)&KsHi[pb][key][ds] = khr[ii];
      *(ushort4*)&KsLo[pb][key][ds] = klr[ii];
      Vt[pb][ds + 0][key] = vvr[ii].x;
      Vt[pb][ds + 1][key] = vvr[ii].y;
      Vt[pb][ds + 2][key] = vvr[ii].z;
      Vt[pb][ds + 3][key] = vvr[ii].w;
    }
    #pragma unroll
    for (int ii = 0; ii < 4; ++ii) {
      int x = t + ii * 128;
      int rr = x >> 4, c4 = (x & 15) * 4;
      *(u32*)&buckS[pb][rr][c4] = bkr[ii];
    }
  };

  f4 Oacc = {0.f, 0.f, 0.f, 0.f};
  float lrun[4] = {0.f, 0.f, 0.f, 0.f};

  load_chunk(c0);
  store_chunk(0);

  for (int c = c0; c < c1; ++c) {
    int pb = (c - c0) & 1;
    bool pf = (c + 1 < c1);
    if (pf) load_chunk(c + 1);
    __syncthreads();

    f4 S[4];
    #pragma unroll
    for (int tt = 0; tt < 4; ++tt) {
      int key = tt * 16 + r16;
      int off = (quad & 1) * 8;
      bf8 bhv = mk8(*(const ushort4*)&KsHi[pb][key][off], *(const ushort4*)&KsHi[pb][key][off + 4]);
      bf8 blv = mk8(*(const ushort4*)&KsLo[pb][key][off], *(const ushort4*)&KsLo[pb][key][off + 4]);
      f4 z = {0.f, 0.f, 0.f, 0.f};
      z = __builtin_amdgcn_mfma_f32_16x16x32_bf16(qfrag, bhv, z, 0, 0, 0);
      z = __builtin_amdgcn_mfma_f32_16x16x32_bf16(qfrag, blv, z, 0, 0, 0);
      S[tt] = z;
    }

    #pragma unroll
    for (int rg = 0; rg < 4; ++rg) {
      int rowb = w * 16 + quad * 4 + rg;
      u32 mw0 = maskS[rowb][2 * (c - c0)];
      u32 mw1 = maskS[rowb][2 * (c - c0) + 1];
      float ps = 0.f;
      #pragma unroll
      for (int tt = 0; tt < 4; ++tt) {
        u32 mword = (tt & 2) ? mw1 : mw0;
        int bit = (tt & 1) * 16 + r16;
        int bk = buckS[pb][rowb][tt * 16 + r16] & 31;
        float rel = qe_s[w][quad * 4 + rg][bk];
        float sc = S[tt][rg] + rel;
        sc += ((mword >> bit) & 1u) ? 0.f : -1.0e9f;
        float p = __expf(sc - SM_OFF);
        ps += p;
        Ps[w][quad * 4 + rg][tt * 16 + r16] = f2bf(p);
      }
      #pragma unroll
      for (int o = 1; o < 16; o <<= 1) ps += __shfl_xor(ps, o);
      lrun[rg] += ps;
    }
    #pragma unroll
    for (int half = 0; half < 2; ++half) {
      bf8 pa = *(const bf8*)&Ps[w][r16][half * 32 + quad * 8];
      bf8 vb = mk8(*(const ushort4*)&Vt[pb][r16][half * 32 + quad * 8],
                   *(const ushort4*)&Vt[pb][r16][half * 32 + quad * 8 + 4]);
      Oacc = __builtin_amdgcn_mfma_f32_16x16x32_bf16(pa, vb, Oacc, 0, 0, 0);
    }

    if (pf) store_chunk(pb ^ 1);
  }

  // atomic-accumulate unnormalized partials (plain sums under fixed-offset softmax)
  #pragma unroll
  for (int rg = 0; rg < 4; ++rg) {
    int gi = i0 + w * 16 + quad * 4 + rg;
    if (gi < N1) {
      size_t base = (size_t)bh * N1 + gi;
      atomicAdd(&Osum[base * 16 + r16], Oacc[rg]);
      if (r16 == 0) atomicAdd(&lsum[base], lrun[rg]);
    }
  }
}

// ---------------------------------------------------------------- instance norm (+pool/g, +split emit)
// oM==nullptr: no emit; oL==nullptr: 2-level (oH,oM as hi/lo); else 3-level (oH,oM,oL)
__global__ void inorm_kernel(float* __restrict__ X, const float* __restrict__ w,
                             const float* __restrict__ b_, float* __restrict__ pool,
                             int do_g, u16* __restrict__ oH, u16* __restrict__ oM,
                             u16* __restrict__ oL) {
  int d = blockIdx.x; int bb = blockIdx.y; int lane = threadIdx.x;
  float g_old = X[((size_t)bb * N1 + NN) * DM + d];
  float s = 0.f;
  for (int n = lane; n < N1; n += 64) s += X[((size_t)bb * N1 + n) * DM + d];
  #pragma unroll
  for (int o = 1; o < 64; o <<= 1) s += __shfl_xor(s, o);
  float mu = s * (1.0f / N1);
  float v = 0.f;
  for (int n = lane; n < N1; n += 64) {
    float tt = X[((size_t)bb * N1 + n) * DM + d] - mu;
    v += tt * tt;
  }
  #pragma unroll
  for (int o = 1; o < 64; o <<= 1) v += __shfl_xor(v, o);
  float var = v * (1.0f / N1);
  float scv = rsqrtf(var + 1e-5f) * w[d];
  float sh = b_[d];
  for (int n = lane; n < N1; n += 64) {
    size_t id = ((size_t)bb * N1 + n) * DM + d;
    float nv = (X[id] - mu) * scv + sh;
    X[id] = nv;
    if (oH) {
      u16 hh = f2bf(nv); float r1 = nv - bf2f(hh);
      u16 mm = f2bf(r1);
      oH[id] = hh;
      oM[id] = mm;
      if (oL) oL[id] = f2bf(r1 - bf2f(mm));
    }
  }
  if (lane == 0) {
    float hmean = ((s - g_old) * (1.0f / NN) - mu) * scv + sh;
    if (pool) pool[bb * DM + d] = hmean;
    if (do_g) X[((size_t)bb * N1 + NN) * DM + d] += hmean;
  }
}

// ---------------------------------------------------------------- final GEMM (inline h+pm split, +out_pm)
__global__ __launch_bounds__(256) void gemm_final_kernel(
    const float* __restrict__ X, const float* __restrict__ pools,
    const u16* __restrict__ PH, const u16* __restrict__ PL,
    const float* __restrict__ bias, float* __restrict__ out, float* __restrict__ out_pm) {
  int t = threadIdx.x;
  if (blockIdx.x == 0 && blockIdx.y == 0) {
    float pmv = (pools[t] + pools[BB * DM + t] + pools[2 * BB * DM + t]) * (1.0f / 3.0f);
    out_pm[t] = pmv;
  }
  int lane = t & 63;
  int quad = lane >> 4, r16 = lane & 15;
  int mt = blockIdx.x * 4 + (t >> 6), nt = blockIdx.y;
  const int M = BB * NN;
  f4 acc = {0.f, 0.f, 0.f, 0.f};
  int m0 = mt * 16;
  int mrow = m0 + r16; if (mrow >= M) mrow = M - 1;
  int mb = mrow / NN, mn = mrow % NN;
  const float* xp = X + ((size_t)mb * N1 + mn) * DM + quad * 8;
  const float* pp = pools + mb * DM + quad * 8;
  const u16* ph = PH + ((size_t)nt * 4 * 64 + lane) * 8;
  const u16* pl = PL + ((size_t)nt * 4 * 64 + lane) * 8;
  #pragma unroll
  for (int ks = 0; ks < 4; ++ks) {
    bf8 aH, aL;
    #pragma unroll
    for (int half = 0; half < 2; ++half) {
      float4 xv = *(const float4*)(xp + ks * 32 + half * 4);
      float4 p0 = *(const float4*)(pp + ks * 32 + half * 4);
      float4 p1 = *(const float4*)(pp + BB * DM + ks * 32 + half * 4);
      float4 p2 = *(const float4*)(pp + 2 * BB * DM + ks * 32 + half * 4);
      float av[4] = {xv.x + (p0.x + p1.x + p2.x) * (1.0f / 3.0f),
                     xv.y + (p0.y + p1.y + p2.y) * (1.0f / 3.0f),
                     xv.z + (p0.z + p1.z + p2.z) * (1.0f / 3.0f),
                     xv.w + (p0.w + p1.w + p2.w) * (1.0f / 3.0f)};
      #pragma unroll
      for (int q = 0; q < 4; ++q) {
        u16 hh = f2bf(av[q]);
        aH[half * 4 + q] = (short)hh;
        aL[half * 4 + q] = (short)f2bf(av[q] - bf2f(hh));
      }
    }
    bf8 bH = *(const bf8*)(ph + (size_t)ks * 512);
    bf8 bL = *(const bf8*)(pl + (size_t)ks * 512);
    acc = __builtin_amdgcn_mfma_f32_16x16x32_bf16(aH, bH, acc, 0, 0, 0);
    acc = __builtin_amdgcn_mfma_f32_16x16x32_bf16(aH, bL, acc, 0, 0, 0);
    acc = __builtin_amdgcn_mfma_f32_16x16x32_bf16(aL, bH, acc, 0, 0, 0);
  }
  int n = nt * 16 + r16;
  #pragma unroll
  for (int reg = 0; reg < 4; ++reg) {
    int m = m0 + quad * 4 + reg;
    if (m < M) out[(size_t)m * DM + n] = acc[reg] + bias[n];
  }
}

// ================================================================ launch
extern "C" void kernel_launch(void* const* d_in, const int* in_sizes, int n_in,
                              void* d_out, int out_size, void* d_ws, size_t ws_size,
                              hipStream_t stream) {
  const float* coords = (const float*)d_in[0];
  const float* inW    = (const float*)d_in[1];
  const float* inb    = (const float*)d_in[2];
  const float* gnode  = (const float*)d_in[3];
  const float* Wq     = (const float*)d_in[4];
  const float* Wk     = (const float*)d_in[5];
  const float* Wv     = (const float*)d_in[6];
  const float* Wo     = (const float*)d_in[7];
  const float* emb    = (const float*)d_in[8];
  const float* W1     = (const float*)d_in[9];
  const float* b1     = (const float*)d_in[10];
  const float* W2     = (const float*)d_in[11];
  const float* b2     = (const float*)d_in[12];
  const float* n1w    = (const float*)d_in[13];
  const float* n1b    = (const float*)d_in[14];
  const float* n2w    = (const float*)d_in[15];
  const float* n2b    = (const float*)d_in[16];
  const float* outW   = (const float*)d_in[17];
  const float* outb   = (const float*)d_in[18];
  float* out = (float*)d_out;

  char* wsp = (char*)d_ws;
  size_t off = 0;
  auto alloc = [&](size_t bytes) -> void* {
    off = (off + 255) & ~(size_t)255;
    void* p = wsp + off;
    off += bytes;
    return p;
  };
  const size_t XB = (size_t)BB * N1 * DM * 4;       // fp32 activation buffer
  const size_t HB = (size_t)BB * N1 * DM * 2;       // u16 half buffer
  float* X0   = (float*)alloc(XB);
  float* X1   = (float*)alloc(XB);
  float* Yb   = (float*)alloc(XB);
  u16* XH = (u16*)alloc(HB); u16* XM = (u16*)alloc(HB); u16* XL = (u16*)alloc(HB);
  u16* QH = (u16*)alloc(HB); u16* QL = (u16*)alloc(HB);
  u16* KH = (u16*)alloc(HB); u16* KL = (u16*)alloc(HB);
  u16* Vbf = (u16*)alloc(HB);
  u16* YbH = (u16*)alloc(HB); u16* YbL = (u16*)alloc(HB);
  u16* FbH = (u16*)alloc((size_t)BB * N1 * DFF * 2);
  u16* FbL = (u16*)alloc((size_t)BB * N1 * DFF * 2);
  unsigned char* buckp = (unsigned char*)alloc((size_t)BB * N1 * BSTR);
  unsigned long long* adj = (unsigned long long*)alloc((size_t)BB * N1 * ADJW * 8);
  float* pools = (float*)alloc((size_t)NLAYERS * BB * DM * 4);
  float* qe_all = (float*)alloc((size_t)BB * NH * N1 * 32 * 4);
  float* zbuf = (float*)alloc((size_t)ZTOT * 4);    // Osum + lsum accumulators
  u16* PH = (u16*)alloc((size_t)PW_TOT * 2);
  u16* PL = (u16*)alloc((size_t)PW_TOT * 2);
  float* d2 = (float*)alloc((size_t)BB * NN * NN * 4);

  float* Osum = zbuf;
  float* lsum = zbuf + OSUM_N;

  init_kernel<<<PBLK + EBLK + BBLK, 256, 0, stream>>>(
      coords, inW, inb, gnode, Wq, Wk, Wv, Wo, W1, W2, outW, emb,
      PH, PL, X0, XH, XM, XL, buckp);

  float* Xin = X0; float* Xout = X1;
  const int M = BB * N1;
  const int GX = 33;     // ceil(129 m-tiles / 4 waves)
  for (int l = 0; l < NLAYERS; ++l) {
    gram_kernel<<<dim3(32, 16, BB), 256, 0, stream>>>(XH, XM, XL, adj, d2);

    // knnsel || qkv (independent) merged; also zeroes Osum/lsum for attn
    knnqkv_kernel<<<KSEL_BLK + QKV_BLK, 256, 0, stream>>>(
        d2, adj, XH, XM, PH, PL,
        (size_t)PWQ_OFF + (size_t)l * DM * DM,
        (size_t)PWK_OFF + (size_t)l * DM * DM,
        (size_t)PWV_OFF + (size_t)l * DM * DM,
        (size_t)PWQE_OFF + (size_t)l * 256 * DM,
        QH, QL, KH, KL, Vbf, qe_all, zbuf, M);

    attn_kernel<<<dim3(33, NH * BB, NSPLIT), 128, 0, stream>>>(
        QH, QL, KH, KL, Vbf, qe_all, buckp, adj, Osum, lsum);

    gemm_wo_kernel<<<dim3(GX, 8), 256, 0, stream>>>(
        Osum, lsum, PH + PWO_OFF + (size_t)l * DM * DM, PL + PWO_OFF + (size_t)l * DM * DM,
        Xin, Yb, M);
    inorm_kernel<<<dim3(DM, BB), 64, 0, stream>>>(Yb, n1w + l * DM, n1b + l * DM,
                                                  nullptr, 0, YbH, YbL, nullptr);

    gemm_kernel<<<dim3(GX, 32), 256, 0, stream>>>(
        YbH, YbL, PH + PW1_OFF + (size_t)l * DFF * DM, PL + PW1_OFF + (size_t)l * DFF * DM,
        b1 + l * DFF, nullptr, nullptr, FbH, FbL, M, DM, DFF, 1);
    gemm_kernel<<<dim3(GX, 8), 256, 0, stream>>>(
        FbH, FbL, PH + PW2_OFF + (size_t)l * DM * DFF, PL + PW2_OFF + (size_t)l * DM * DFF,
        b2 + l * DM, Yb, Xout, nullptr, nullptr, M, DFF, DM, 0);
    // inorm2 emits next layer's 3-level X splits inline
    inorm_kernel<<<dim3(DM, BB), 64, 0, stream>>>(Xout, n2w + l * DM, n2b + l * DM,
                                                  pools + (size_t)l * BB * DM, 1,
                                                  XH, XM, XL);

    float* t2 = Xin; Xin = Xout; Xout = t2;
  }

  gemm_final_kernel<<<dim3(32, 8), 256, 0, stream>>>(
      Xin, pools, PH + PWOUT_OFF, PL + PWOUT_OFF, outb, out, out + (size_t)BB * NN * DM);
}

// Round 18
// 422.308 us; speedup vs baseline: 1.2551x; 1.1073x over previous
//
#include <hip/hip_runtime.h>

#define BB 2
#define NN 1024
#define N1 1025
#define DM 128
#define NH 8
#define DK 16
#define DFF 512
#define NBUK 32
#define NLAYERS 3
#define KNN_K 10
#define ADJW 17          // 1025 bits -> 17 u64 words per row
#define BSTR 1088        // padded bucket row stride (bytes)
#define NSPLIT 8
#define BIGF 3.0e38f
#define SM_OFF 24.0f     // fixed softmax exponent offset (|s| bounded << 24+88)

// prepacked-weight element offsets (see init_kernel prepack branch)
#define PWQ_OFF 0
#define PWK_OFF 49152
#define PWV_OFF 98304
#define PWO_OFF 147456
#define PW1_OFF 196608
#define PW2_OFF 393216
#define PWOUT_OFF 589824
#define PWQE_OFF 606208
#define PW_TOT 704512

// init kernel block ranges
#define PBLK 344         // ceil(88064/256) prepack
#define NBNODE 1024      // embed node blocks
#define EBLK (NBNODE + BB)
#define BBLK 8713        // ceil(BB*N1*BSTR/256) bucket

// knnsel+qkv merged kernel block ranges
#define KSEL_BLK 512     // BB*NN/4
#define QKV_GX 33
#define QKV_BLK (QKV_GX * 40)
#define OSUM_N (BB * NH * N1 * 16)       // 262400
#define LSUM_N (BB * NH * N1)            // 16400
#define STAT_N (BB * DM)                 // 256
#define ZTOT (OSUM_N + LSUM_N + 2 * STAT_N)   // 279312

typedef __attribute__((ext_vector_type(8))) short bf8;
typedef __attribute__((ext_vector_type(4))) float f4;
typedef unsigned short u16;
typedef unsigned int u32;

__device__ __forceinline__ u16 f2bf(float x) {
  unsigned u = __float_as_uint(x);
  return (u16)((u + 0x7fff + ((u >> 16) & 1)) >> 16);   // RNE
}
__device__ __forceinline__ float bf2f(u16 u) {
  return __uint_as_float(((unsigned)u) << 16);
}
__device__ __forceinline__ bf8 mk8(ushort4 a, ushort4 b) {
  bf8 r;
  r[0] = (short)a.x; r[1] = (short)a.y; r[2] = (short)a.z; r[3] = (short)a.w;
  r[4] = (short)b.x; r[5] = (short)b.y; r[6] = (short)b.z; r[7] = (short)b.w;
  return r;
}

// ---------------------------------------------------------------- init: prepack + embed(+splits) + bucket
__global__ __launch_bounds__(256) void init_kernel(
    const float* __restrict__ coords, const float* __restrict__ inW,
    const float* __restrict__ inb, const float* __restrict__ gnode,
    const float* __restrict__ Wq, const float* __restrict__ Wk,
    const float* __restrict__ Wv, const float* __restrict__ Wo,
    const float* __restrict__ W1, const float* __restrict__ W2,
    const float* __restrict__ oW, const float* __restrict__ emb,
    u16* __restrict__ PH, u16* __restrict__ PL,
    float* __restrict__ X, u16* __restrict__ XH, u16* __restrict__ XM,
    u16* __restrict__ XL, unsigned char* __restrict__ buckp) {
  int blk = blockIdx.x;
  if (blk < PBLK) {
    int idx = blk * 256 + threadIdx.x;
    if (idx >= 88064) return;
    if (idx >= 75776) {
      int rel = idx - 75776;
      int lane = rel & 63, g = rel >> 6;
      int ks = g & 3, nt = g >> 2;
      int n = nt * 16 + (lane & 15);
      int k = ks * 32 + (lane >> 4) * 8;
      int l = n >> 8; int c = n & 255; int h = c >> 5, bk = c & 31;
      const float* e = emb + ((size_t)l * NBUK + bk) * DM + h * DK;
      const float* wq = Wq + ((size_t)l * DM + h * DK) * DM;
      u16* ph = PH + (size_t)idx * 8;
      u16* pl = PL + (size_t)idx * 8;
      #pragma unroll
      for (int q = 0; q < 8; ++q) {
        float s = 0.f;
        #pragma unroll
        for (int d = 0; d < DK; ++d) s += e[d] * wq[(size_t)d * DM + k + q];
        u16 hh = f2bf(s);
        ph[q] = hh;
        pl[q] = f2bf(s - bf2f(hh));
      }
      return;
    }
    const float* W; int rel, Kdim;
    if (idx < 24576) {
      int seg = idx / 6144; rel = idx % 6144; Kdim = 128;
      W = seg == 0 ? Wq : seg == 1 ? Wk : seg == 2 ? Wv : Wo;
    } else if (idx < 49152) { rel = idx - 24576; Kdim = 128; W = W1; }
    else if (idx < 73728)   { rel = idx - 49152; Kdim = 512; W = W2; }
    else                    { rel = idx - 73728; Kdim = 128; W = oW; }
    int lane = rel & 63;
    int g = rel >> 6;
    int ksteps = Kdim >> 5;
    int ks = g % ksteps, nt = g / ksteps;
    int n = nt * 16 + (lane & 15);
    int k = ks * 32 + (lane >> 4) * 8;
    const float* p = W + (size_t)n * Kdim + k;
    u16* ph = PH + (size_t)idx * 8;
    u16* pl = PL + (size_t)idx * 8;
    #pragma unroll
    for (int q = 0; q < 8; ++q) {
      float x = p[q];
      u16 hh = f2bf(x);
      ph[q] = hh;
      pl[q] = f2bf(x - bf2f(hh));
    }
    return;
  }
  if (blk < PBLK + EBLK) {
    int eb = blk - PBLK;
    if (eb >= NBNODE) {
      int b = eb - NBNODE;
      int t = threadIdx.x;
      if (t >= 128) return;
      int lane = t & 63;
      float sx = 0.f, sy = 0.f;
      for (int n = lane; n < NN; n += 64) {
        float2 c = *(const float2*)(coords + (size_t)(b * NN + n) * 2);
        sx += c.x; sy += c.y;
      }
      #pragma unroll
      for (int o = 1; o < 64; o <<= 1) { sx += __shfl_xor(sx, o); sy += __shfl_xor(sy, o); }
      float mx = sx * (1.0f / NN), my = sy * (1.0f / NN);
      int d = t;
      size_t id = ((size_t)b * N1 + NN) * DM + d;
      float v = gnode[d] + inb[d] + mx * inW[d * 2 + 0] + my * inW[d * 2 + 1];
      X[id] = v;
      u16 hh = f2bf(v); float r1 = v - bf2f(hh);
      u16 mm = f2bf(r1);
      XH[id] = hh; XM[id] = mm; XL[id] = f2bf(r1 - bf2f(mm));
      return;
    }
    int idx = eb * 256 + threadIdx.x;
    if (idx >= BB * NN * DM) return;
    int d = idx % DM; int r = idx / DM; int n = r % NN; int b = r / NN;
    float cx = coords[(b * NN + n) * 2 + 0], cy = coords[(b * NN + n) * 2 + 1];
    size_t id = ((size_t)b * N1 + n) * DM + d;
    float v = cx * inW[d * 2 + 0] + cy * inW[d * 2 + 1] + inb[d];
    X[id] = v;
    u16 hh = f2bf(v); float r1 = v - bf2f(hh);
    u16 mm = f2bf(r1);
    XH[id] = hh; XM[id] = mm; XL[id] = f2bf(r1 - bf2f(mm));
    return;
  }
  int idx = (blk - PBLK - EBLK) * 256 + threadIdx.x;
  if (idx >= BB * N1 * BSTR) return;
  int j = idx % BSTR; int r = idx / BSTR; int i = r % N1; int b = r / N1;
  unsigned char v = 0;
  if (j < N1) {
    float xi = 0.f, yi = 0.f, xj = 0.f, yj = 0.f;
    if (i < NN) { xi = coords[(b * NN + i) * 2]; yi = coords[(b * NN + i) * 2 + 1]; }
    if (j < NN) { xj = coords[(b * NN + j) * 2]; yj = coords[(b * NN + j) * 2 + 1]; }
    float dx = xi - xj, dy = yi - yj;
    float dist = sqrtf(dx * dx + dy * dy);
    int bu = (int)(dist * 32.0f);
    bu = bu < 0 ? 0 : (bu > 31 ? 31 : bu);
    v = (unsigned char)bu;
  }
  buckp[idx] = v;
}

// ---------------------------------------------------------------- exact MFMA gram (+adj zero)
__global__ __launch_bounds__(256) void gram_kernel(
    const u16* __restrict__ XH, const u16* __restrict__ XM, const u16* __restrict__ XL,
    unsigned long long* __restrict__ adj, float* __restrict__ d2) {
  __shared__ __align__(16) u16 AsH[32][72];
  __shared__ __align__(16) u16 AsM[32][72];
  __shared__ __align__(16) u16 AsL[32][72];
  __shared__ __align__(16) u16 BsH[64][72];
  __shared__ __align__(16) u16 BsM[64][72];
  __shared__ __align__(16) u16 BsL[64][72];
  __shared__ float sqS[64];
  int b = blockIdx.z;
  int m0 = blockIdx.x * 32, n0 = blockIdx.y * 64;
  size_t boff = (size_t)b * N1;
  int t = threadIdx.x;

  {
    int flat = blockIdx.x + 32 * (blockIdx.y + 16 * blockIdx.z);
    int tid = flat * 256 + t;
    if (tid < BB * N1 * ADJW) adj[tid] = 0ull;
  }

  int lane = t & 63, w = t >> 6;
  int wm = (w >> 1) * 16, wn = (w & 1) * 32;
  int quad = lane >> 4, r16 = lane & 15;

  f4 acc0 = {0.f, 0.f, 0.f, 0.f}, acc1 = {0.f, 0.f, 0.f, 0.f};
  int ar = t >> 3, as_ = (t & 7) * 8;
  int br = t >> 2, bs_ = (t & 3) * 16;
  int sqrow = t >> 2, sqk = (t & 3) * 16;
  float mySq = 0.f;

  for (int k0 = 0; k0 < DM; k0 += 64) {
    {
      size_t src = (boff + m0 + ar) * DM + k0 + as_;
      *(bf8*)&AsH[ar][as_] = *(const bf8*)(XH + src);
      *(bf8*)&AsM[ar][as_] = *(const bf8*)(XM + src);
      *(bf8*)&AsL[ar][as_] = *(const bf8*)(XL + src);
    }
    {
      size_t src = (boff + n0 + br) * DM + k0 + bs_;
      *(bf8*)&BsH[br][bs_] = *(const bf8*)(XH + src);
      *(bf8*)&BsH[br][bs_ + 8] = *(const bf8*)(XH + src + 8);
      *(bf8*)&BsM[br][bs_] = *(const bf8*)(XM + src);
      *(bf8*)&BsM[br][bs_ + 8] = *(const bf8*)(XM + src + 8);
      *(bf8*)&BsL[br][bs_] = *(const bf8*)(XL + src);
      *(bf8*)&BsL[br][bs_ + 8] = *(const bf8*)(XL + src + 8);
    }
    __syncthreads();
    #pragma unroll
    for (int ks = 0; ks < 64; ks += 16) {
      int seg = (quad & 1) * 8;
      bf8 aHM = *(const bf8*)((quad < 2) ? &AsH[wm + r16][ks + seg] : &AsM[wm + r16][ks + seg]);
      bf8 aHL = *(const bf8*)((quad < 2) ? &AsH[wm + r16][ks + seg] : &AsL[wm + r16][ks + seg]);
      #pragma unroll
      for (int tt = 0; tt < 2; ++tt) {
        int nr = wn + tt * 16 + r16;
        bf8 bH = *(const bf8*)&BsH[nr][ks + seg];
        bf8 bM = *(const bf8*)&BsM[nr][ks + seg];
        bf8 b3 = *(const bf8*)((quad < 2) ? &BsL[nr][ks + seg] : &BsH[nr][ks + seg]);
        f4& a = tt ? acc1 : acc0;
        a = __builtin_amdgcn_mfma_f32_16x16x32_bf16(aHM, bH, a, 0, 0, 0);  // HH' + MH'
        a = __builtin_amdgcn_mfma_f32_16x16x32_bf16(aHM, bM, a, 0, 0, 0);  // HM' + MM'
        a = __builtin_amdgcn_mfma_f32_16x16x32_bf16(aHL, b3, a, 0, 0, 0);  // HL' + LH'
      }
    }
    #pragma unroll
    for (int half = 0; half < 2; ++half) {
      bf8 hv = *(const bf8*)&BsH[sqrow][sqk + half * 8];
      bf8 mv = *(const bf8*)&BsM[sqrow][sqk + half * 8];
      bf8 lv = *(const bf8*)&BsL[sqrow][sqk + half * 8];
      #pragma unroll
      for (int q = 0; q < 8; ++q) {
        float x = (bf2f((u16)hv[q]) + bf2f((u16)mv[q])) + bf2f((u16)lv[q]);
        mySq += x * x;
      }
    }
    __syncthreads();
  }
  mySq += __shfl_xor(mySq, 1);
  mySq += __shfl_xor(mySq, 2);
  if ((t & 3) == 0) sqS[sqrow] = mySq;
  __syncthreads();

  #pragma unroll
  for (int tt = 0; tt < 2; ++tt) {
    f4 a = tt ? acc1 : acc0;
    int nl = wn + tt * 16 + r16;
    int n = n0 + nl;
    float sj = sqS[nl];
    #pragma unroll
    for (int reg = 0; reg < 4; ++reg) {
      int m = m0 + wm + quad * 4 + reg;
      float v = (m == n) ? BIGF : (sj - 2.f * a[reg]);
      d2[((size_t)b * NN + m) * NN + n] = v;
    }
  }
}

// ---------------------------------------------------------------- merged: knnsel || qkv+qe (+acc zero)
__global__ __launch_bounds__(256) void knnqkv_kernel(
    const float* __restrict__ d2, unsigned long long* __restrict__ adj,
    const u16* __restrict__ AH, const u16* __restrict__ AL,
    const u16* __restrict__ Pbase_H, const u16* __restrict__ Pbase_L,
    size_t offQ, size_t offK, size_t offV, size_t offE,
    u16* __restrict__ QH, u16* __restrict__ QL,
    u16* __restrict__ KH, u16* __restrict__ KL, u16* __restrict__ Vbf,
    float* __restrict__ qe_all, float* __restrict__ zbuf, int M) {
  __shared__ float dd[4][NN];
  {
    int ztid = blockIdx.x * 256 + threadIdx.x;
    if (ztid < ZTOT) zbuf[ztid] = 0.f;
  }
  int blk = blockIdx.x;
  if (blk < KSEL_BLK) {
    int b = blk / (NN / 4);
    int i0 = (blk % (NN / 4)) * 4;
    int t = threadIdx.x, lane = t & 63, w = t >> 6;

    const float4* src = (const float4*)(d2 + ((size_t)b * NN + i0) * NN);
    float4* dst = (float4*)&dd[0][0];
    #pragma unroll
    for (int x = 0; x < 4; ++x) dst[t + x * 256] = src[t + x * 256];
    __syncthreads();

    int i = i0 + w;
    for (int it = 0; it < KNN_K; ++it) {
      float bv = BIGF; int bi = 0x3fffffff;
      for (int j = lane; j < NN; j += 64) {
        float v = dd[w][j];
        if (v < bv) { bv = v; bi = j; }
      }
      #pragma unroll
      for (int o = 1; o < 64; o <<= 1) {
        float ov = __shfl_xor(bv, o); int oi = __shfl_xor(bi, o);
        if (ov < bv || (ov == bv && oi < bi)) { bv = ov; bi = oi; }
      }
      if (lane == 0) {
        dd[w][bi] = BIGF;
        atomicOr(&adj[((size_t)b * N1 + i) * ADJW + (bi >> 6)], 1ull << (bi & 63));
        atomicOr(&adj[((size_t)b * N1 + bi) * ADJW + (i >> 6)], 1ull << (i & 63));
      }
    }
    return;
  }
  int rel = blk - KSEL_BLK;
  int gx = rel % QKV_GX;
  int y = rel / QKV_GX;
  int z, nt;
  if (y < 8) { z = 0; nt = y; }
  else if (y < 16) { z = 1; nt = y - 8; }
  else if (y < 24) { z = 2; nt = y - 16; }
  else { z = 3; nt = y - 24; }
  size_t woff = z == 0 ? offQ : (z == 1 ? offK : (z == 2 ? offV : offE));
  const u16* PH = Pbase_H + woff;
  const u16* PL = Pbase_L + woff;
  int lane = threadIdx.x & 63;
  int quad = lane >> 4, r16 = lane & 15;
  int mt = gx * 4 + (threadIdx.x >> 6);
  f4 acc = {0.f, 0.f, 0.f, 0.f};
  int m0 = mt * 16;
  int mrow = m0 + r16; if (mrow >= M) mrow = M - 1;
  const u16* aph = AH + (size_t)mrow * DM + quad * 8;
  const u16* apl = AL + (size_t)mrow * DM + quad * 8;
  const u16* ph = PH + ((size_t)nt * 4 * 64 + lane) * 8;
  const u16* pl = PL + ((size_t)nt * 4 * 64 + lane) * 8;
  #pragma unroll
  for (int ks = 0; ks < 4; ++ks) {
    bf8 aH = *(const bf8*)(aph);
    bf8 aL = *(const bf8*)(apl);
    aph += 32; apl += 32;
    bf8 bH = *(const bf8*)(ph + (size_t)ks * 512);
    bf8 bL = *(const bf8*)(pl + (size_t)ks * 512);
    acc = __builtin_amdgcn_mfma_f32_16x16x32_bf16(aH, bH, acc, 0, 0, 0);
    acc = __builtin_amdgcn_mfma_f32_16x16x32_bf16(aH, bL, acc, 0, 0, 0);
    acc = __builtin_amdgcn_mfma_f32_16x16x32_bf16(aL, bH, acc, 0, 0, 0);
  }
  if (m0 >= M) return;
  int n = nt * 16 + r16;
  #pragma unroll
  for (int reg = 0; reg < 4; ++reg) {
    int m = m0 + quad * 4 + reg;
    if (m >= M) continue;
    float v = acc[reg];
    if (z == 3) {
      int b = m / N1, nr = m % N1;
      int h = n >> 5, bk = n & 31;
      qe_all[(((size_t)b * NH + h) * N1 + nr) * 32 + bk] = v;
      continue;
    }
    size_t oi = (size_t)m * DM + n;
    if (z == 0) {
      float sv = v * 0.25f;
      u16 hh = f2bf(sv);
      QH[oi] = hh;
      QL[oi] = f2bf(sv - bf2f(hh));
    } else if (z == 1) {
      u16 hh = f2bf(v);
      KH[oi] = hh;
      KL[oi] = f2bf(v - bf2f(hh));
    } else {
      Vbf[oi] = f2bf(v);
    }
  }
}

// ---------------------------------------------------------------- Wo GEMM: A = Osum/lsum inline (+inorm1 stats)
__global__ __launch_bounds__(256) void gemm_wo_kernel(
    const float* __restrict__ Osum, const float* __restrict__ lsum,
    const u16* __restrict__ PH, const u16* __restrict__ PL,
    const float* __restrict__ res, float* __restrict__ outF,
    float* __restrict__ sumY, float* __restrict__ sumY2, int M) {
  __shared__ float sA[2][16], sQ[2][16];
  int t = threadIdx.x;
  if (t < 32) {
    sA[t >> 4][t & 15] = 0.f;
    sQ[t >> 4][t & 15] = 0.f;
  }
  __syncthreads();
  int lane = t & 63;
  int quad = lane >> 4, r16 = lane & 15;
  int mt = blockIdx.x * 4 + (t >> 6), nt = blockIdx.y;
  f4 acc = {0.f, 0.f, 0.f, 0.f};
  int m0 = mt * 16;
  int mrow = m0 + r16; if (mrow >= M) mrow = M - 1;
  int b = mrow / N1, nr = mrow % N1;
  const u16* ph = PH + ((size_t)nt * 4 * 64 + lane) * 8;
  const u16* pl = PL + ((size_t)nt * 4 * 64 + lane) * 8;
  #pragma unroll
  for (int ks = 0; ks < 4; ++ks) {
    int k = ks * 32 + quad * 8;
    int h = k >> 4, d0 = k & 15;
    size_t base = (size_t)(b * NH + h) * N1 + nr;
    float inv = 1.0f / lsum[base];
    const float* op = Osum + base * 16 + d0;
    bf8 aH, aL;
    #pragma unroll
    for (int j = 0; j < 8; ++j) {
      float v = op[j] * inv;
      u16 hh = f2bf(v);
      aH[j] = (short)hh;
      aL[j] = (short)f2bf(v - bf2f(hh));
    }
    bf8 bH = *(const bf8*)(ph + (size_t)ks * 512);
    bf8 bL = *(const bf8*)(pl + (size_t)ks * 512);
    acc = __builtin_amdgcn_mfma_f32_16x16x32_bf16(aH, bH, acc, 0, 0, 0);
    acc = __builtin_amdgcn_mfma_f32_16x16x32_bf16(aH, bL, acc, 0, 0, 0);
    acc = __builtin_amdgcn_mfma_f32_16x16x32_bf16(aL, bH, acc, 0, 0, 0);
  }
  int n = nt * 16 + r16;
  if (m0 < M) {
    #pragma unroll
    for (int reg = 0; reg < 4; ++reg) {
      int m = m0 + quad * 4 + reg;
      if (m < M) {
        float v = acc[reg] + res[(size_t)m * DM + n];
        outF[(size_t)m * DM + n] = v;
        int mb2 = m / N1;
        atomicAdd(&sA[mb2][r16], v);
        atomicAdd(&sQ[mb2][r16], v * v);
      }
    }
  }
  __syncthreads();
  if (t < 32) {
    int bb = t >> 4, d = nt * 16 + (t & 15);
    atomicAdd(&sumY[bb * DM + d], sA[bb][t & 15]);
    atomicAdd(&sumY2[bb * DM + d], sQ[bb][t & 15]);
  }
}

// ---------------------------------------------------------------- W1 GEMM: A = inorm1(Yb) inline
__global__ __launch_bounds__(256) void gemm_w1_kernel(
    const float* __restrict__ Yb, const float* __restrict__ sumY,
    const float* __restrict__ sumY2, const float* __restrict__ n1w,
    const float* __restrict__ n1b,
    const u16* __restrict__ PH, const u16* __restrict__ PL,
    const float* __restrict__ bias,
    u16* __restrict__ outH, u16* __restrict__ outL, int M) {
  __shared__ float muS[STAT_N], scvS[STAT_N], shS[STAT_N];
  int t = threadIdx.x;
  {
    float mu = sumY[t] * (1.0f / N1);
    float var = sumY2[t] * (1.0f / N1) - mu * mu;
    int d = t & (DM - 1);
    muS[t] = mu;
    scvS[t] = rsqrtf(var + 1e-5f) * n1w[d];
    shS[t] = n1b[d];
  }
  __syncthreads();
  int lane = t & 63;
  int quad = lane >> 4, r16 = lane & 15;
  int mt = blockIdx.x * 4 + (t >> 6), nt = blockIdx.y;
  f4 acc = {0.f, 0.f, 0.f, 0.f};
  int m0 = mt * 16;
  int mrow = m0 + r16; if (mrow >= M) mrow = M - 1;
  int b = mrow / N1;
  const float* yp = Yb + (size_t)mrow * DM + quad * 8;
  const u16* ph = PH + ((size_t)nt * 4 * 64 + lane) * 8;
  const u16* pl = PL + ((size_t)nt * 4 * 64 + lane) * 8;
  #pragma unroll
  for (int ks = 0; ks < 4; ++ks) {
    int k = ks * 32 + quad * 8;
    bf8 aH, aL;
    #pragma unroll
    for (int half = 0; half < 2; ++half) {
      float4 yv = *(const float4*)(yp + ks * 32 + half * 4);
      float ya[4] = {yv.x, yv.y, yv.z, yv.w};
      #pragma unroll
      for (int q = 0; q < 4; ++q) {
        int sidx = b * DM + k + half * 4 + q;
        float nv = (ya[q] - muS[sidx]) * scvS[sidx] + shS[sidx];
        u16 hh = f2bf(nv);
        aH[half * 4 + q] = (short)hh;
        aL[half * 4 + q] = (short)f2bf(nv - bf2f(hh));
      }
    }
    bf8 bH = *(const bf8*)(ph + (size_t)ks * 512);
    bf8 bL = *(const bf8*)(pl + (size_t)ks * 512);
    acc = __builtin_amdgcn_mfma_f32_16x16x32_bf16(aH, bH, acc, 0, 0, 0);
    acc = __builtin_amdgcn_mfma_f32_16x16x32_bf16(aH, bL, acc, 0, 0, 0);
    acc = __builtin_amdgcn_mfma_f32_16x16x32_bf16(aL, bH, acc, 0, 0, 0);
  }
  if (m0 >= M) return;
  int n = nt * 16 + r16;
  #pragma unroll
  for (int reg = 0; reg < 4; ++reg) {
    int m = m0 + quad * 4 + reg;
    if (m < M) {
      float v = fmaxf(acc[reg] + bias[n], 0.f);
      size_t oi = (size_t)m * DFF + n;
      u16 hh = f2bf(v);
      outH[oi] = hh;
      outL[oi] = f2bf(v - bf2f(hh));
    }
  }
}

// ---------------------------------------------------------------- W2 GEMM: res = inorm1(Yb) inline
__global__ __launch_bounds__(256) void gemm_w2_kernel(
    const u16* __restrict__ AH, const u16* __restrict__ AL,
    const u16* __restrict__ PH, const u16* __restrict__ PL,
    const float* __restrict__ bias, const float* __restrict__ Yb,
    const float* __restrict__ sumY, const float* __restrict__ sumY2,
    const float* __restrict__ n1w, const float* __restrict__ n1b,
    float* __restrict__ outF, int M) {
  __shared__ float muS[STAT_N], scvS[STAT_N], shS[STAT_N];
  int t = threadIdx.x;
  {
    float mu = sumY[t] * (1.0f / N1);
    float var = sumY2[t] * (1.0f / N1) - mu * mu;
    int d = t & (DM - 1);
    muS[t] = mu;
    scvS[t] = rsqrtf(var + 1e-5f) * n1w[d];
    shS[t] = n1b[d];
  }
  __syncthreads();
  int lane = t & 63;
  int quad = lane >> 4, r16 = lane & 15;
  int mt = blockIdx.x * 4 + (t >> 6), nt = blockIdx.y;
  f4 acc = {0.f, 0.f, 0.f, 0.f};
  int m0 = mt * 16;
  int mrow = m0 + r16; if (mrow >= M) mrow = M - 1;
  const u16* aph = AH + (size_t)mrow * DFF + quad * 8;
  const u16* apl = AL + (size_t)mrow * DFF + quad * 8;
  const u16* ph = PH + ((size_t)nt * 16 * 64 + lane) * 8;
  const u16* pl = PL + ((size_t)nt * 16 * 64 + lane) * 8;
  #pragma unroll 4
  for (int ks = 0; ks < 16; ++ks) {
    bf8 aH = *(const bf8*)(aph);
    bf8 aL = *(const bf8*)(apl);
    aph += 32; apl += 32;
    bf8 bH = *(const bf8*)(ph + (size_t)ks * 512);
    bf8 bL = *(const bf8*)(pl + (size_t)ks * 512);
    acc = __builtin_amdgcn_mfma_f32_16x16x32_bf16(aH, bH, acc, 0, 0, 0);
    acc = __builtin_amdgcn_mfma_f32_16x16x32_bf16(aH, bL, acc, 0, 0, 0);
    acc = __builtin_amdgcn_mfma_f32_16x16x32_bf16(aL, bH, acc, 0, 0, 0);
  }
  if (m0 >= M) return;
  int n = nt * 16 + r16;
  #pragma unroll
  for (int reg = 0; reg < 4; ++reg) {
    int m = m0 + quad * 4 + reg;
    if (m < M) {
      int b = m / N1;
      int sidx = b * DM + n;
      float h1 = (Yb[(size_t)m * DM + n] - muS[sidx]) * scvS[sidx] + shS[sidx];
      outF[(size_t)m * DM + n] = acc[reg] + bias[n] + h1;
    }
  }
}

// ---------------------------------------------------------------- MFMA flash attention, key-split
#define CH 64
#define NCH 17
__global__ __launch_bounds__(128) void attn_kernel(
    const u16* __restrict__ QH, const u16* __restrict__ QL,
    const u16* __restrict__ KH, const u16* __restrict__ KL,
    const u16* __restrict__ Vbf, const float* __restrict__ qe_all,
    const unsigned char* __restrict__ buckp, const unsigned long long* __restrict__ adj,
    float* __restrict__ Osum, float* __restrict__ lsum) {
  __shared__ __align__(16) u16 KsHi[2][CH][20];
  __shared__ __align__(16) u16 KsLo[2][CH][20];
  __shared__ __align__(16) u16 Vt[2][DK][68];
  __shared__ __align__(16) u16 Ps[2][16][72];
  __shared__ __align__(16) float qe_s[2][16][36];
  __shared__ u32 maskS[32][6];
  __shared__ unsigned char buckS[2][32][68];

  int qt = blockIdx.x;
  int h = blockIdx.y & 7, b = blockIdx.y >> 3;
  int s = blockIdx.z;
  int c0 = (NCH * s) / NSPLIT, c1 = (NCH * (s + 1)) / NSPLIT;
  int nwm = 2 * (c1 - c0);
  int t = threadIdx.x, lane = t & 63, w = t >> 6;
  int quad = lane >> 4, r16 = lane & 15;
  int i0 = qt * 32;
  int iw = i0 + w * 16;
  int bh = b * NH + h;

  for (int x = t; x < 32 * nwm; x += 128) {
    int rr = x / nwm, ww = x % nwm;
    int gi = i0 + rr; if (gi > NN) gi = NN;
    int W = 2 * c0 + ww;
    u32 v;
    if (gi == 0 || gi == NN) {
      v = 0xffffffffu;
    } else {
      const u32* a32 = (const u32*)(adj + ((size_t)b * N1 + gi) * ADJW);
      v = a32[W];
      int bs = gi & ~127;
      int lo = gi - 11 < bs ? bs : gi - 11;
      int be = bs + 127;
      int hi = gi + 11 > be ? be : gi + 11;
      int aa = lo - 32 * W, bnd = hi - 32 * W;
      if (aa < 0) aa = 0; if (bnd > 31) bnd = 31;
      if (aa <= bnd) v |= (0xffffffffu << aa) & (0xffffffffu >> (31 - bnd));
      if (W == 0) v |= 1u;
      if (W == 32) v |= 1u;
      int dg = gi - 32 * W;
      if (dg >= 0 && dg < 32) v |= 1u << dg;
    }
    if (W == 32) v &= 1u;
    else if (W == 33) v = 0u;
    maskS[rr][ww] = v;
  }
  #pragma unroll
  for (int e = 0; e < 2; ++e) {
    int x = lane + e * 64;
    int rr = x >> 3, bk = (x & 7) * 4;
    int gi = iw + rr; if (gi > NN) gi = NN;
    f4 v = *(const f4*)(qe_all + (((size_t)b * NH + h) * N1 + gi) * 32 + bk);
    *(f4*)&qe_s[w][rr][bk] = v;
  }
  bf8 qfrag;
  {
    int gi = iw + r16; if (gi > NN) gi = NN;
    const u16* qsrc = (quad < 2 ? QH : QL) + ((size_t)(b * N1 + gi) * DM + h * DK + (quad & 1) * 8);
    qfrag = *(const bf8*)qsrc;
  }

  ushort4 khr[2], klr[2], vvr[2]; u32 bkr[4];
  auto load_chunk = [&](int c) {
    int j0 = c * CH;
    #pragma unroll
    for (int ii = 0; ii < 2; ++ii) {
      int x = t + ii * 128;
      int key = x >> 2, ds = (x & 3) * 4;
      int jg = j0 + key; if (jg > NN) jg = NN;
      size_t src = (size_t)(b * N1 + jg) * DM + h * DK + ds;
      khr[ii] = *(const ushort4*)(KH + src);
      klr[ii] = *(const ushort4*)(KL + src);
      vvr[ii] = *(const ushort4*)(Vbf + src);
    }
    #pragma unroll
    for (int ii = 0; ii < 4; ++ii) {
      int x = t + ii * 128;
      int rr = x >> 4, c4 = (x & 15) * 4;
      int gi = i0 + rr; if (gi > NN) gi = NN;
      bkr[ii] = *(const u32*)(buckp + ((size_t)b * N1 + gi) * BSTR + j0 + c4);
    }
  };
  auto store_chunk = [&](int pb) {
    #pragma unroll
    for (int ii = 0; ii < 2; ++ii) {
      int x = t + ii * 128;
      int key = x >> 2, ds = (x & 3) * 4;
      *(ushort4*)&KsHi[pb][key][ds] = khr[ii];
      *(ushort4*)&KsLo[pb][key][ds] = klr[ii];
      Vt[pb][ds + 0][key] = vvr[ii].x;
      Vt[pb][ds + 1][key] = vvr[ii].y;
      Vt[pb][ds + 2][key] = vvr[ii].z;
      Vt[pb][ds + 3][key] = vvr[ii].w;
    }
    #pragma unroll
    for (int ii = 0; ii < 4; ++ii) {
      int x = t + ii * 128;
      int rr = x >> 4, c4 = (x & 15) * 4;
      *(u32*)&buckS[pb][rr][c4] = bkr[ii];
    }
  };

  f4 Oacc = {0.f, 0.f, 0.f, 0.f};
  float lrun[4] = {0.f, 0.f, 0.f, 0.f};

  load_chunk(c0);
  store_chunk(0);

  for (int c = c0; c < c1; ++c) {
    int pb = (c - c0) & 1;
    bool pf = (c + 1 < c1);
    if (pf) load_chunk(c + 1);
    __syncthreads();

    f4 S[4];
    #pragma unroll
    for (int tt = 0; tt < 4; ++tt) {
      int key = tt * 16 + r16;
      int off = (quad & 1) * 8;
      bf8 bhv = mk8(*(const ushort4*)&KsHi[pb][key][off], *(const ushort4*)&KsHi[pb][key][off + 4]);
      bf8 blv = mk8(*(const ushort4*)&KsLo[pb][key][off], *(const ushort4*)&KsLo[pb][key][off + 4]);
      f4 z = {0.f, 0.f, 0.f, 0.f};
      z = __builtin_amdgcn_mfma_f32_16x16x32_bf16(qfrag, bhv, z, 0, 0, 0);
      z = __builtin_amdgcn_mfma_f32_16x16x32_bf16(qfrag, blv, z, 0, 0, 0);
      S[tt] = z;
    }

    #pragma unroll
    for (int rg = 0; rg < 4; ++rg) {
      int rowb = w * 16 + quad * 4 + rg;
      u32 mw0 = maskS[rowb][2 * (c - c0)];
      u32 mw1 = maskS[rowb][2 * (c - c0) + 1];
      float ps = 0.f;
      #pragma unroll
      for (int tt = 0; tt < 4; ++tt) {
        u32 mword = (tt & 2) ? mw1 : mw0;
        int bit = (tt & 1) * 16 + r16;
        int bk = buckS[pb][rowb][tt * 16 + r16] & 31;
        float rel = qe_s[w][quad * 4 + rg][bk];
        float sc = S[tt][rg] + rel;
        sc += ((mword >> bit) & 1u) ? 0.f : -1.0e9f;
        float p = __expf(sc - SM_OFF);
        ps += p;
        Ps[w][quad * 4 + rg][tt * 16 + r16] = f2bf(p);
      }
      #pragma unroll
      for (int o = 1; o < 16; o <<= 1) ps += __shfl_xor(ps, o);
      lrun[rg] += ps;
    }
    #pragma unroll
    for (int half = 0; half < 2; ++half) {
      bf8 pa = *(const bf8*)&Ps[w][r16][half * 32 + quad * 8];
      bf8 vb = mk8(*(const ushort4*)&Vt[pb][r16][half * 32 + quad * 8],
                   *(const ushort4*)&Vt[pb][r16][half * 32 + quad * 8 + 4]);
      Oacc = __builtin_amdgcn_mfma_f32_16x16x32_bf16(pa, vb, Oacc, 0, 0, 0);
    }

    if (pf) store_chunk(pb ^ 1);
  }

  #pragma unroll
  for (int rg = 0; rg < 4; ++rg) {
    int gi = i0 + w * 16 + quad * 4 + rg;
    if (gi < N1) {
      size_t base = (size_t)bh * N1 + gi;
      atomicAdd(&Osum[base * 16 + r16], Oacc[rg]);
      if (r16 == 0) atomicAdd(&lsum[base], lrun[rg]);
    }
  }
}

// ---------------------------------------------------------------- instance norm (+pool/g, +split emit)
__global__ void inorm_kernel(float* __restrict__ X, const float* __restrict__ w,
                             const float* __restrict__ b_, float* __restrict__ pool,
                             int do_g, u16* __restrict__ oH, u16* __restrict__ oM,
                             u16* __restrict__ oL) {
  int d = blockIdx.x; int bb = blockIdx.y; int lane = threadIdx.x;
  float g_old = X[((size_t)bb * N1 + NN) * DM + d];
  float s = 0.f;
  for (int n = lane; n < N1; n += 64) s += X[((size_t)bb * N1 + n) * DM + d];
  #pragma unroll
  for (int o = 1; o < 64; o <<= 1) s += __shfl_xor(s, o);
  float mu = s * (1.0f / N1);
  float v = 0.f;
  for (int n = lane; n < N1; n += 64) {
    float tt = X[((size_t)bb * N1 + n) * DM + d] - mu;
    v += tt * tt;
  }
  #pragma unroll
  for (int o = 1; o < 64; o <<= 1) v += __shfl_xor(v, o);
  float var = v * (1.0f / N1);
  float scv = rsqrtf(var + 1e-5f) * w[d];
  float sh = b_[d];
  for (int n = lane; n < N1; n += 64) {
    size_t id = ((size_t)bb * N1 + n) * DM + d;
    float nv = (X[id] - mu) * scv + sh;
    X[id] = nv;
    if (oH) {
      u16 hh = f2bf(nv); float r1 = nv - bf2f(hh);
      u16 mm = f2bf(r1);
      oH[id] = hh;
      oM[id] = mm;
      if (oL) oL[id] = f2bf(r1 - bf2f(mm));
    }
  }
  if (lane == 0) {
    float hmean = ((s - g_old) * (1.0f / NN) - mu) * scv + sh;
    if (pool) pool[bb * DM + d] = hmean;
    if (do_g) X[((size_t)bb * N1 + NN) * DM + d] += hmean;
  }
}

// ---------------------------------------------------------------- final GEMM (inline h+pm split, +out_pm)
__global__ __launch_bounds__(256) void gemm_final_kernel(
    const float* __restrict__ X, const float* __restrict__ pools,
    const u16* __restrict__ PH, const u16* __restrict__ PL,
    const float* __restrict__ bias, float* __restrict__ out, float* __restrict__ out_pm) {
  int t = threadIdx.x;
  if (blockIdx.x == 0 && blockIdx.y == 0) {
    float pmv = (pools[t] + pools[BB * DM + t] + pools[2 * BB * DM + t]) * (1.0f / 3.0f);
    out_pm[t] = pmv;
  }
  int lane = t & 63;
  int quad = lane >> 4, r16 = lane & 15;
  int mt = blockIdx.x * 4 + (t >> 6), nt = blockIdx.y;
  const int M = BB * NN;
  f4 acc = {0.f, 0.f, 0.f, 0.f};
  int m0 = mt * 16;
  int mrow = m0 + r16; if (mrow >= M) mrow = M - 1;
  int mb = mrow / NN, mn = mrow % NN;
  const float* xp = X + ((size_t)mb * N1 + mn) * DM + quad * 8;
  const float* pp = pools + mb * DM + quad * 8;
  const u16* ph = PH + ((size_t)nt * 4 * 64 + lane) * 8;
  const u16* pl = PL + ((size_t)nt * 4 * 64 + lane) * 8;
  #pragma unroll
  for (int ks = 0; ks < 4; ++ks) {
    bf8 aH, aL;
    #pragma unroll
    for (int half = 0; half < 2; ++half) {
      float4 xv = *(const float4*)(xp + ks * 32 + half * 4);
      float4 p0 = *(const float4*)(pp + ks * 32 + half * 4);
      float4 p1 = *(const float4*)(pp + BB * DM + ks * 32 + half * 4);
      float4 p2 = *(const float4*)(pp + 2 * BB * DM + ks * 32 + half * 4);
      float av[4] = {xv.x + (p0.x + p1.x + p2.x) * (1.0f / 3.0f),
                     xv.y + (p0.y + p1.y + p2.y) * (1.0f / 3.0f),
                     xv.z + (p0.z + p1.z + p2.z) * (1.0f / 3.0f),
                     xv.w + (p0.w + p1.w + p2.w) * (1.0f / 3.0f)};
      #pragma unroll
      for (int q = 0; q < 4; ++q) {
        u16 hh = f2bf(av[q]);
        aH[half * 4 + q] = (short)hh;
        aL[half * 4 + q] = (short)f2bf(av[q] - bf2f(hh));
      }
    }
    bf8 bH = *(const bf8*)(ph + (size_t)ks * 512);
    bf8 bL = *(const bf8*)(pl + (size_t)ks * 512);
    acc = __builtin_amdgcn_mfma_f32_16x16x32_bf16(aH, bH, acc, 0, 0, 0);
    acc = __builtin_amdgcn_mfma_f32_16x16x32_bf16(aH, bL, acc, 0, 0, 0);
    acc = __builtin_amdgcn_mfma_f32_16x16x32_bf16(aL, bH, acc, 0, 0, 0);
  }
  int n = nt * 16 + r16;
  #pragma unroll
  for (int reg = 0; reg < 4; ++reg) {
    int m = m0 + quad * 4 + reg;
    if (m < M) out[(size_t)m * DM + n] = acc[reg] + bias[n];
  }
}

// ================================================================ launch
extern "C" void kernel_launch(void* const* d_in, const int* in_sizes, int n_in,
                              void* d_out, int out_size, void* d_ws, size_t ws_size,
                              hipStream_t stream) {
  const float* coords = (const float*)d_in[0];
  const float* inW    = (const float*)d_in[1];
  const float* inb    = (const float*)d_in[2];
  const float* gnode  = (const float*)d_in[3];
  const float* Wq     = (const float*)d_in[4];
  const float* Wk     = (const float*)d_in[5];
  const float* Wv     = (const float*)d_in[6];
  const float* Wo     = (const float*)d_in[7];
  const float* emb    = (const float*)d_in[8];
  const float* W1     = (const float*)d_in[9];
  const float* b1     = (const float*)d_in[10];
  const float* W2     = (const float*)d_in[11];
  const float* b2     = (const float*)d_in[12];
  const float* n1w    = (const float*)d_in[13];
  const float* n1b    = (const float*)d_in[14];
  const float* n2w    = (const float*)d_in[15];
  const float* n2b    = (const float*)d_in[16];
  const float* outW   = (const float*)d_in[17];
  const float* outb   = (const float*)d_in[18];
  float* out = (float*)d_out;

  char* wsp = (char*)d_ws;
  size_t off = 0;
  auto alloc = [&](size_t bytes) -> void* {
    off = (off + 255) & ~(size_t)255;
    void* p = wsp + off;
    off += bytes;
    return p;
  };
  const size_t XB = (size_t)BB * N1 * DM * 4;       // fp32 activation buffer
  const size_t HB = (size_t)BB * N1 * DM * 2;       // u16 half buffer
  float* X0   = (float*)alloc(XB);
  float* X1   = (float*)alloc(XB);
  float* Yb   = (float*)alloc(XB);
  u16* XH = (u16*)alloc(HB); u16* XM = (u16*)alloc(HB); u16* XL = (u16*)alloc(HB);
  u16* QH = (u16*)alloc(HB); u16* QL = (u16*)alloc(HB);
  u16* KH = (u16*)alloc(HB); u16* KL = (u16*)alloc(HB);
  u16* Vbf = (u16*)alloc(HB);
  u16* FbH = (u16*)alloc((size_t)BB * N1 * DFF * 2);
  u16* FbL = (u16*)alloc((size_t)BB * N1 * DFF * 2);
  unsigned char* buckp = (unsigned char*)alloc((size_t)BB * N1 * BSTR);
  unsigned long long* adj = (unsigned long long*)alloc((size_t)BB * N1 * ADJW * 8);
  float* pools = (float*)alloc((size_t)NLAYERS * BB * DM * 4);
  float* qe_all = (float*)alloc((size_t)BB * NH * N1 * 32 * 4);
  float* zbuf = (float*)alloc((size_t)ZTOT * 4);    // Osum + lsum + sumY + sumY2
  u16* PH = (u16*)alloc((size_t)PW_TOT * 2);
  u16* PL = (u16*)alloc((size_t)PW_TOT * 2);
  float* d2 = (float*)alloc((size_t)BB * NN * NN * 4);

  float* Osum = zbuf;
  float* lsum = zbuf + OSUM_N;
  float* sumY = zbuf + OSUM_N + LSUM_N;
  float* sumY2 = sumY + STAT_N;

  init_kernel<<<PBLK + EBLK + BBLK, 256, 0, stream>>>(
      coords, inW, inb, gnode, Wq, Wk, Wv, Wo, W1, W2, outW, emb,
      PH, PL, X0, XH, XM, XL, buckp);

  float* Xin = X0; float* Xout = X1;
  const int M = BB * N1;
  const int GX = 33;     // ceil(129 m-tiles / 4 waves)
  for (int l = 0; l < NLAYERS; ++l) {
    gram_kernel<<<dim3(32, 16, BB), 256, 0, stream>>>(XH, XM, XL, adj, d2);

    // knnsel || qkv (independent) merged; also zeroes Osum/lsum/stats
    knnqkv_kernel<<<KSEL_BLK + QKV_BLK, 256, 0, stream>>>(
        d2, adj, XH, XM, PH, PL,
        (size_t)PWQ_OFF + (size_t)l * DM * DM,
        (size_t)PWK_OFF + (size_t)l * DM * DM,
        (size_t)PWV_OFF + (size_t)l * DM * DM,
        (size_t)PWQE_OFF + (size_t)l * 256 * DM,
        QH, QL, KH, KL, Vbf, qe_all, zbuf, M);

    attn_kernel<<<dim3(33, NH * BB, NSPLIT), 128, 0, stream>>>(
        QH, QL, KH, KL, Vbf, qe_all, buckp, adj, Osum, lsum);

    gemm_wo_kernel<<<dim3(GX, 8), 256, 0, stream>>>(
        Osum, lsum, PH + PWO_OFF + (size_t)l * DM * DM, PL + PWO_OFF + (size_t)l * DM * DM,
        Xin, Yb, sumY, sumY2, M);

    gemm_w1_kernel<<<dim3(GX, 32), 256, 0, stream>>>(
        Yb, sumY, sumY2, n1w + l * DM, n1b + l * DM,
        PH + PW1_OFF + (size_t)l * DFF * DM, PL + PW1_OFF + (size_t)l * DFF * DM,
        b1 + l * DFF, FbH, FbL, M);

    gemm_w2_kernel<<<dim3(GX, 8), 256, 0, stream>>>(
        FbH, FbL, PH + PW2_OFF + (size_t)l * DM * DFF, PL + PW2_OFF + (size_t)l * DM * DFF,
        b2 + l * DM, Yb, sumY, sumY2, n1w + l * DM, n1b + l * DM, Xout, M);

    // inorm2 emits next layer's 3-level X splits inline
    inorm_kernel<<<dim3(DM, BB), 64, 0, stream>>>(Xout, n2w + l * DM, n2b + l * DM,
                                                  pools + (size_t)l * BB * DM, 1,
                                                  XH, XM, XL);

    float* t2 = Xin; Xin = Xout; Xout = t2;
  }

  gemm_final_kernel<<<dim3(32, 8), 256, 0, stream>>>(
      Xin, pools, PH + PWOUT_OFF, PL + PWOUT_OFF, outb, out, out + (size_t)BB * NN * DM);
}

// Round 19
// 379.788 us; speedup vs baseline: 1.3956x; 1.1120x over previous
//
#include <hip/hip_runtime.h>

#define BB 2
#define NN 1024
#define N1 1025
#define DM 128
#define NH 8
#define DK 16
#define DFF 512
#define NBUK 32
#define NLAYERS 3
#define KNN_K 10
#define ADJW 17          // 1025 bits -> 17 u64 words per row
#define BSTR 1088        // padded bucket row stride (bytes)
#define NSPLIT 8
#define BIGF 3.0e38f
#define SM_OFF 24.0f     // fixed softmax exponent offset (|s| bounded << 24+88)

// prepacked-weight element offsets (see init_kernel prepack branch)
#define PWQ_OFF 0
#define PWK_OFF 49152
#define PWV_OFF 98304
#define PWO_OFF 147456
#define PW1_OFF 196608
#define PW2_OFF 393216
#define PWOUT_OFF 589824
#define PWQE_OFF 606208
#define PW_TOT 704512

// init kernel block ranges
#define PBLK 344         // ceil(88064/256) prepack
#define NBNODE 1024      // embed node blocks
#define EBLK (NBNODE + BB)
#define BBLK 8713        // ceil(BB*N1*BSTR/256) bucket

// knnsel+qkv merged kernel block ranges
#define KSEL_BLK 512     // BB*NN/4
#define QKV_GX 33
#define QKV_BLK (QKV_GX * 40)
#define OSUM_N (BB * NH * N1 * 16)       // 262400
#define LSUM_N (BB * NH * N1)            // 16400
#define STAT_N (BB * DM)                 // 256
#define ZTOT (OSUM_N + LSUM_N + 4 * STAT_N)   // 279824

typedef __attribute__((ext_vector_type(8))) short bf8;
typedef __attribute__((ext_vector_type(4))) float f4;
typedef unsigned short u16;
typedef unsigned int u32;

__device__ __forceinline__ u16 f2bf(float x) {
  unsigned u = __float_as_uint(x);
  return (u16)((u + 0x7fff + ((u >> 16) & 1)) >> 16);   // RNE
}
__device__ __forceinline__ float bf2f(u16 u) {
  return __uint_as_float(((unsigned)u) << 16);
}
__device__ __forceinline__ bf8 mk8(ushort4 a, ushort4 b) {
  bf8 r;
  r[0] = (short)a.x; r[1] = (short)a.y; r[2] = (short)a.z; r[3] = (short)a.w;
  r[4] = (short)b.x; r[5] = (short)b.y; r[6] = (short)b.z; r[7] = (short)b.w;
  return r;
}

// ---------------------------------------------------------------- init: prepack + embed(+splits) + bucket
__global__ __launch_bounds__(256) void init_kernel(
    const float* __restrict__ coords, const float* __restrict__ inW,
    const float* __restrict__ inb, const float* __restrict__ gnode,
    const float* __restrict__ Wq, const float* __restrict__ Wk,
    const float* __restrict__ Wv, const float* __restrict__ Wo,
    const float* __restrict__ W1, const float* __restrict__ W2,
    const float* __restrict__ oW, const float* __restrict__ emb,
    u16* __restrict__ PH, u16* __restrict__ PL,
    float* __restrict__ X, u16* __restrict__ XH, u16* __restrict__ XM,
    u16* __restrict__ XL, unsigned char* __restrict__ buckp) {
  int blk = blockIdx.x;
  if (blk < PBLK) {
    int idx = blk * 256 + threadIdx.x;
    if (idx >= 88064) return;
    if (idx >= 75776) {
      int rel = idx - 75776;
      int lane = rel & 63, g = rel >> 6;
      int ks = g & 3, nt = g >> 2;
      int n = nt * 16 + (lane & 15);
      int k = ks * 32 + (lane >> 4) * 8;
      int l = n >> 8; int c = n & 255; int h = c >> 5, bk = c & 31;
      const float* e = emb + ((size_t)l * NBUK + bk) * DM + h * DK;
      const float* wq = Wq + ((size_t)l * DM + h * DK) * DM;
      u16* ph = PH + (size_t)idx * 8;
      u16* pl = PL + (size_t)idx * 8;
      #pragma unroll
      for (int q = 0; q < 8; ++q) {
        float s = 0.f;
        #pragma unroll
        for (int d = 0; d < DK; ++d) s += e[d] * wq[(size_t)d * DM + k + q];
        u16 hh = f2bf(s);
        ph[q] = hh;
        pl[q] = f2bf(s - bf2f(hh));
      }
      return;
    }
    const float* W; int rel, Kdim;
    if (idx < 24576) {
      int seg = idx / 6144; rel = idx % 6144; Kdim = 128;
      W = seg == 0 ? Wq : seg == 1 ? Wk : seg == 2 ? Wv : Wo;
    } else if (idx < 49152) { rel = idx - 24576; Kdim = 128; W = W1; }
    else if (idx < 73728)   { rel = idx - 49152; Kdim = 512; W = W2; }
    else                    { rel = idx - 73728; Kdim = 128; W = oW; }
    int lane = rel & 63;
    int g = rel >> 6;
    int ksteps = Kdim >> 5;
    int ks = g % ksteps, nt = g / ksteps;
    int n = nt * 16 + (lane & 15);
    int k = ks * 32 + (lane >> 4) * 8;
    const float* p = W + (size_t)n * Kdim + k;
    u16* ph = PH + (size_t)idx * 8;
    u16* pl = PL + (size_t)idx * 8;
    #pragma unroll
    for (int q = 0; q < 8; ++q) {
      float x = p[q];
      u16 hh = f2bf(x);
      ph[q] = hh;
      pl[q] = f2bf(x - bf2f(hh));
    }
    return;
  }
  if (blk < PBLK + EBLK) {
    int eb = blk - PBLK;
    if (eb >= NBNODE) {
      int b = eb - NBNODE;
      int t = threadIdx.x;
      if (t >= 128) return;
      int lane = t & 63;
      float sx = 0.f, sy = 0.f;
      for (int n = lane; n < NN; n += 64) {
        float2 c = *(const float2*)(coords + (size_t)(b * NN + n) * 2);
        sx += c.x; sy += c.y;
      }
      #pragma unroll
      for (int o = 1; o < 64; o <<= 1) { sx += __shfl_xor(sx, o); sy += __shfl_xor(sy, o); }
      float mx = sx * (1.0f / NN), my = sy * (1.0f / NN);
      int d = t;
      size_t id = ((size_t)b * N1 + NN) * DM + d;
      float v = gnode[d] + inb[d] + mx * inW[d * 2 + 0] + my * inW[d * 2 + 1];
      X[id] = v;
      u16 hh = f2bf(v); float r1 = v - bf2f(hh);
      u16 mm = f2bf(r1);
      XH[id] = hh; XM[id] = mm; XL[id] = f2bf(r1 - bf2f(mm));
      return;
    }
    int idx = eb * 256 + threadIdx.x;
    if (idx >= BB * NN * DM) return;
    int d = idx % DM; int r = idx / DM; int n = r % NN; int b = r / NN;
    float cx = coords[(b * NN + n) * 2 + 0], cy = coords[(b * NN + n) * 2 + 1];
    size_t id = ((size_t)b * N1 + n) * DM + d;
    float v = cx * inW[d * 2 + 0] + cy * inW[d * 2 + 1] + inb[d];
    X[id] = v;
    u16 hh = f2bf(v); float r1 = v - bf2f(hh);
    u16 mm = f2bf(r1);
    XH[id] = hh; XM[id] = mm; XL[id] = f2bf(r1 - bf2f(mm));
    return;
  }
  int idx = (blk - PBLK - EBLK) * 256 + threadIdx.x;
  if (idx >= BB * N1 * BSTR) return;
  int j = idx % BSTR; int r = idx / BSTR; int i = r % N1; int b = r / N1;
  unsigned char v = 0;
  if (j < N1) {
    float xi = 0.f, yi = 0.f, xj = 0.f, yj = 0.f;
    if (i < NN) { xi = coords[(b * NN + i) * 2]; yi = coords[(b * NN + i) * 2 + 1]; }
    if (j < NN) { xj = coords[(b * NN + j) * 2]; yj = coords[(b * NN + j) * 2 + 1]; }
    float dx = xi - xj, dy = yi - yj;
    float dist = sqrtf(dx * dx + dy * dy);
    int bu = (int)(dist * 32.0f);
    bu = bu < 0 ? 0 : (bu > 31 ? 31 : bu);
    v = (unsigned char)bu;
  }
  buckp[idx] = v;
}

// ---------------------------------------------------------------- exact MFMA gram (+adj zero)
__global__ __launch_bounds__(256) void gram_kernel(
    const u16* __restrict__ XH, const u16* __restrict__ XM, const u16* __restrict__ XL,
    unsigned long long* __restrict__ adj, float* __restrict__ d2) {
  __shared__ __align__(16) u16 AsH[32][72];
  __shared__ __align__(16) u16 AsM[32][72];
  __shared__ __align__(16) u16 AsL[32][72];
  __shared__ __align__(16) u16 BsH[64][72];
  __shared__ __align__(16) u16 BsM[64][72];
  __shared__ __align__(16) u16 BsL[64][72];
  __shared__ float sqS[64];
  int b = blockIdx.z;
  int m0 = blockIdx.x * 32, n0 = blockIdx.y * 64;
  size_t boff = (size_t)b * N1;
  int t = threadIdx.x;

  {
    int flat = blockIdx.x + 32 * (blockIdx.y + 16 * blockIdx.z);
    int tid = flat * 256 + t;
    if (tid < BB * N1 * ADJW) adj[tid] = 0ull;
  }

  int lane = t & 63, w = t >> 6;
  int wm = (w >> 1) * 16, wn = (w & 1) * 32;
  int quad = lane >> 4, r16 = lane & 15;

  f4 acc0 = {0.f, 0.f, 0.f, 0.f}, acc1 = {0.f, 0.f, 0.f, 0.f};
  int ar = t >> 3, as_ = (t & 7) * 8;
  int br = t >> 2, bs_ = (t & 3) * 16;
  int sqrow = t >> 2, sqk = (t & 3) * 16;
  float mySq = 0.f;

  for (int k0 = 0; k0 < DM; k0 += 64) {
    {
      size_t src = (boff + m0 + ar) * DM + k0 + as_;
      *(bf8*)&AsH[ar][as_] = *(const bf8*)(XH + src);
      *(bf8*)&AsM[ar][as_] = *(const bf8*)(XM + src);
      *(bf8*)&AsL[ar][as_] = *(const bf8*)(XL + src);
    }
    {
      size_t src = (boff + n0 + br) * DM + k0 + bs_;
      *(bf8*)&BsH[br][bs_] = *(const bf8*)(XH + src);
      *(bf8*)&BsH[br][bs_ + 8] = *(const bf8*)(XH + src + 8);
      *(bf8*)&BsM[br][bs_] = *(const bf8*)(XM + src);
      *(bf8*)&BsM[br][bs_ + 8] = *(const bf8*)(XM + src + 8);
      *(bf8*)&BsL[br][bs_] = *(const bf8*)(XL + src);
      *(bf8*)&BsL[br][bs_ + 8] = *(const bf8*)(XL + src + 8);
    }
    __syncthreads();
    #pragma unroll
    for (int ks = 0; ks < 64; ks += 16) {
      int seg = (quad & 1) * 8;
      bf8 aHM = *(const bf8*)((quad < 2) ? &AsH[wm + r16][ks + seg] : &AsM[wm + r16][ks + seg]);
      bf8 aHL = *(const bf8*)((quad < 2) ? &AsH[wm + r16][ks + seg] : &AsL[wm + r16][ks + seg]);
      #pragma unroll
      for (int tt = 0; tt < 2; ++tt) {
        int nr = wn + tt * 16 + r16;
        bf8 bH = *(const bf8*)&BsH[nr][ks + seg];
        bf8 bM = *(const bf8*)&BsM[nr][ks + seg];
        bf8 b3 = *(const bf8*)((quad < 2) ? &BsL[nr][ks + seg] : &BsH[nr][ks + seg]);
        f4& a = tt ? acc1 : acc0;
        a = __builtin_amdgcn_mfma_f32_16x16x32_bf16(aHM, bH, a, 0, 0, 0);  // HH' + MH'
        a = __builtin_amdgcn_mfma_f32_16x16x32_bf16(aHM, bM, a, 0, 0, 0);  // HM' + MM'
        a = __builtin_amdgcn_mfma_f32_16x16x32_bf16(aHL, b3, a, 0, 0, 0);  // HL' + LH'
      }
    }
    #pragma unroll
    for (int half = 0; half < 2; ++half) {
      bf8 hv = *(const bf8*)&BsH[sqrow][sqk + half * 8];
      bf8 mv = *(const bf8*)&BsM[sqrow][sqk + half * 8];
      bf8 lv = *(const bf8*)&BsL[sqrow][sqk + half * 8];
      #pragma unroll
      for (int q = 0; q < 8; ++q) {
        float x = (bf2f((u16)hv[q]) + bf2f((u16)mv[q])) + bf2f((u16)lv[q]);
        mySq += x * x;
      }
    }
    __syncthreads();
  }
  mySq += __shfl_xor(mySq, 1);
  mySq += __shfl_xor(mySq, 2);
  if ((t & 3) == 0) sqS[sqrow] = mySq;
  __syncthreads();

  #pragma unroll
  for (int tt = 0; tt < 2; ++tt) {
    f4 a = tt ? acc1 : acc0;
    int nl = wn + tt * 16 + r16;
    int n = n0 + nl;
    float sj = sqS[nl];
    #pragma unroll
    for (int reg = 0; reg < 4; ++reg) {
      int m = m0 + wm + quad * 4 + reg;
      float v = (m == n) ? BIGF : (sj - 2.f * a[reg]);
      d2[((size_t)b * NN + m) * NN + n] = v;
    }
  }
}

// ---------------------------------------------------------------- merged: knnsel || qkv+qe (+acc zero)
__global__ __launch_bounds__(256) void knnqkv_kernel(
    const float* __restrict__ d2, unsigned long long* __restrict__ adj,
    const u16* __restrict__ AH, const u16* __restrict__ AL,
    const u16* __restrict__ Pbase_H, const u16* __restrict__ Pbase_L,
    size_t offQ, size_t offK, size_t offV, size_t offE,
    u16* __restrict__ QH, u16* __restrict__ QL,
    u16* __restrict__ KH, u16* __restrict__ KL, u16* __restrict__ Vbf,
    float* __restrict__ qe_all, float* __restrict__ zbuf, int M) {
  __shared__ float dd[4][NN];
  {
    int ztid = blockIdx.x * 256 + threadIdx.x;
    if (ztid < ZTOT) zbuf[ztid] = 0.f;
  }
  int blk = blockIdx.x;
  if (blk < KSEL_BLK) {
    int b = blk / (NN / 4);
    int i0 = (blk % (NN / 4)) * 4;
    int t = threadIdx.x, lane = t & 63, w = t >> 6;

    const float4* src = (const float4*)(d2 + ((size_t)b * NN + i0) * NN);
    float4* dst = (float4*)&dd[0][0];
    #pragma unroll
    for (int x = 0; x < 4; ++x) dst[t + x * 256] = src[t + x * 256];
    __syncthreads();

    int i = i0 + w;
    for (int it = 0; it < KNN_K; ++it) {
      float bv = BIGF; int bi = 0x3fffffff;
      for (int j = lane; j < NN; j += 64) {
        float v = dd[w][j];
        if (v < bv) { bv = v; bi = j; }
      }
      #pragma unroll
      for (int o = 1; o < 64; o <<= 1) {
        float ov = __shfl_xor(bv, o); int oi = __shfl_xor(bi, o);
        if (ov < bv || (ov == bv && oi < bi)) { bv = ov; bi = oi; }
      }
      if (lane == 0) {
        dd[w][bi] = BIGF;
        atomicOr(&adj[((size_t)b * N1 + i) * ADJW + (bi >> 6)], 1ull << (bi & 63));
        atomicOr(&adj[((size_t)b * N1 + bi) * ADJW + (i >> 6)], 1ull << (i & 63));
      }
    }
    return;
  }
  int rel = blk - KSEL_BLK;
  int gx = rel % QKV_GX;
  int y = rel / QKV_GX;
  int z, nt;
  if (y < 8) { z = 0; nt = y; }
  else if (y < 16) { z = 1; nt = y - 8; }
  else if (y < 24) { z = 2; nt = y - 16; }
  else { z = 3; nt = y - 24; }
  size_t woff = z == 0 ? offQ : (z == 1 ? offK : (z == 2 ? offV : offE));
  const u16* PH = Pbase_H + woff;
  const u16* PL = Pbase_L + woff;
  int lane = threadIdx.x & 63;
  int quad = lane >> 4, r16 = lane & 15;
  int mt = gx * 4 + (threadIdx.x >> 6);
  f4 acc = {0.f, 0.f, 0.f, 0.f};
  int m0 = mt * 16;
  int mrow = m0 + r16; if (mrow >= M) mrow = M - 1;
  const u16* aph = AH + (size_t)mrow * DM + quad * 8;
  const u16* apl = AL + (size_t)mrow * DM + quad * 8;
  const u16* ph = PH + ((size_t)nt * 4 * 64 + lane) * 8;
  const u16* pl = PL + ((size_t)nt * 4 * 64 + lane) * 8;
  #pragma unroll
  for (int ks = 0; ks < 4; ++ks) {
    bf8 aH = *(const bf8*)(aph);
    bf8 aL = *(const bf8*)(apl);
    aph += 32; apl += 32;
    bf8 bH = *(const bf8*)(ph + (size_t)ks * 512);
    bf8 bL = *(const bf8*)(pl + (size_t)ks * 512);
    acc = __builtin_amdgcn_mfma_f32_16x16x32_bf16(aH, bH, acc, 0, 0, 0);
    acc = __builtin_amdgcn_mfma_f32_16x16x32_bf16(aH, bL, acc, 0, 0, 0);
    acc = __builtin_amdgcn_mfma_f32_16x16x32_bf16(aL, bH, acc, 0, 0, 0);
  }
  if (m0 >= M) return;
  int n = nt * 16 + r16;
  #pragma unroll
  for (int reg = 0; reg < 4; ++reg) {
    int m = m0 + quad * 4 + reg;
    if (m >= M) continue;
    float v = acc[reg];
    if (z == 3) {
      int b = m / N1, nr = m % N1;
      int h = n >> 5, bk = n & 31;
      qe_all[(((size_t)b * NH + h) * N1 + nr) * 32 + bk] = v;
      continue;
    }
    size_t oi = (size_t)m * DM + n;
    if (z == 0) {
      float sv = v * 0.25f;
      u16 hh = f2bf(sv);
      QH[oi] = hh;
      QL[oi] = f2bf(sv - bf2f(hh));
    } else if (z == 1) {
      u16 hh = f2bf(v);
      KH[oi] = hh;
      KL[oi] = f2bf(v - bf2f(hh));
    } else {
      Vbf[oi] = f2bf(v);
    }
  }
}

// ---------------------------------------------------------------- Wo GEMM: A = Osum/lsum inline (+inorm1 stats)
__global__ __launch_bounds__(256) void gemm_wo_kernel(
    const float* __restrict__ Osum, const float* __restrict__ lsum,
    const u16* __restrict__ PH, const u16* __restrict__ PL,
    const float* __restrict__ res, float* __restrict__ outF,
    float* __restrict__ sumY, float* __restrict__ sumY2, int M) {
  __shared__ float sA[2][16], sQ[2][16];
  int t = threadIdx.x;
  if (t < 32) {
    sA[t >> 4][t & 15] = 0.f;
    sQ[t >> 4][t & 15] = 0.f;
  }
  __syncthreads();
  int lane = t & 63;
  int quad = lane >> 4, r16 = lane & 15;
  int mt = blockIdx.x * 4 + (t >> 6), nt = blockIdx.y;
  f4 acc = {0.f, 0.f, 0.f, 0.f};
  int m0 = mt * 16;
  int mrow = m0 + r16; if (mrow >= M) mrow = M - 1;
  int b = mrow / N1, nr = mrow % N1;
  const u16* ph = PH + ((size_t)nt * 4 * 64 + lane) * 8;
  const u16* pl = PL + ((size_t)nt * 4 * 64 + lane) * 8;
  #pragma unroll
  for (int ks = 0; ks < 4; ++ks) {
    int k = ks * 32 + quad * 8;
    int h = k >> 4, d0 = k & 15;
    size_t base = (size_t)(b * NH + h) * N1 + nr;
    float inv = 1.0f / lsum[base];
    const float* op = Osum + base * 16 + d0;
    bf8 aH, aL;
    #pragma unroll
    for (int j = 0; j < 8; ++j) {
      float v = op[j] * inv;
      u16 hh = f2bf(v);
      aH[j] = (short)hh;
      aL[j] = (short)f2bf(v - bf2f(hh));
    }
    bf8 bH = *(const bf8*)(ph + (size_t)ks * 512);
    bf8 bL = *(const bf8*)(pl + (size_t)ks * 512);
    acc = __builtin_amdgcn_mfma_f32_16x16x32_bf16(aH, bH, acc, 0, 0, 0);
    acc = __builtin_amdgcn_mfma_f32_16x16x32_bf16(aH, bL, acc, 0, 0, 0);
    acc = __builtin_amdgcn_mfma_f32_16x16x32_bf16(aL, bH, acc, 0, 0, 0);
  }
  int n = nt * 16 + r16;
  if (m0 < M) {
    #pragma unroll
    for (int reg = 0; reg < 4; ++reg) {
      int m = m0 + quad * 4 + reg;
      if (m < M) {
        float v = acc[reg] + res[(size_t)m * DM + n];
        outF[(size_t)m * DM + n] = v;
        int mb2 = m / N1;
        atomicAdd(&sA[mb2][r16], v);
        atomicAdd(&sQ[mb2][r16], v * v);
      }
    }
  }
  __syncthreads();
  if (t < 32) {
    int bb = t >> 4, d = nt * 16 + (t & 15);
    atomicAdd(&sumY[bb * DM + d], sA[bb][t & 15]);
    atomicAdd(&sumY2[bb * DM + d], sQ[bb][t & 15]);
  }
}

// ---------------------------------------------------------------- W1 GEMM: A = inorm1(Yb) inline
__global__ __launch_bounds__(256) void gemm_w1_kernel(
    const float* __restrict__ Yb, const float* __restrict__ sumY,
    const float* __restrict__ sumY2, const float* __restrict__ n1w,
    const float* __restrict__ n1b,
    const u16* __restrict__ PH, const u16* __restrict__ PL,
    const float* __restrict__ bias,
    u16* __restrict__ outH, u16* __restrict__ outL, int M) {
  __shared__ float muS[STAT_N], scvS[STAT_N], shS[STAT_N];
  int t = threadIdx.x;
  {
    float mu = sumY[t] * (1.0f / N1);
    float var = sumY2[t] * (1.0f / N1) - mu * mu;
    int d = t & (DM - 1);
    muS[t] = mu;
    scvS[t] = rsqrtf(var + 1e-5f) * n1w[d];
    shS[t] = n1b[d];
  }
  __syncthreads();
  int lane = t & 63;
  int quad = lane >> 4, r16 = lane & 15;
  int mt = blockIdx.x * 4 + (t >> 6), nt = blockIdx.y;
  f4 acc = {0.f, 0.f, 0.f, 0.f};
  int m0 = mt * 16;
  int mrow = m0 + r16; if (mrow >= M) mrow = M - 1;
  int b = mrow / N1;
  const float* yp = Yb + (size_t)mrow * DM + quad * 8;
  const u16* ph = PH + ((size_t)nt * 4 * 64 + lane) * 8;
  const u16* pl = PL + ((size_t)nt * 4 * 64 + lane) * 8;
  #pragma unroll
  for (int ks = 0; ks < 4; ++ks) {
    int k = ks * 32 + quad * 8;
    bf8 aH, aL;
    #pragma unroll
    for (int half = 0; half < 2; ++half) {
      float4 yv = *(const float4*)(yp + ks * 32 + half * 4);
      float ya[4] = {yv.x, yv.y, yv.z, yv.w};
      #pragma unroll
      for (int q = 0; q < 4; ++q) {
        int sidx = b * DM + k + half * 4 + q;
        float nv = (ya[q] - muS[sidx]) * scvS[sidx] + shS[sidx];
        u16 hh = f2bf(nv);
        aH[half * 4 + q] = (short)hh;
        aL[half * 4 + q] = (short)f2bf(nv - bf2f(hh));
      }
    }
    bf8 bH = *(const bf8*)(ph + (size_t)ks * 512);
    bf8 bL = *(const bf8*)(pl + (size_t)ks * 512);
    acc = __builtin_amdgcn_mfma_f32_16x16x32_bf16(aH, bH, acc, 0, 0, 0);
    acc = __builtin_amdgcn_mfma_f32_16x16x32_bf16(aH, bL, acc, 0, 0, 0);
    acc = __builtin_amdgcn_mfma_f32_16x16x32_bf16(aL, bH, acc, 0, 0, 0);
  }
  if (m0 >= M) return;
  int n = nt * 16 + r16;
  #pragma unroll
  for (int reg = 0; reg < 4; ++reg) {
    int m = m0 + quad * 4 + reg;
    if (m < M) {
      float v = fmaxf(acc[reg] + bias[n], 0.f);
      size_t oi = (size_t)m * DFF + n;
      u16 hh = f2bf(v);
      outH[oi] = hh;
      outL[oi] = f2bf(v - bf2f(hh));
    }
  }
}

// ---------------------------------------------------------------- W2 GEMM: res = inorm1(Yb) inline (+inorm2 stats, +gsave)
__global__ __launch_bounds__(256) void gemm_w2_kernel(
    const u16* __restrict__ AH, const u16* __restrict__ AL,
    const u16* __restrict__ PH, const u16* __restrict__ PL,
    const float* __restrict__ bias, const float* __restrict__ Yb,
    const float* __restrict__ sumY, const float* __restrict__ sumY2,
    const float* __restrict__ n1w, const float* __restrict__ n1b,
    float* __restrict__ outF, float* __restrict__ sumX, float* __restrict__ sumX2,
    float* __restrict__ gsave, int M) {
  __shared__ float muS[STAT_N], scvS[STAT_N], shS[STAT_N];
  __shared__ float sA[2][16], sQ[2][16];
  int t = threadIdx.x;
  {
    float mu = sumY[t] * (1.0f / N1);
    float var = sumY2[t] * (1.0f / N1) - mu * mu;
    int d = t & (DM - 1);
    muS[t] = mu;
    scvS[t] = rsqrtf(var + 1e-5f) * n1w[d];
    shS[t] = n1b[d];
  }
  if (t < 32) {
    sA[t >> 4][t & 15] = 0.f;
    sQ[t >> 4][t & 15] = 0.f;
  }
  __syncthreads();
  int lane = t & 63;
  int quad = lane >> 4, r16 = lane & 15;
  int mt = blockIdx.x * 4 + (t >> 6), nt = blockIdx.y;
  f4 acc = {0.f, 0.f, 0.f, 0.f};
  int m0 = mt * 16;
  int mrow = m0 + r16; if (mrow >= M) mrow = M - 1;
  const u16* aph = AH + (size_t)mrow * DFF + quad * 8;
  const u16* apl = AL + (size_t)mrow * DFF + quad * 8;
  const u16* ph = PH + ((size_t)nt * 16 * 64 + lane) * 8;
  const u16* pl = PL + ((size_t)nt * 16 * 64 + lane) * 8;
  #pragma unroll 4
  for (int ks = 0; ks < 16; ++ks) {
    bf8 aH = *(const bf8*)(aph);
    bf8 aL = *(const bf8*)(apl);
    aph += 32; apl += 32;
    bf8 bH = *(const bf8*)(ph + (size_t)ks * 512);
    bf8 bL = *(const bf8*)(pl + (size_t)ks * 512);
    acc = __builtin_amdgcn_mfma_f32_16x16x32_bf16(aH, bH, acc, 0, 0, 0);
    acc = __builtin_amdgcn_mfma_f32_16x16x32_bf16(aH, bL, acc, 0, 0, 0);
    acc = __builtin_amdgcn_mfma_f32_16x16x32_bf16(aL, bH, acc, 0, 0, 0);
  }
  int n = nt * 16 + r16;
  if (m0 < M) {
    #pragma unroll
    for (int reg = 0; reg < 4; ++reg) {
      int m = m0 + quad * 4 + reg;
      if (m < M) {
        int b = m / N1, mn2 = m % N1;
        int sidx = b * DM + n;
        float h1 = (Yb[(size_t)m * DM + n] - muS[sidx]) * scvS[sidx] + shS[sidx];
        float v = acc[reg] + bias[n] + h1;
        outF[(size_t)m * DM + n] = v;
        atomicAdd(&sA[b][r16], v);
        atomicAdd(&sQ[b][r16], v * v);
        if (mn2 == NN) gsave[sidx] = v;
      }
    }
  }
  __syncthreads();
  if (t < 32) {
    int bb = t >> 4, d = nt * 16 + (t & 15);
    atomicAdd(&sumX[bb * DM + d], sA[bb][t & 15]);
    atomicAdd(&sumX2[bb * DM + d], sQ[bb][t & 15]);
  }
}

// ---------------------------------------------------------------- xsplit2: parallel inorm2 + split emit (+pool, +g)
__global__ __launch_bounds__(256) void xsplit2_kernel(
    float* __restrict__ X, const float* __restrict__ sumX, const float* __restrict__ sumX2,
    const float* __restrict__ gsave, const float* __restrict__ w, const float* __restrict__ b_,
    float* __restrict__ pool, u16* __restrict__ XH, u16* __restrict__ XM,
    u16* __restrict__ XL) {
  int idx = blockIdx.x * 256 + threadIdx.x;
  if (idx >= BB * N1 * DM) return;
  int d = idx % DM; int r = idx / DM; int n = r % N1; int b = r / N1;
  int sidx = b * DM + d;
  float sx = sumX[sidx];
  float mu = sx * (1.0f / N1);
  float var = sumX2[sidx] * (1.0f / N1) - mu * mu;
  float scv = rsqrtf(var + 1e-5f) * w[d];
  float sh = b_[d];
  float hmean = ((sx - gsave[sidx]) * (1.0f / NN) - mu) * scv + sh;
  float nv = (X[idx] - mu) * scv + sh;
  if (n == NN) nv += hmean;       // g-update for next layer
  X[idx] = nv;
  u16 hh = f2bf(nv); float r1 = nv - bf2f(hh);
  u16 mm = f2bf(r1);
  XH[idx] = hh; XM[idx] = mm; XL[idx] = f2bf(r1 - bf2f(mm));
  if (n == 0) pool[sidx] = hmean;
}

// ---------------------------------------------------------------- MFMA flash attention, key-split
#define CH 64
#define NCH 17
__global__ __launch_bounds__(128) void attn_kernel(
    const u16* __restrict__ QH, const u16* __restrict__ QL,
    const u16* __restrict__ KH, const u16* __restrict__ KL,
    const u16* __restrict__ Vbf, const float* __restrict__ qe_all,
    const unsigned char* __restrict__ buckp, const unsigned long long* __restrict__ adj,
    float* __restrict__ Osum, float* __restrict__ lsum) {
  __shared__ __align__(16) u16 KsHi[2][CH][20];
  __shared__ __align__(16) u16 KsLo[2][CH][20];
  __shared__ __align__(16) u16 Vt[2][DK][68];
  __shared__ __align__(16) u16 Ps[2][16][72];
  __shared__ __align__(16) float qe_s[2][16][36];
  __shared__ u32 maskS[32][6];
  __shared__ unsigned char buckS[2][32][68];

  int qt = blockIdx.x;
  int h = blockIdx.y & 7, b = blockIdx.y >> 3;
  int s = blockIdx.z;
  int c0 = (NCH * s) / NSPLIT, c1 = (NCH * (s + 1)) / NSPLIT;
  int nwm = 2 * (c1 - c0);
  int t = threadIdx.x, lane = t & 63, w = t >> 6;
  int quad = lane >> 4, r16 = lane & 15;
  int i0 = qt * 32;
  int iw = i0 + w * 16;
  int bh = b * NH + h;

  for (int x = t; x < 32 * nwm; x += 128) {
    int rr = x / nwm, ww = x % nwm;
    int gi = i0 + rr; if (gi > NN) gi = NN;
    int W = 2 * c0 + ww;
    u32 v;
    if (gi == 0 || gi == NN) {
      v = 0xffffffffu;
    } else {
      const u32* a32 = (const u32*)(adj + ((size_t)b * N1 + gi) * ADJW);
      v = a32[W];
      int bs = gi & ~127;
      int lo = gi - 11 < bs ? bs : gi - 11;
      int be = bs + 127;
      int hi = gi + 11 > be ? be : gi + 11;
      int aa = lo - 32 * W, bnd = hi - 32 * W;
      if (aa < 0) aa = 0; if (bnd > 31) bnd = 31;
      if (aa <= bnd) v |= (0xffffffffu << aa) & (0xffffffffu >> (31 - bnd));
      if (W == 0) v |= 1u;
      if (W == 32) v |= 1u;
      int dg = gi - 32 * W;
      if (dg >= 0 && dg < 32) v |= 1u << dg;
    }
    if (W == 32) v &= 1u;
    else if (W == 33) v = 0u;
    maskS[rr][ww] = v;
  }
  #pragma unroll
  for (int e = 0; e < 2; ++e) {
    int x = lane + e * 64;
    int rr = x >> 3, bk = (x & 7) * 4;
    int gi = iw + rr; if (gi > NN) gi = NN;
    f4 v = *(const f4*)(qe_all + (((size_t)b * NH + h) * N1 + gi) * 32 + bk);
    *(f4*)&qe_s[w][rr][bk] = v;
  }
  bf8 qfrag;
  {
    int gi = iw + r16; if (gi > NN) gi = NN;
    const u16* qsrc = (quad < 2 ? QH : QL) + ((size_t)(b * N1 + gi) * DM + h * DK + (quad & 1) * 8);
    qfrag = *(const bf8*)qsrc;
  }

  ushort4 khr[2], klr[2], vvr[2]; u32 bkr[4];
  auto load_chunk = [&](int c) {
    int j0 = c * CH;
    #pragma unroll
    for (int ii = 0; ii < 2; ++ii) {
      int x = t + ii * 128;
      int key = x >> 2, ds = (x & 3) * 4;
      int jg = j0 + key; if (jg > NN) jg = NN;
      size_t src = (size_t)(b * N1 + jg) * DM + h * DK + ds;
      khr[ii] = *(const ushort4*)(KH + src);
      klr[ii] = *(const ushort4*)(KL + src);
      vvr[ii] = *(const ushort4*)(Vbf + src);
    }
    #pragma unroll
    for (int ii = 0; ii < 4; ++ii) {
      int x = t + ii * 128;
      int rr = x >> 4, c4 = (x & 15) * 4;
      int gi = i0 + rr; if (gi > NN) gi = NN;
      bkr[ii] = *(const u32*)(buckp + ((size_t)b * N1 + gi) * BSTR + j0 + c4);
    }
  };
  auto store_chunk = [&](int pb) {
    #pragma unroll
    for (int ii = 0; ii < 2; ++ii) {
      int x = t + ii * 128;
      int key = x >> 2, ds = (x & 3) * 4;
      *(ushort4*)&KsHi[pb][key][ds] = khr[ii];
      *(ushort4*)&KsLo[pb][key][ds] = klr[ii];
      Vt[pb][ds + 0][key] = vvr[ii].x;
      Vt[pb][ds + 1][key] = vvr[ii].y;
      Vt[pb][ds + 2][key] = vvr[ii].z;
      Vt[pb][ds + 3][key] = vvr[ii].w;
    }
    #pragma unroll
    for (int ii = 0; ii < 4; ++ii) {
      int x = t + ii * 128;
      int rr = x >> 4, c4 = (x & 15) * 4;
      *(u32*)&buckS[pb][rr][c4] = bkr[ii];
    }
  };

  f4 Oacc = {0.f, 0.f, 0.f, 0.f};
  float lrun[4] = {0.f, 0.f, 0.f, 0.f};

  load_chunk(c0);
  store_chunk(0);

  for (int c = c0; c < c1; ++c) {
    int pb = (c - c0) & 1;
    bool pf = (c + 1 < c1);
    if (pf) load_chunk(c + 1);
    __syncthreads();

    f4 S[4];
    #pragma unroll
    for (int tt = 0; tt < 4; ++tt) {
      int key = tt * 16 + r16;
      int off = (quad & 1) * 8;
      bf8 bhv = mk8(*(const ushort4*)&KsHi[pb][key][off], *(const ushort4*)&KsHi[pb][key][off + 4]);
      bf8 blv = mk8(*(const ushort4*)&KsLo[pb][key][off], *(const ushort4*)&KsLo[pb][key][off + 4]);
      f4 z = {0.f, 0.f, 0.f, 0.f};
      z = __builtin_amdgcn_mfma_f32_16x16x32_bf16(qfrag, bhv, z, 0, 0, 0);
      z = __builtin_amdgcn_mfma_f32_16x16x32_bf16(qfrag, blv, z, 0, 0, 0);
      S[tt] = z;
    }

    #pragma unroll
    for (int rg = 0; rg < 4; ++rg) {
      int rowb = w * 16 + quad * 4 + rg;
      u32 mw0 = maskS[rowb][2 * (c - c0)];
      u32 mw1 = maskS[rowb][2 * (c - c0) + 1];
      float ps = 0.f;
      #pragma unroll
      for (int tt = 0; tt < 4; ++tt) {
        u32 mword = (tt & 2) ? mw1 : mw0;
        int bit = (tt & 1) * 16 + r16;
        int bk = buckS[pb][rowb][tt * 16 + r16] & 31;
        float rel = qe_s[w][quad * 4 + rg][bk];
        float sc = S[tt][rg] + rel;
        sc += ((mword >> bit) & 1u) ? 0.f : -1.0e9f;
        float p = __expf(sc - SM_OFF);
        ps += p;
        Ps[w][quad * 4 + rg][tt * 16 + r16] = f2bf(p);
      }
      #pragma unroll
      for (int o = 1; o < 16; o <<= 1) ps += __shfl_xor(ps, o);
      lrun[rg] += ps;
    }
    #pragma unroll
    for (int half = 0; half < 2; ++half) {
      bf8 pa = *(const bf8*)&Ps[w][r16][half * 32 + quad * 8];
      bf8 vb = mk8(*(const ushort4*)&Vt[pb][r16][half * 32 + quad * 8],
                   *(const ushort4*)&Vt[pb][r16][half * 32 + quad * 8 + 4]);
      Oacc = __builtin_amdgcn_mfma_f32_16x16x32_bf16(pa, vb, Oacc, 0, 0, 0);
    }

    if (pf) store_chunk(pb ^ 1);
  }

  #pragma unroll
  for (int rg = 0; rg < 4; ++rg) {
    int gi = i0 + w * 16 + quad * 4 + rg;
    if (gi < N1) {
      size_t base = (size_t)bh * N1 + gi;
      atomicAdd(&Osum[base * 16 + r16], Oacc[rg]);
      if (r16 == 0) atomicAdd(&lsum[base], lrun[rg]);
    }
  }
}

// ---------------------------------------------------------------- final GEMM (inline inorm2 + pm, +out_pm)
__global__ __launch_bounds__(256) void gemm_final_kernel(
    const float* __restrict__ X, const float* __restrict__ sumX,
    const float* __restrict__ sumX2, const float* __restrict__ gsave,
    const float* __restrict__ n2w, const float* __restrict__ n2b,
    const float* __restrict__ pools,
    const u16* __restrict__ PH, const u16* __restrict__ PL,
    const float* __restrict__ bias, float* __restrict__ out, float* __restrict__ out_pm) {
  __shared__ float muS[STAT_N], scvS[STAT_N], shS[STAT_N], pmS[STAT_N];
  int t = threadIdx.x;
  {
    float sx = sumX[t];
    float mu = sx * (1.0f / N1);
    float var = sumX2[t] * (1.0f / N1) - mu * mu;
    int d = t & (DM - 1);
    float scv = rsqrtf(var + 1e-5f) * n2w[d];
    float sh = n2b[d];
    float hmean = ((sx - gsave[t]) * (1.0f / NN) - mu) * scv + sh;
    float pm = (pools[t] + pools[BB * DM + t] + hmean) * (1.0f / 3.0f);
    muS[t] = mu; scvS[t] = scv; shS[t] = sh; pmS[t] = pm;
    if (blockIdx.x == 0 && blockIdx.y == 0) out_pm[t] = pm;
  }
  __syncthreads();
  int lane = t & 63;
  int quad = lane >> 4, r16 = lane & 15;
  int mt = blockIdx.x * 4 + (t >> 6), nt = blockIdx.y;
  const int M = BB * NN;
  f4 acc = {0.f, 0.f, 0.f, 0.f};
  int m0 = mt * 16;
  int mrow = m0 + r16; if (mrow >= M) mrow = M - 1;
  int mb = mrow / NN, mn = mrow % NN;
  const float* xp = X + ((size_t)mb * N1 + mn) * DM + quad * 8;
  const u16* ph = PH + ((size_t)nt * 4 * 64 + lane) * 8;
  const u16* pl = PL + ((size_t)nt * 4 * 64 + lane) * 8;
  #pragma unroll
  for (int ks = 0; ks < 4; ++ks) {
    int k = ks * 32 + quad * 8;
    bf8 aH, aL;
    #pragma unroll
    for (int half = 0; half < 2; ++half) {
      float4 xv = *(const float4*)(xp + ks * 32 + half * 4);
      float xa[4] = {xv.x, xv.y, xv.z, xv.w};
      #pragma unroll
      for (int q = 0; q < 4; ++q) {
        int sidx = mb * DM + k + half * 4 + q;
        float av = (xa[q] - muS[sidx]) * scvS[sidx] + shS[sidx] + pmS[sidx];
        u16 hh = f2bf(av);
        aH[half * 4 + q] = (short)hh;
        aL[half * 4 + q] = (short)f2bf(av - bf2f(hh));
      }
    }
    bf8 bH = *(const bf8*)(ph + (size_t)ks * 512);
    bf8 bL = *(const bf8*)(pl + (size_t)ks * 512);
    acc = __builtin_amdgcn_mfma_f32_16x16x32_bf16(aH, bH, acc, 0, 0, 0);
    acc = __builtin_amdgcn_mfma_f32_16x16x32_bf16(aH, bL, acc, 0, 0, 0);
    acc = __builtin_amdgcn_mfma_f32_16x16x32_bf16(aL, bH, acc, 0, 0, 0);
  }
  int n = nt * 16 + r16;
  #pragma unroll
  for (int reg = 0; reg < 4; ++reg) {
    int m = m0 + quad * 4 + reg;
    if (m < M) out[(size_t)m * DM + n] = acc[reg] + bias[n];
  }
}

// ================================================================ launch
extern "C" void kernel_launch(void* const* d_in, const int* in_sizes, int n_in,
                              void* d_out, int out_size, void* d_ws, size_t ws_size,
                              hipStream_t stream) {
  const float* coords = (const float*)d_in[0];
  const float* inW    = (const float*)d_in[1];
  const float* inb    = (const float*)d_in[2];
  const float* gnode  = (const float*)d_in[3];
  const float* Wq     = (const float*)d_in[4];
  const float* Wk     = (const float*)d_in[5];
  const float* Wv     = (const float*)d_in[6];
  const float* Wo     = (const float*)d_in[7];
  const float* emb    = (const float*)d_in[8];
  const float* W1     = (const float*)d_in[9];
  const float* b1     = (const float*)d_in[10];
  const float* W2     = (const float*)d_in[11];
  const float* b2     = (const float*)d_in[12];
  const float* n1w    = (const float*)d_in[13];
  const float* n1b    = (const float*)d_in[14];
  const float* n2w    = (const float*)d_in[15];
  const float* n2b    = (const float*)d_in[16];
  const float* outW   = (const float*)d_in[17];
  const float* outb   = (const float*)d_in[18];
  float* out = (float*)d_out;

  char* wsp = (char*)d_ws;
  size_t off = 0;
  auto alloc = [&](size_t bytes) -> void* {
    off = (off + 255) & ~(size_t)255;
    void* p = wsp + off;
    off += bytes;
    return p;
  };
  const size_t XB = (size_t)BB * N1 * DM * 4;       // fp32 activation buffer
  const size_t HB = (size_t)BB * N1 * DM * 2;       // u16 half buffer
  float* X0   = (float*)alloc(XB);
  float* X1   = (float*)alloc(XB);
  float* Yb   = (float*)alloc(XB);
  u16* XH = (u16*)alloc(HB); u16* XM = (u16*)alloc(HB); u16* XL = (u16*)alloc(HB);
  u16* QH = (u16*)alloc(HB); u16* QL = (u16*)alloc(HB);
  u16* KH = (u16*)alloc(HB); u16* KL = (u16*)alloc(HB);
  u16* Vbf = (u16*)alloc(HB);
  u16* FbH = (u16*)alloc((size_t)BB * N1 * DFF * 2);
  u16* FbL = (u16*)alloc((size_t)BB * N1 * DFF * 2);
  unsigned char* buckp = (unsigned char*)alloc((size_t)BB * N1 * BSTR);
  unsigned long long* adj = (unsigned long long*)alloc((size_t)BB * N1 * ADJW * 8);
  float* pools = (float*)alloc((size_t)NLAYERS * BB * DM * 4);
  float* qe_all = (float*)alloc((size_t)BB * NH * N1 * 32 * 4);
  float* zbuf = (float*)alloc((size_t)ZTOT * 4);    // Osum + lsum + sumY/sumY2 + sumX/sumX2
  float* gsave = (float*)alloc((size_t)STAT_N * 4);
  u16* PH = (u16*)alloc((size_t)PW_TOT * 2);
  u16* PL = (u16*)alloc((size_t)PW_TOT * 2);
  float* d2 = (float*)alloc((size_t)BB * NN * NN * 4);

  float* Osum = zbuf;
  float* lsum = zbuf + OSUM_N;
  float* sumY = zbuf + OSUM_N + LSUM_N;
  float* sumY2 = sumY + STAT_N;
  float* sumX = sumY2 + STAT_N;
  float* sumX2 = sumX + STAT_N;

  init_kernel<<<PBLK + EBLK + BBLK, 256, 0, stream>>>(
      coords, inW, inb, gnode, Wq, Wk, Wv, Wo, W1, W2, outW, emb,
      PH, PL, X0, XH, XM, XL, buckp);

  float* Xin = X0; float* Xout = X1;
  const int M = BB * N1;
  const int GX = 33;     // ceil(129 m-tiles / 4 waves)
  for (int l = 0; l < NLAYERS; ++l) {
    gram_kernel<<<dim3(32, 16, BB), 256, 0, stream>>>(XH, XM, XL, adj, d2);

    // knnsel || qkv (independent) merged; also zeroes Osum/lsum/stats
    knnqkv_kernel<<<KSEL_BLK + QKV_BLK, 256, 0, stream>>>(
        d2, adj, XH, XM, PH, PL,
        (size_t)PWQ_OFF + (size_t)l * DM * DM,
        (size_t)PWK_OFF + (size_t)l * DM * DM,
        (size_t)PWV_OFF + (size_t)l * DM * DM,
        (size_t)PWQE_OFF + (size_t)l * 256 * DM,
        QH, QL, KH, KL, Vbf, qe_all, zbuf, M);

    attn_kernel<<<dim3(33, NH * BB, NSPLIT), 128, 0, stream>>>(
        QH, QL, KH, KL, Vbf, qe_all, buckp, adj, Osum, lsum);

    gemm_wo_kernel<<<dim3(GX, 8), 256, 0, stream>>>(
        Osum, lsum, PH + PWO_OFF + (size_t)l * DM * DM, PL + PWO_OFF + (size_t)l * DM * DM,
        Xin, Yb, sumY, sumY2, M);

    gemm_w1_kernel<<<dim3(GX, 32), 256, 0, stream>>>(
        Yb, sumY, sumY2, n1w + l * DM, n1b + l * DM,
        PH + PW1_OFF + (size_t)l * DFF * DM, PL + PW1_OFF + (size_t)l * DFF * DM,
        b1 + l * DFF, FbH, FbL, M);

    gemm_w2_kernel<<<dim3(GX, 8), 256, 0, stream>>>(
        FbH, FbL, PH + PW2_OFF + (size_t)l * DM * DFF, PL + PW2_OFF + (size_t)l * DM * DFF,
        b2 + l * DM, Yb, sumY, sumY2, n1w + l * DM, n1b + l * DM,
        Xout, sumX, sumX2, gsave, M);

    if (l < NLAYERS - 1) {
      // parallel inorm2 + split emit + pool + g-update (layers 0,1 only)
      xsplit2_kernel<<<(BB * N1 * DM + 255) / 256, 256, 0, stream>>>(
          Xout, sumX, sumX2, gsave, n2w + l * DM, n2b + l * DM,
          pools + (size_t)l * BB * DM, XH, XM, XL);
    }

    float* t2 = Xin; Xin = Xout; Xout = t2;
  }

  // layer-3 inorm2 folded into final GEMM (pools[2] == hmean computed inline)
  gemm_final_kernel<<<dim3(32, 8), 256, 0, stream>>>(
      Xin, sumX, sumX2, gsave, n2w + 2 * DM, n2b + 2 * DM, pools,
      PH + PWOUT_OFF, PL + PWOUT_OFF, outb, out, out + (size_t)BB * NN * DM);
}